// Round 1
// baseline (17709.622 us; speedup 1.0000x reference)
//
#include <hip/hip_runtime.h>
#include <hip/hip_bf16.h>
#include <math.h>

// Problem dims
#define NB 16
#define NS 256
#define ND 512
#define NH 1024
#define NF 2048
#define NHID 256

// ---------------------------------------------------------------------------
// Generic fp32 tiled GEMM: C[M,N] = A[M,K] * op(B) (+bias) (+gelu)
// A row-major lda=K. TRANSB=1: B is (N,K) row-major (dot rows). TRANSB=0: B is (K,N) ldb given.
// Tile 64x64, BK=16, 256 threads, 4x4 per thread. All dims assumed multiples of tile.
// ---------------------------------------------------------------------------
template<int TRANSB, int ACT>
__global__ __launch_bounds__(256) void gemm_kernel(
    const float* __restrict__ A, const float* __restrict__ B,
    const float* __restrict__ bias, float* __restrict__ C,
    int M, int N, int K, int ldb)
{
    __shared__ float As[16][65];
    __shared__ float Bs[16][65];
    int tid = threadIdx.x;
    int tx = tid & 15, ty = tid >> 4;
    int m0 = blockIdx.y * 64, n0 = blockIdx.x * 64;
    float acc[4][4] = {};

    for (int k0 = 0; k0 < K; k0 += 16) {
        {   // A tile: 64 rows x 16 cols
            int r = tid >> 2, kq = (tid & 3) * 4;
            float4 v = *(const float4*)(A + (size_t)(m0 + r) * K + k0 + kq);
            As[kq + 0][r] = v.x; As[kq + 1][r] = v.y;
            As[kq + 2][r] = v.z; As[kq + 3][r] = v.w;
        }
        if (TRANSB) {  // B tile from (N,K): rows n, cols k
            int r = tid >> 2, kq = (tid & 3) * 4;
            float4 v = *(const float4*)(B + (size_t)(n0 + r) * ldb + k0 + kq);
            Bs[kq + 0][r] = v.x; Bs[kq + 1][r] = v.y;
            Bs[kq + 2][r] = v.z; Bs[kq + 3][r] = v.w;
        } else {       // B tile from (K,N): rows k, cols n
            int kr = tid >> 4, nq = (tid & 15) * 4;
            float4 v = *(const float4*)(B + (size_t)(k0 + kr) * ldb + n0 + nq);
            Bs[kr][nq + 0] = v.x; Bs[kr][nq + 1] = v.y;
            Bs[kr][nq + 2] = v.z; Bs[kr][nq + 3] = v.w;
        }
        __syncthreads();
        #pragma unroll
        for (int kk = 0; kk < 16; ++kk) {
            float a[4], b[4];
            #pragma unroll
            for (int i = 0; i < 4; ++i) a[i] = As[kk][ty * 4 + i];
            #pragma unroll
            for (int j = 0; j < 4; ++j) b[j] = Bs[kk][tx * 4 + j];
            #pragma unroll
            for (int i = 0; i < 4; ++i)
                #pragma unroll
                for (int j = 0; j < 4; ++j)
                    acc[i][j] += a[i] * b[j];
        }
        __syncthreads();
    }

    #pragma unroll
    for (int i = 0; i < 4; ++i) {
        int m = m0 + ty * 4 + i;
        int n = n0 + tx * 4;
        float4 v;
        float* vp = &v.x;
        #pragma unroll
        for (int j = 0; j < 4; ++j) {
            float x = acc[i][j];
            if (bias) x += bias[n + j];
            if (ACT == 1) x = 0.5f * x * (1.0f + erff(x * 0.70710678118654752f));
            vp[j] = x;
        }
        *(float4*)(C + (size_t)m * N + n) = v;
    }
}

// ---------------------------------------------------------------------------
// bias combine: bsum[0:1024)=bih_f+bhh_f ; bsum[1024:2048)=bih_b+bhh_b
// ---------------------------------------------------------------------------
__global__ __launch_bounds__(256) void bias_sum_kernel(
    const float* bihF, const float* bhhF, const float* bihB, const float* bhhB,
    float* out)
{
    int i = blockIdx.x * 256 + threadIdx.x;
    if (i < 1024) out[i] = bihF[i] + bhhF[i];
    else out[i] = bihB[i - 1024] + bhhB[i - 1024];
}

// ---------------------------------------------------------------------------
// LSTM recurrence. grid=32 (dir*16+b), block=256. Thread t owns c[t]/h[t] and
// computes gates {t, 256+t, 512+t, 768+t}. h broadcast via LDS.
// pre layout: row (b*NS+s) x 1024. Writes features (B,S,512), fwd→[0:256), bwd→[256:512).
// ---------------------------------------------------------------------------
__global__ __launch_bounds__(256) void lstm_rec_kernel(
    const float* __restrict__ preF, const float* __restrict__ preB,
    const float* __restrict__ WhhF, const float* __restrict__ WhhB,
    float* __restrict__ feat)
{
    int blk = blockIdx.x;
    int dir = blk >> 4, b = blk & 15;
    const float* pre = dir ? preB : preF;
    const float* Whh = dir ? WhhB : WhhF;
    int t = threadIdx.x;

    __shared__ float h_lds[256];
    h_lds[t] = 0.0f;
    float c = 0.0f;
    __syncthreads();

    const float4* wi = (const float4*)(Whh + (size_t)t * 256);
    const float4* wf = (const float4*)(Whh + (size_t)(256 + t) * 256);
    const float4* wg = (const float4*)(Whh + (size_t)(512 + t) * 256);
    const float4* wo = (const float4*)(Whh + (size_t)(768 + t) * 256);

    for (int si = 0; si < NS; ++si) {
        int s = dir ? (NS - 1 - si) : si;
        const float* prow = pre + ((size_t)(b * NS + s)) * 1024;
        float ai = prow[t], af = prow[256 + t], ag = prow[512 + t], ao = prow[768 + t];
        #pragma unroll 4
        for (int k4 = 0; k4 < 64; ++k4) {
            float4 hv = ((const float4*)h_lds)[k4];
            float4 a = wi[k4], f = wf[k4], g = wg[k4], o = wo[k4];
            ai += a.x * hv.x + a.y * hv.y + a.z * hv.z + a.w * hv.w;
            af += f.x * hv.x + f.y * hv.y + f.z * hv.z + f.w * hv.w;
            ag += g.x * hv.x + g.y * hv.y + g.z * hv.z + g.w * hv.w;
            ao += o.x * hv.x + o.y * hv.y + o.z * hv.z + o.w * hv.w;
        }
        float gi = 1.0f / (1.0f + expf(-ai));
        float gf = 1.0f / (1.0f + expf(-af));
        float gg = tanhf(ag);
        float go = 1.0f / (1.0f + expf(-ao));
        c = gf * c + gi * gg;
        float h = go * tanhf(c);
        __syncthreads();
        h_lds[t] = h;
        __syncthreads();
        feat[((size_t)(b * NS + s)) * 512 + dir * 256 + t] = h;
    }
}

// ---------------------------------------------------------------------------
// broadcast label_embeddings (1024x512) to query (16,1024,512), float4
// ---------------------------------------------------------------------------
__global__ __launch_bounds__(256) void bcast_query_kernel(
    const float* __restrict__ le, float* __restrict__ q)
{
    size_t i = (size_t)blockIdx.x * 256 + threadIdx.x;   // float4 index, 2,097,152 total
    float4 v = ((const float4*)le)[i & (131072 - 1)];    // 1024*512/4 = 131072
    ((float4*)q)[i] = v;
}

// ---------------------------------------------------------------------------
// row softmax in place: grid = rows, block = 256
// ---------------------------------------------------------------------------
__global__ __launch_bounds__(256) void softmax_kernel(float* __restrict__ X, int N)
{
    float* row = X + (size_t)blockIdx.x * N;
    int t = threadIdx.x;
    float m = -1e30f;
    for (int j = t; j < N; j += 256) m = fmaxf(m, row[j]);
    for (int o = 32; o; o >>= 1) m = fmaxf(m, __shfl_xor(m, o));
    __shared__ float lm[4];
    if ((t & 63) == 0) lm[t >> 6] = m;
    __syncthreads();
    m = fmaxf(fmaxf(lm[0], lm[1]), fmaxf(lm[2], lm[3]));
    float s = 0.0f;
    for (int j = t; j < N; j += 256) { float e = expf(row[j] - m); row[j] = e; s += e; }
    for (int o = 32; o; o >>= 1) s += __shfl_xor(s, o);
    __shared__ float ls[4];
    if ((t & 63) == 0) ls[t >> 6] = s;
    __syncthreads();
    s = ls[0] + ls[1] + ls[2] + ls[3];
    float inv = 1.0f / s;
    for (int j = t; j < N; j += 256) row[j] *= inv;
}

// ---------------------------------------------------------------------------
// LayerNorm in place over rows of 512. grid = rows, block = 256 (2 elems/thread)
// ---------------------------------------------------------------------------
__global__ __launch_bounds__(256) void layernorm_kernel(
    float* __restrict__ X, const float* __restrict__ g, const float* __restrict__ b)
{
    float* row = X + (size_t)blockIdx.x * 512;
    int t = threadIdx.x;
    float x0 = row[t], x1 = row[t + 256];
    float s = x0 + x1, sq = x0 * x0 + x1 * x1;
    for (int o = 32; o; o >>= 1) { s += __shfl_xor(s, o); sq += __shfl_xor(sq, o); }
    __shared__ float ls[8];
    int w = t >> 6;
    if ((t & 63) == 0) { ls[w] = s; ls[4 + w] = sq; }
    __syncthreads();
    s = ls[0] + ls[1] + ls[2] + ls[3];
    sq = ls[4] + ls[5] + ls[6] + ls[7];
    float mu = s * (1.0f / 512.0f);
    float var = sq * (1.0f / 512.0f) - mu * mu;
    float inv = rsqrtf(var + 1e-5f);
    row[t]       = (x0 - mu) * inv * g[t]       + b[t];
    row[t + 256] = (x1 - mu) * inv * g[t + 256] + b[t + 256];
}

// ---------------------------------------------------------------------------
// out[b,h] = dot(query[b,h,:], proj[:,h]); one wave per (b,h); grid 4096 x 256
// ---------------------------------------------------------------------------
__global__ __launch_bounds__(256) void outproj_kernel(
    const float* __restrict__ query, const float* __restrict__ proj, float* __restrict__ out)
{
    int gw = blockIdx.x * 4 + (threadIdx.x >> 6);  // 0..16383 = b*1024+h
    int lane = threadIdx.x & 63;
    int h = gw & 1023;
    const float* q = query + (size_t)gw * 512;
    float s = 0.0f;
    for (int d = lane; d < 512; d += 64) s += q[d] * proj[(size_t)d * 1024 + h];
    for (int o = 32; o; o >>= 1) s += __shfl_xor(s, o);
    if (lane == 0) out[gw] = s;
}

// ---------------------------------------------------------------------------
// launcher
// ---------------------------------------------------------------------------
static void launch_gemm(int transb, int act, const float* A, const float* B,
                        const float* bias, float* C, int M, int N, int K, int ldb,
                        hipStream_t s)
{
    dim3 g(N / 64, M / 64), blk(256);
    if (transb) {
        gemm_kernel<1, 0><<<g, blk, 0, s>>>(A, B, bias, C, M, N, K, ldb);
    } else if (act) {
        gemm_kernel<0, 1><<<g, blk, 0, s>>>(A, B, bias, C, M, N, K, ldb);
    } else {
        gemm_kernel<0, 0><<<g, blk, 0, s>>>(A, B, bias, C, M, N, K, ldb);
    }
}

extern "C" void kernel_launch(void* const* d_in, const int* in_sizes, int n_in,
                              void* d_out, int out_size, void* d_ws, size_t ws_size,
                              hipStream_t stream)
{
    (void)in_sizes; (void)n_in; (void)out_size; (void)ws_size;

    const float* x     = (const float*)d_in[0];   // (16,256,512)
    const float* le    = (const float*)d_in[1];   // (1024,512)
    const float* proj  = (const float*)d_in[2];   // (512,1024)
    const float* WihF  = (const float*)d_in[3];   // (1024,512)
    const float* WhhF  = (const float*)d_in[4];   // (1024,256)
    const float* bihF  = (const float*)d_in[5];
    const float* bhhF  = (const float*)d_in[6];
    const float* WihB  = (const float*)d_in[7];
    const float* WhhB  = (const float*)d_in[8];
    const float* bihB  = (const float*)d_in[9];
    const float* bhhB  = (const float*)d_in[10];
    const float* w1    = (const float*)d_in[11];  // (2,512,2048)
    const float* b1    = (const float*)d_in[12];  // (2,2048)
    const float* w2    = (const float*)d_in[13];  // (2,2048,512)
    const float* b2    = (const float*)d_in[14];  // (2,512)
    const float* lng   = (const float*)d_in[15];  // (2,512)
    const float* lnb   = (const float*)d_in[16];  // (2,512)
    float* out = (float*)d_out;
    float* ws  = (float*)d_ws;

    // workspace layout (floats)
    const size_t PRE_F = 0;                       // 4096*1024
    const size_t PRE_B = PRE_F + 4194304;         // 4096*1024
    const size_t FEAT  = PRE_B + 4194304;         // 16*256*512
    const size_t QUERY = FEAT + 2097152;          // 16*1024*512
    const size_t WSC   = QUERY + 8388608;         // 1024*1024
    const size_t Q1S   = WSC + 1048576;           // 1024*512
    const size_t S2S   = Q1S + 524288;            // 1024*256
    const size_t FFH   = S2S + 262144;            // 1024*2048
    const size_t BSUM  = FFH + 2097152;           // 2048
    const size_t Q2    = PRE_F;                   // alias: pre dead after recurrence (16*1024*512)

    float* preF  = ws + PRE_F;
    float* preB  = ws + PRE_B;
    float* feat  = ws + FEAT;
    float* query = ws + QUERY;
    float* wsc   = ws + WSC;
    float* q1s   = ws + Q1S;
    float* s2s   = ws + S2S;
    float* ffh   = ws + FFH;
    float* bsum  = ws + BSUM;
    float* q2    = ws + Q2;

    // 1. combined biases
    bias_sum_kernel<<<8, 256, 0, stream>>>(bihF, bhhF, bihB, bhhB, bsum);

    // 2. LSTM input projections: pre = x @ Wih^T + (bih+bhh)
    launch_gemm(1, 0, x, WihF, bsum,        preF, NB * NS, 1024, ND, ND, stream);
    launch_gemm(1, 0, x, WihB, bsum + 1024, preB, NB * NS, 1024, ND, ND, stream);

    // 3. recurrence → features
    lstm_rec_kernel<<<32, 256, 0, stream>>>(preF, preB, WhhF, WhhB, feat);

    // 4. query init
    bcast_query_kernel<<<8192, 256, 0, stream>>>(le, query);

    // 5. attention layers
    for (int l = 0; l < 2; ++l) {
        const float* w1l = w1 + (size_t)l * ND * NF;
        const float* b1l = b1 + (size_t)l * NF;
        const float* w2l = w2 + (size_t)l * NF * ND;
        const float* b2l = b2 + (size_t)l * ND;
        const float* gl  = lng + (size_t)l * ND;
        const float* bl  = lnb + (size_t)l * ND;

        if (l == 0) {
            // query identical across batch: self-attn once
            launch_gemm(1, 0, query, query, nullptr, wsc, NH, NH, ND, ND, stream);
            softmax_kernel<<<NH, 256, 0, stream>>>(wsc, NH);
            launch_gemm(0, 0, wsc, query, nullptr, q1s, NH, ND, NH, ND, stream);
            for (int b = 0; b < NB; ++b) {
                const float* Fb = feat + (size_t)b * NS * ND;
                float* q2b = q2 + (size_t)b * NH * ND;
                launch_gemm(1, 0, q1s, Fb, nullptr, s2s, NH, NS, ND, ND, stream);
                softmax_kernel<<<NH, 256, 0, stream>>>(s2s, NS);
                launch_gemm(0, 0, s2s, Fb, nullptr, q2b, NH, ND, NS, ND, stream);
            }
        } else {
            for (int b = 0; b < NB; ++b) {
                const float* Qb = query + (size_t)b * NH * ND;
                const float* Fb = feat + (size_t)b * NS * ND;
                float* q2b = q2 + (size_t)b * NH * ND;
                launch_gemm(1, 0, Qb, Qb, nullptr, wsc, NH, NH, ND, ND, stream);
                softmax_kernel<<<NH, 256, 0, stream>>>(wsc, NH);
                launch_gemm(0, 0, wsc, Qb, nullptr, q1s, NH, ND, NH, ND, stream);
                launch_gemm(1, 0, q1s, Fb, nullptr, s2s, NH, NS, ND, ND, stream);
                softmax_kernel<<<NH, 256, 0, stream>>>(s2s, NS);
                launch_gemm(0, 0, s2s, Fb, nullptr, q2b, NH, ND, NS, ND, stream);
            }
        }

        // FFN, chunked 1024 rows; output overwrites `query`, then LN in place
        for (int c = 0; c < 16; ++c) {
            const float* rows_in = q2 + (size_t)c * 1024 * ND;
            float* rows_out      = query + (size_t)c * 1024 * ND;
            launch_gemm(0, 1, rows_in, w1l, b1l, ffh, 1024, NF, ND, NF, stream);
            launch_gemm(0, 0, ffh, w2l, b2l, rows_out, 1024, ND, NF, ND, stream);
        }
        layernorm_kernel<<<NB * NH, 256, 0, stream>>>(query, gl, bl);
    }

    // 6. final projection
    outproj_kernel<<<4096, 256, 0, stream>>>(query, proj, out);
}

// Round 3
// 9742.227 us; speedup vs baseline: 1.8178x; 1.8178x over previous
//
#include <hip/hip_runtime.h>
#include <hip/hip_bf16.h>
#include <math.h>

// Problem dims
#define NB 16
#define NS 256
#define ND 512
#define NH 1024
#define NF 2048
#define NHID 256

typedef __attribute__((ext_vector_type(8))) short bf16x8;
typedef __attribute__((ext_vector_type(4))) float f32x4;

__device__ __forceinline__ unsigned short f2bf(float f) {
    unsigned u = __float_as_uint(f);
    unsigned r = u + 0x7fffu + ((u >> 16) & 1u);
    return (unsigned short)(r >> 16);
}
__device__ __forceinline__ float bf2f(unsigned short h) {
    return __uint_as_float(((unsigned)h) << 16);
}

// ---------------------------------------------------------------------------
// Split-bf16 MFMA GEMM: C[M,N] fp32 = A[M,K] @ B[N,K]^T (+bias)(+gelu)
// Operands as hi+lo bf16 pairs; C = Ah*Bh + Al*Bh + Ah*Bl  (~fp32 precision).
// TA_SPLIT=0: A fp32 source, hi/lo computed during staging.
// TA_SPLIT=1: A pre-split (Ahi/Alo bf16 arrays).
// B always pre-split (Bhi/Blo).
// Tile 128x128, BK=32, 256 threads (4 waves, 2x2 of 64x64 per wave).
// LDS rows padded to 40 ushorts (80B). M,N %128==0, K %32==0.
// Batched via blockIdx.z, element strides sA,sB,sC (apply to hi AND lo).
// ---------------------------------------------------------------------------
template<int TA_SPLIT, int ACT>
__global__ __launch_bounds__(256) void sgemm(
    const float* __restrict__ Af,
    const unsigned short* __restrict__ Ahi, const unsigned short* __restrict__ Alo,
    const unsigned short* __restrict__ Bhi, const unsigned short* __restrict__ Blo,
    const float* __restrict__ bias, float* __restrict__ Cp,
    int M, int N, int K, long sA, long sB, long sC)
{
    __shared__ unsigned short Ah[128 * 40];
    __shared__ unsigned short Al[128 * 40];
    __shared__ unsigned short Bh[128 * 40];
    __shared__ unsigned short Bl[128 * 40];

    const int t = threadIdx.x;
    const int z = blockIdx.z;
    const int m0 = blockIdx.y * 128, n0 = blockIdx.x * 128;

    float* C = Cp + (size_t)z * sC;

    const int wid = t >> 6, lane = t & 63;
    const int wr = (wid >> 1) * 64, wc = (wid & 1) * 64;
    const int lr = lane & 15, lk = lane >> 4;

    f32x4 acc[4][4];
    #pragma unroll
    for (int i = 0; i < 4; ++i)
        #pragma unroll
        for (int j = 0; j < 4; ++j) acc[i][j] = (f32x4){0.f, 0.f, 0.f, 0.f};

    const int sr = t >> 1;            // staging row 0..127
    const int sc = (t & 1) * 16;      // staging col elem base (16 elems each)

    for (int k0 = 0; k0 < K; k0 += 32) {
        // ---- stage A hi/lo
        {
            char* dh = (char*)Ah + sr * 80 + sc * 2;
            char* dl = (char*)Al + sr * 80 + sc * 2;
            if (TA_SPLIT) {
                size_t off = (size_t)z * sA + (size_t)(m0 + sr) * K + k0 + sc;
                const unsigned short* shp = Ahi + off;
                const unsigned short* slp = Alo + off;
                *(uint4*)dh = *(const uint4*)(shp);
                *(uint4*)(dh + 16) = *(const uint4*)(shp + 8);
                *(uint4*)dl = *(const uint4*)(slp);
                *(uint4*)(dl + 16) = *(const uint4*)(slp + 8);
            } else {
                const float* src = Af + (size_t)z * sA + (size_t)(m0 + sr) * K + k0 + sc;
                float v[16];
                *(float4*)(v)      = *(const float4*)(src);
                *(float4*)(v + 4)  = *(const float4*)(src + 4);
                *(float4*)(v + 8)  = *(const float4*)(src + 8);
                *(float4*)(v + 12) = *(const float4*)(src + 12);
                unsigned short hh[16], ll[16];
                #pragma unroll
                for (int i = 0; i < 16; ++i) {
                    unsigned short h = f2bf(v[i]);
                    hh[i] = h;
                    ll[i] = f2bf(v[i] - bf2f(h));
                }
                *(uint4*)dh = *(uint4*)hh;
                *(uint4*)(dh + 16) = *(uint4*)(hh + 8);
                *(uint4*)dl = *(uint4*)ll;
                *(uint4*)(dl + 16) = *(uint4*)(ll + 8);
            }
        }
        // ---- stage B hi/lo
        {
            size_t off = (size_t)z * sB + (size_t)(n0 + sr) * K + k0 + sc;
            const unsigned short* shp = Bhi + off;
            const unsigned short* slp = Blo + off;
            char* dh = (char*)Bh + sr * 80 + sc * 2;
            char* dl = (char*)Bl + sr * 80 + sc * 2;
            *(uint4*)dh = *(const uint4*)(shp);
            *(uint4*)(dh + 16) = *(const uint4*)(shp + 8);
            *(uint4*)dl = *(const uint4*)(slp);
            *(uint4*)(dl + 16) = *(const uint4*)(slp + 8);
        }
        __syncthreads();

        bf16x8 ah[4], al[4], bh[4], bl[4];
        #pragma unroll
        for (int mt = 0; mt < 4; ++mt) {
            int r = wr + mt * 16 + lr;
            ah[mt] = *(const bf16x8*)((const char*)Ah + r * 80 + lk * 16);
            al[mt] = *(const bf16x8*)((const char*)Al + r * 80 + lk * 16);
        }
        #pragma unroll
        for (int nt = 0; nt < 4; ++nt) {
            int r = wc + nt * 16 + lr;
            bh[nt] = *(const bf16x8*)((const char*)Bh + r * 80 + lk * 16);
            bl[nt] = *(const bf16x8*)((const char*)Bl + r * 80 + lk * 16);
        }
        #pragma unroll
        for (int mt = 0; mt < 4; ++mt)
            #pragma unroll
            for (int nt = 0; nt < 4; ++nt) {
                acc[mt][nt] = __builtin_amdgcn_mfma_f32_16x16x32_bf16(ah[mt], bh[nt], acc[mt][nt], 0, 0, 0);
                acc[mt][nt] = __builtin_amdgcn_mfma_f32_16x16x32_bf16(al[mt], bh[nt], acc[mt][nt], 0, 0, 0);
                acc[mt][nt] = __builtin_amdgcn_mfma_f32_16x16x32_bf16(ah[mt], bl[nt], acc[mt][nt], 0, 0, 0);
            }
        __syncthreads();
    }

    // epilogue: C/D layout col=lane&15, row=(lane>>4)*4+reg
    #pragma unroll
    for (int nt = 0; nt < 4; ++nt) {
        int col = n0 + wc + nt * 16 + (lane & 15);
        float bv = bias ? bias[col] : 0.0f;
        #pragma unroll
        for (int mt = 0; mt < 4; ++mt) {
            #pragma unroll
            for (int i = 0; i < 4; ++i) {
                int row = m0 + wr + mt * 16 + (lane >> 4) * 4 + i;
                float x = acc[mt][nt][i] + bv;
                if (ACT == 1) x = 0.5f * x * (1.0f + erff(x * 0.70710678118654752f));
                C[(size_t)row * N + col] = x;
            }
        }
    }
}

static void gemm_f32A(int act, const float* A,
                      const unsigned short* Bhi, const unsigned short* Blo,
                      const float* bias, float* C, int M, int N, int K,
                      long sA, long sB, long sC, int Z, hipStream_t st)
{
    dim3 g(N / 128, M / 128, Z), b(256);
    if (act) sgemm<0, 1><<<g, b, 0, st>>>(A, nullptr, nullptr, Bhi, Blo, bias, C, M, N, K, sA, sB, sC);
    else     sgemm<0, 0><<<g, b, 0, st>>>(A, nullptr, nullptr, Bhi, Blo, bias, C, M, N, K, sA, sB, sC);
}

static void gemm_splitA(const unsigned short* Ahi, const unsigned short* Alo,
                        const unsigned short* Bhi, const unsigned short* Blo,
                        const float* bias, float* C, int M, int N, int K,
                        long sA, long sB, long sC, int Z, hipStream_t st)
{
    dim3 g(N / 128, M / 128, Z), b(256);
    sgemm<1, 0><<<g, b, 0, st>>>(nullptr, Ahi, Alo, Bhi, Blo, bias, C, M, N, K, sA, sB, sC);
}

// ---------------------------------------------------------------------------
// fp32 -> split bf16 hi/lo (n multiple of 1024)
// ---------------------------------------------------------------------------
__global__ __launch_bounds__(256) void cvt_split(const float* __restrict__ in,
                                                 unsigned short* __restrict__ hi,
                                                 unsigned short* __restrict__ lo)
{
    size_t i = ((size_t)blockIdx.x * 256 + threadIdx.x) * 4;
    float4 v = *(const float4*)(in + i);
    ushort4 h, l;
    h.x = f2bf(v.x); l.x = f2bf(v.x - bf2f(h.x));
    h.y = f2bf(v.y); l.y = f2bf(v.y - bf2f(h.y));
    h.z = f2bf(v.z); l.z = f2bf(v.z - bf2f(h.z));
    h.w = f2bf(v.w); l.w = f2bf(v.w - bf2f(h.w));
    *(ushort4*)(hi + i) = h;
    *(ushort4*)(lo + i) = l;
}

// ---------------------------------------------------------------------------
// bf16 (R,C) -> (C,R) transpose, z-batched. R,C multiples of 64.
// ---------------------------------------------------------------------------
__global__ __launch_bounds__(256) void tcvt_bf16(const unsigned short* __restrict__ in,
                                                 unsigned short* __restrict__ out,
                                                 int R, int C)
{
    __shared__ unsigned short tile[64 * 72];
    int z = blockIdx.z;
    in += (size_t)z * R * C;
    out += (size_t)z * R * C;
    int r0 = blockIdx.y * 64, c0 = blockIdx.x * 64;
    int t = threadIdx.x;
    int tr = t >> 2, tc = (t & 3) * 16;

    uint4 q0 = *(const uint4*)(in + (size_t)(r0 + tr) * C + c0 + tc);
    uint4 q1 = *(const uint4*)(in + (size_t)(r0 + tr) * C + c0 + tc + 8);
    unsigned short e[16];
    *(uint4*)(e) = q0;
    *(uint4*)(e + 8) = q1;
    #pragma unroll
    for (int i = 0; i < 16; ++i) tile[(tc + i) * 72 + tr] = e[i];
    __syncthreads();

    uint4 o0 = *(const uint4*)(&tile[tr * 72 + tc]);
    uint4 o1 = *(const uint4*)(&tile[tr * 72 + tc + 8]);
    *(uint4*)(out + (size_t)(c0 + tr) * R + r0 + tc) = o0;
    *(uint4*)(out + (size_t)(c0 + tr) * R + r0 + tc + 8) = o1;
}

// ---------------------------------------------------------------------------
// Whh (1024,256) fp32 -> packed fp32 [k8][row][8] for coalesced streaming
// ---------------------------------------------------------------------------
__global__ __launch_bounds__(256) void whh_pack_f32(const float* __restrict__ whh,
                                                    float* __restrict__ out)
{
    int id = blockIdx.x * 256 + threadIdx.x;      // 0..32767
    int k8 = id >> 10, r = id & 1023;
    float4 a = *(const float4*)(whh + (size_t)r * 256 + k8 * 8);
    float4 b = *(const float4*)(whh + (size_t)r * 256 + k8 * 8 + 4);
    ((float4*)out)[(size_t)id * 2]     = a;
    ((float4*)out)[(size_t)id * 2 + 1] = b;
}

// ---------------------------------------------------------------------------
// bias combine
// ---------------------------------------------------------------------------
__global__ __launch_bounds__(256) void bias_sum_kernel(
    const float* bihF, const float* bhhF, const float* bihB, const float* bhhB,
    float* out)
{
    int i = blockIdx.x * 256 + threadIdx.x;
    if (i < 1024) out[i] = bihF[i] + bhhF[i];
    else out[i] = bihB[i - 1024] + bhhB[i - 1024];
}

// ---------------------------------------------------------------------------
// LSTM recurrence, fp32 weights. grid=32 (dir*16+b), block=256.
// Thread t owns unit t: gate rows {t,256+t,512+t,768+t}. Weights packed
// [k8][row][8] fp32 (32B per (k8,row), lane-coalesced as 2x float4).
// Ring-3 prefetch (distance 2). h broadcast via LDS float4.
// Features written as split bf16 (B,S,512): fwd [0:256), bwd [256:512).
// ---------------------------------------------------------------------------
__global__ __launch_bounds__(256) void lstm_rec3(
    const float* __restrict__ preF, const float* __restrict__ preB,
    const float* __restrict__ whhF, const float* __restrict__ whhB,
    unsigned short* __restrict__ fhi, unsigned short* __restrict__ flo)
{
    int blk = blockIdx.x;
    int dir = blk >> 4, b = blk & 15;
    const float* pre = dir ? preB : preF;
    const float4* W = (const float4*)(dir ? whhB : whhF);  // entry (k8*1024+r)*2
    int t = threadIdx.x;

    __shared__ float h_lds[256];
    h_lds[t] = 0.0f;
    float c = 0.0f;
    __syncthreads();

    const int r0 = t, r1 = 256 + t, r2 = 512 + t, r3 = 768 + t;

    for (int si = 0; si < NS; ++si) {
        int s = dir ? (NS - 1 - si) : si;
        const float* prow = pre + ((size_t)(b * NS + s)) * 1024;
        float ai = prow[r0], af = prow[r1], ag = prow[r2], ao = prow[r3];

        float4 buf[3][8];
        #pragma unroll
        for (int p = 0; p < 2; ++p) {
            buf[p][0] = W[(size_t)(p * 1024 + r0) * 2];
            buf[p][1] = W[(size_t)(p * 1024 + r0) * 2 + 1];
            buf[p][2] = W[(size_t)(p * 1024 + r1) * 2];
            buf[p][3] = W[(size_t)(p * 1024 + r1) * 2 + 1];
            buf[p][4] = W[(size_t)(p * 1024 + r2) * 2];
            buf[p][5] = W[(size_t)(p * 1024 + r2) * 2 + 1];
            buf[p][6] = W[(size_t)(p * 1024 + r3) * 2];
            buf[p][7] = W[(size_t)(p * 1024 + r3) * 2 + 1];
        }

        #pragma unroll
        for (int k8 = 0; k8 < 32; ++k8) {
            const int slot = k8 % 3;
            if (k8 + 2 < 32) {
                const int ns = (k8 + 2) % 3;
                const int kb = (k8 + 2) * 1024;
                buf[ns][0] = W[(size_t)(kb + r0) * 2];
                buf[ns][1] = W[(size_t)(kb + r0) * 2 + 1];
                buf[ns][2] = W[(size_t)(kb + r1) * 2];
                buf[ns][3] = W[(size_t)(kb + r1) * 2 + 1];
                buf[ns][4] = W[(size_t)(kb + r2) * 2];
                buf[ns][5] = W[(size_t)(kb + r2) * 2 + 1];
                buf[ns][6] = W[(size_t)(kb + r3) * 2];
                buf[ns][7] = W[(size_t)(kb + r3) * 2 + 1];
            }
            float4 h0 = ((const float4*)h_lds)[k8 * 2];
            float4 h1 = ((const float4*)h_lds)[k8 * 2 + 1];
            #pragma unroll
            for (int r = 0; r < 4; ++r) {
                float4 wa = buf[slot][r * 2];
                float4 wb = buf[slot][r * 2 + 1];
                float acc = wa.x * h0.x + wa.y * h0.y + wa.z * h0.z + wa.w * h0.w
                          + wb.x * h1.x + wb.y * h1.y + wb.z * h1.z + wb.w * h1.w;
                if (r == 0) ai += acc;
                else if (r == 1) af += acc;
                else if (r == 2) ag += acc;
                else ao += acc;
            }
        }

        float gi = 1.0f / (1.0f + expf(-ai));
        float gf = 1.0f / (1.0f + expf(-af));
        float gg = tanhf(ag);
        float go = 1.0f / (1.0f + expf(-ao));
        c = gf * c + gi * gg;
        float h = go * tanhf(c);
        __syncthreads();
        h_lds[t] = h;
        __syncthreads();
        size_t oi = ((size_t)(b * NS + s)) * 512 + dir * 256 + t;
        unsigned short hh = f2bf(h);
        fhi[oi] = hh;
        flo[oi] = f2bf(h - bf2f(hh));
    }
}

// ---------------------------------------------------------------------------
// row softmax in place: grid = rows, block = 256
// ---------------------------------------------------------------------------
__global__ __launch_bounds__(256) void softmax_kernel(float* __restrict__ X, int N)
{
    float* row = X + (size_t)blockIdx.x * N;
    int t = threadIdx.x;
    float m = -1e30f;
    for (int j = t; j < N; j += 256) m = fmaxf(m, row[j]);
    for (int o = 32; o; o >>= 1) m = fmaxf(m, __shfl_xor(m, o));
    __shared__ float lm[4];
    if ((t & 63) == 0) lm[t >> 6] = m;
    __syncthreads();
    m = fmaxf(fmaxf(lm[0], lm[1]), fmaxf(lm[2], lm[3]));
    float s = 0.0f;
    for (int j = t; j < N; j += 256) { float e = expf(row[j] - m); row[j] = e; s += e; }
    for (int o = 32; o; o >>= 1) s += __shfl_xor(s, o);
    __shared__ float ls[4];
    if ((t & 63) == 0) ls[t >> 6] = s;
    __syncthreads();
    s = ls[0] + ls[1] + ls[2] + ls[3];
    float inv = 1.0f / s;
    for (int j = t; j < N; j += 256) row[j] *= inv;
}

// ---------------------------------------------------------------------------
// LayerNorm rows of 512 fp32 -> split bf16 out. grid = rows, block = 256.
// ---------------------------------------------------------------------------
__global__ __launch_bounds__(256) void layernorm_split(
    const float* __restrict__ X, const float* __restrict__ g, const float* __restrict__ b,
    unsigned short* __restrict__ ohi, unsigned short* __restrict__ olo)
{
    const float* row = X + (size_t)blockIdx.x * 512;
    size_t ob = (size_t)blockIdx.x * 512;
    int t = threadIdx.x;
    float x0 = row[t], x1 = row[t + 256];
    float s = x0 + x1, sq = x0 * x0 + x1 * x1;
    for (int o = 32; o; o >>= 1) { s += __shfl_xor(s, o); sq += __shfl_xor(sq, o); }
    __shared__ float ls[8];
    int w = t >> 6;
    if ((t & 63) == 0) { ls[w] = s; ls[4 + w] = sq; }
    __syncthreads();
    s = ls[0] + ls[1] + ls[2] + ls[3];
    sq = ls[4] + ls[5] + ls[6] + ls[7];
    float mu = s * (1.0f / 512.0f);
    float var = sq * (1.0f / 512.0f) - mu * mu;
    float inv = rsqrtf(var + 1e-5f);
    float y0 = (x0 - mu) * inv * g[t]       + b[t];
    float y1 = (x1 - mu) * inv * g[t + 256] + b[t + 256];
    unsigned short h0 = f2bf(y0), h1 = f2bf(y1);
    ohi[ob + t]       = h0;  olo[ob + t]       = f2bf(y0 - bf2f(h0));
    ohi[ob + t + 256] = h1;  olo[ob + t + 256] = f2bf(y1 - bf2f(h1));
}

// ---------------------------------------------------------------------------
// out[b,h] = dot(q[b,h,:], projT[h,:]) with hi+lo reconstruction
// ---------------------------------------------------------------------------
__global__ __launch_bounds__(256) void outproj3(
    const unsigned short* __restrict__ qhi, const unsigned short* __restrict__ qlo,
    const unsigned short* __restrict__ phi, const unsigned short* __restrict__ plo,
    float* __restrict__ out)
{
    int gw = blockIdx.x * 4 + (threadIdx.x >> 6);  // b*1024+h
    int lane = threadIdx.x & 63;
    int h = gw & 1023;
    uint4 qh = ((const uint4*)(qhi + (size_t)gw * 512))[lane];
    uint4 ql = ((const uint4*)(qlo + (size_t)gw * 512))[lane];
    uint4 ph = ((const uint4*)(phi + (size_t)h * 512))[lane];
    uint4 pl = ((const uint4*)(plo + (size_t)h * 512))[lane];
    unsigned short qhe[8], qle[8], phe[8], ple[8];
    *(uint4*)qhe = qh; *(uint4*)qle = ql; *(uint4*)phe = ph; *(uint4*)ple = pl;
    float s = 0.0f;
    #pragma unroll
    for (int i = 0; i < 8; ++i) {
        float q = bf2f(qhe[i]) + bf2f(qle[i]);
        float p = bf2f(phe[i]) + bf2f(ple[i]);
        s += q * p;
    }
    for (int o = 32; o; o >>= 1) s += __shfl_xor(s, o);
    if (lane == 0) out[gw] = s;
}

// ---------------------------------------------------------------------------
// launcher
// ---------------------------------------------------------------------------
extern "C" void kernel_launch(void* const* d_in, const int* in_sizes, int n_in,
                              void* d_out, int out_size, void* d_ws, size_t ws_size,
                              hipStream_t stream)
{
    (void)in_sizes; (void)n_in; (void)out_size; (void)ws_size;

    const float* x     = (const float*)d_in[0];   // (16,256,512)
    const float* le    = (const float*)d_in[1];   // (1024,512)
    const float* proj  = (const float*)d_in[2];   // (512,1024)
    const float* WihF  = (const float*)d_in[3];   // (1024,512)
    const float* WhhF  = (const float*)d_in[4];   // (1024,256)
    const float* bihF  = (const float*)d_in[5];
    const float* bhhF  = (const float*)d_in[6];
    const float* WihB  = (const float*)d_in[7];
    const float* WhhB  = (const float*)d_in[8];
    const float* bihB  = (const float*)d_in[9];
    const float* bhhB  = (const float*)d_in[10];
    const float* w1    = (const float*)d_in[11];  // (2,512,2048)
    const float* b1    = (const float*)d_in[12];  // (2,2048)
    const float* w2    = (const float*)d_in[13];  // (2,2048,512)
    const float* b2    = (const float*)d_in[14];  // (2,512)
    const float* lng   = (const float*)d_in[15];  // (2,512)
    const float* lnb   = (const float*)d_in[16];  // (2,512)
    float* out = (float*)d_out;
    float* ws  = (float*)d_ws;
    unsigned short* wsu = (unsigned short*)d_ws;

    const size_t MEG = 1048576;
    // float-offset layout (total ~42M floats = 168MB)
    const size_t LNSRC = 0;              // 8M: preF/preB -> qt hi/lo (L1 attn) -> FFN2 out
    const size_t HB    = 8 * MEG;        // 8M: attn value output q2attn fp32
    const size_t AR    = 16 * MEG;       // 8M: wsc/q1s/s2s scratch; ffh
    const size_t QHI   = 24 * MEG;       // 4M fl (8M elems bf16)
    const size_t QLO   = 28 * MEG;
    const size_t FHI   = 32 * MEG;       // 1M fl
    const size_t FLO   = 33 * MEG;
    const size_t FTHI  = 34 * MEG;
    const size_t FTLO  = 35 * MEG;
    const size_t LEHI  = 36 * MEG;                 // .25M fl
    const size_t LELO  = LEHI  + MEG / 4;
    const size_t LETHI = LELO  + MEG / 4;
    const size_t LETLO = LETHI + MEG / 4;
    const size_t WIHFH = LETLO + MEG / 4;
    const size_t WIHFL = WIHFH + MEG / 4;
    const size_t WIHBH = WIHFL + MEG / 4;
    const size_t WIHBL = WIHBH + MEG / 4;
    const size_t WHHF  = WIHBL + MEG / 4;          // .25M fl fp32 packed
    const size_t WHHB  = WHHF  + MEG / 4;
    const size_t W1TH  = WHHB  + MEG / 4;          // .5M fl (1M elems)
    const size_t W1TL  = W1TH  + MEG / 2;
    const size_t W2TH  = W1TL  + MEG / 2;
    const size_t W2TL  = W2TH  + MEG / 2;
    const size_t WTH   = W2TL  + MEG / 2;          // .5M fl tmp
    const size_t WTL   = WTH   + MEG / 2;
    const size_t PTH   = WTL   + MEG / 2;          // .25M fl
    const size_t PTL   = PTH   + MEG / 4;
    const size_t BSUM  = PTL   + MEG / 4;

    float* preF   = ws + LNSRC;
    float* preB   = ws + LNSRC + 4 * MEG;
    float* lnsrc  = ws + LNSRC;
    float* q2a    = ws + HB;
    float* arena  = ws + AR;
    float* bsum   = ws + BSUM;
    float* whhFp  = ws + WHHF;
    float* whhBp  = ws + WHHB;
    unsigned short* qthi  = wsu + 2 * LNSRC;            // alias (layer-1 attn only)
    unsigned short* qtlo  = wsu + 2 * (LNSRC + 4 * MEG);
    unsigned short* qhi   = wsu + 2 * QHI;
    unsigned short* qlo   = wsu + 2 * QLO;
    unsigned short* fhi   = wsu + 2 * FHI;
    unsigned short* flo   = wsu + 2 * FLO;
    unsigned short* fthi  = wsu + 2 * FTHI;
    unsigned short* ftlo  = wsu + 2 * FTLO;
    unsigned short* lehi  = wsu + 2 * LEHI;
    unsigned short* lelo  = wsu + 2 * LELO;
    unsigned short* lethi = wsu + 2 * LETHI;
    unsigned short* letlo = wsu + 2 * LETLO;
    unsigned short* wihFh = wsu + 2 * WIHFH;
    unsigned short* wihFl = wsu + 2 * WIHFL;
    unsigned short* wihBh = wsu + 2 * WIHBH;
    unsigned short* wihBl = wsu + 2 * WIHBL;
    unsigned short* w1th  = wsu + 2 * W1TH;
    unsigned short* w1tl  = wsu + 2 * W1TL;
    unsigned short* w2th  = wsu + 2 * W2TH;
    unsigned short* w2tl  = wsu + 2 * W2TL;
    unsigned short* wth   = wsu + 2 * WTH;
    unsigned short* wtl   = wsu + 2 * WTL;
    unsigned short* pth   = wsu + 2 * PTH;
    unsigned short* ptl   = wsu + 2 * PTL;

    // ---- prep
    bias_sum_kernel<<<8, 256, 0, stream>>>(bihF, bhhF, bihB, bhhB, bsum);
    cvt_split<<<512, 256, 0, stream>>>(WihF, wihFh, wihFl);
    cvt_split<<<512, 256, 0, stream>>>(WihB, wihBh, wihBl);
    whh_pack_f32<<<128, 256, 0, stream>>>(WhhF, whhFp);
    whh_pack_f32<<<128, 256, 0, stream>>>(WhhB, whhBp);
    cvt_split<<<512, 256, 0, stream>>>(le, lehi, lelo);
    { dim3 g(512 / 64, 1024 / 64, 1);
      tcvt_bf16<<<g, 256, 0, stream>>>(lehi, lethi, 1024, 512);
      tcvt_bf16<<<g, 256, 0, stream>>>(lelo, letlo, 1024, 512); }

    // ---- LSTM input projections: pre = x @ Wih^T + (bih+bhh)
    gemm_f32A(0, x, wihFh, wihFl, bsum,        preF, NB * NS, 1024, ND, 0, 0, 0, 1, stream);
    gemm_f32A(0, x, wihBh, wihBl, bsum + 1024, preB, NB * NS, 1024, ND, 0, 0, 0, 1, stream);

    // ---- recurrence -> features (split bf16)
    lstm_rec3<<<32, 256, 0, stream>>>(preF, preB, whhFp, whhBp, fhi, flo);
    { dim3 g(512 / 64, 256 / 64, 16);
      tcvt_bf16<<<g, 256, 0, stream>>>(fhi, fthi, 256, 512);
      tcvt_bf16<<<g, 256, 0, stream>>>(flo, ftlo, 256, 512); }

    // ---- layers
    for (int l = 0; l < 2; ++l) {
        const float* b1l = b1 + (size_t)l * NF;
        const float* b2l = b2 + (size_t)l * ND;
        const float* gl  = lng + (size_t)l * ND;
        const float* bl  = lnb + (size_t)l * ND;

        // FFN weights -> split bf16, transposed
        cvt_split<<<1024, 256, 0, stream>>>(w1 + (size_t)l * ND * NF, wth, wtl);   // (512,2048)
        { dim3 g(NF / 64, ND / 64, 1);
          tcvt_bf16<<<g, 256, 0, stream>>>(wth, w1th, ND, NF);
          tcvt_bf16<<<g, 256, 0, stream>>>(wtl, w1tl, ND, NF); }                   // (2048,512)
        cvt_split<<<1024, 256, 0, stream>>>(w2 + (size_t)l * NF * ND, wth, wtl);   // (2048,512)
        { dim3 g(ND / 64, NF / 64, 1);
          tcvt_bf16<<<g, 256, 0, stream>>>(wth, w2th, NF, ND);
          tcvt_bf16<<<g, 256, 0, stream>>>(wtl, w2tl, NF, ND); }                   // (512,2048)

        if (l == 0) {
            // query identical across batch: shared self-attn + q1
            float* wsc = arena;                  // 1M (1024,1024)
            float* q1s = arena + MEG;            // .5M (1024,512)
            float* s2s = arena + 2 * MEG;        // 4M (16,1024,256)
            gemm_f32A(0, le, lehi, lelo, nullptr, wsc, NH, NH, ND, 0, 0, 0, 1, stream);
            softmax_kernel<<<NH, 256, 0, stream>>>(wsc, NH);
            gemm_f32A(0, wsc, lethi, letlo, nullptr, q1s, NH, ND, NH, 0, 0, 0, 1, stream);
            gemm_f32A(0, q1s, fhi, flo, nullptr, s2s, NH, NS, ND,
                      0, (long)NS * ND, (long)NH * NS, 16, stream);
            softmax_kernel<<<NB * NH, 256, 0, stream>>>(s2s, NS);
            gemm_f32A(0, s2s, fthi, ftlo, nullptr, q2a, NH, ND, NS,
                      (long)NH * NS, (long)ND * NS, (long)NH * ND, 16, stream);
        } else {
            { dim3 g(512 / 64, 1024 / 64, 16);
              tcvt_bf16<<<g, 256, 0, stream>>>(qhi, qthi, 1024, 512);
              tcvt_bf16<<<g, 256, 0, stream>>>(qlo, qtlo, 1024, 512); }
            float* wsc4 = arena;                 // 4M (4,1024,1024)
            float* q1s4 = arena + 4 * MEG;       // 2M (4,1024,512)
            float* s2s4 = arena + 6 * MEG;       // 1M (4,1024,256)
            for (int g4 = 0; g4 < 4; ++g4) {
                size_t qo = (size_t)g4 * 4;
                gemm_splitA(qhi + qo * NH * ND, qlo + qo * NH * ND,
                            qhi + qo * NH * ND, qlo + qo * NH * ND,
                            nullptr, wsc4, NH, NH, ND,
                            (long)NH * ND, (long)NH * ND, (long)NH * NH, 4, stream);
                softmax_kernel<<<4 * NH, 256, 0, stream>>>(wsc4, NH);
                gemm_f32A(0, wsc4, qthi + qo * ND * NH, qtlo + qo * ND * NH,
                          nullptr, q1s4, NH, ND, NH,
                          (long)NH * NH, (long)ND * NH, (long)NH * ND, 4, stream);
                gemm_f32A(0, q1s4, fhi + qo * NS * ND, flo + qo * NS * ND,
                          nullptr, s2s4, NH, NS, ND,
                          (long)NH * ND, (long)NS * ND, (long)NH * NS, 4, stream);
                softmax_kernel<<<4 * NH, 256, 0, stream>>>(s2s4, NS);
                gemm_f32A(0, s2s4, fthi + qo * ND * NS, ftlo + qo * ND * NS,
                          nullptr, q2a + qo * NH * ND, NH, ND, NS,
                          (long)NH * NS, (long)ND * NS, (long)NH * ND, 4, stream);
            }
        }

        // FFN: 4 chunks of 4096 rows; q2a -> ffh(arena) -> lnsrc
        float* ffh = arena;
        for (int ch = 0; ch < 4; ++ch) {
            const float* rows_in = q2a + (size_t)ch * 4096 * ND;
            float* rows_out      = lnsrc + (size_t)ch * 4096 * ND;
            gemm_f32A(1, rows_in, w1th, w1tl, b1l, ffh, 4096, NF, ND, 0, 0, 0, 1, stream);
            gemm_f32A(0, ffh, w2th, w2tl, b2l, rows_out, 4096, ND, NF, 0, 0, 0, 1, stream);
        }
        layernorm_split<<<NB * NH, 256, 0, stream>>>(lnsrc, gl, bl, qhi, qlo);
    }

    // ---- final projection
    cvt_split<<<512, 256, 0, stream>>>(proj, wth, wtl);                    // (512,1024)
    { dim3 g(1024 / 64, 512 / 64, 1);
      tcvt_bf16<<<g, 256, 0, stream>>>(wth, pth, 512, 1024);
      tcvt_bf16<<<g, 256, 0, stream>>>(wtl, ptl, 512, 1024); }             // (1024,512)
    outproj3<<<4096, 256, 0, stream>>>(qhi, qlo, pth, ptl, out);
}

// Round 4
// 5852.253 us; speedup vs baseline: 3.0261x; 1.6647x over previous
//
#include <hip/hip_runtime.h>
#include <hip/hip_bf16.h>
#include <math.h>

// Problem dims
#define NB 16
#define NS 256
#define ND 512
#define NH 1024
#define NF 2048
#define NHID 256

typedef __attribute__((ext_vector_type(8))) short bf16x8;
typedef __attribute__((ext_vector_type(4))) float f32x4;

__device__ __forceinline__ unsigned short f2bf(float f) {
    unsigned u = __float_as_uint(f);
    unsigned r = u + 0x7fffu + ((u >> 16) & 1u);
    return (unsigned short)(r >> 16);
}
__device__ __forceinline__ float bf2f(unsigned short h) {
    return __uint_as_float(((unsigned)h) << 16);
}

// ---------------------------------------------------------------------------
// Split-bf16 MFMA GEMM: C[M,N] fp32 = A[M,K] @ B[N,K]^T (+bias)(+gelu)
// Operands as hi+lo bf16 pairs; C = Ah*Bh + Al*Bh + Ah*Bl  (~fp32 precision).
// ---------------------------------------------------------------------------
template<int TA_SPLIT, int ACT>
__global__ __launch_bounds__(256) void sgemm(
    const float* __restrict__ Af,
    const unsigned short* __restrict__ Ahi, const unsigned short* __restrict__ Alo,
    const unsigned short* __restrict__ Bhi, const unsigned short* __restrict__ Blo,
    const float* __restrict__ bias, float* __restrict__ Cp,
    int M, int N, int K, long sA, long sB, long sC)
{
    __shared__ unsigned short Ah[128 * 40];
    __shared__ unsigned short Al[128 * 40];
    __shared__ unsigned short Bh[128 * 40];
    __shared__ unsigned short Bl[128 * 40];

    const int t = threadIdx.x;
    const int z = blockIdx.z;
    const int m0 = blockIdx.y * 128, n0 = blockIdx.x * 128;

    float* C = Cp + (size_t)z * sC;

    const int wid = t >> 6, lane = t & 63;
    const int wr = (wid >> 1) * 64, wc = (wid & 1) * 64;
    const int lr = lane & 15, lk = lane >> 4;

    f32x4 acc[4][4];
    #pragma unroll
    for (int i = 0; i < 4; ++i)
        #pragma unroll
        for (int j = 0; j < 4; ++j) acc[i][j] = (f32x4){0.f, 0.f, 0.f, 0.f};

    const int sr = t >> 1;            // staging row 0..127
    const int sc = (t & 1) * 16;      // staging col elem base (16 elems each)

    for (int k0 = 0; k0 < K; k0 += 32) {
        // ---- stage A hi/lo
        {
            char* dh = (char*)Ah + sr * 80 + sc * 2;
            char* dl = (char*)Al + sr * 80 + sc * 2;
            if (TA_SPLIT) {
                size_t off = (size_t)z * sA + (size_t)(m0 + sr) * K + k0 + sc;
                const unsigned short* shp = Ahi + off;
                const unsigned short* slp = Alo + off;
                *(uint4*)dh = *(const uint4*)(shp);
                *(uint4*)(dh + 16) = *(const uint4*)(shp + 8);
                *(uint4*)dl = *(const uint4*)(slp);
                *(uint4*)(dl + 16) = *(const uint4*)(slp + 8);
            } else {
                const float* src = Af + (size_t)z * sA + (size_t)(m0 + sr) * K + k0 + sc;
                float v[16];
                *(float4*)(v)      = *(const float4*)(src);
                *(float4*)(v + 4)  = *(const float4*)(src + 4);
                *(float4*)(v + 8)  = *(const float4*)(src + 8);
                *(float4*)(v + 12) = *(const float4*)(src + 12);
                unsigned short hh[16], ll[16];
                #pragma unroll
                for (int i = 0; i < 16; ++i) {
                    unsigned short h = f2bf(v[i]);
                    hh[i] = h;
                    ll[i] = f2bf(v[i] - bf2f(h));
                }
                *(uint4*)dh = *(uint4*)hh;
                *(uint4*)(dh + 16) = *(uint4*)(hh + 8);
                *(uint4*)dl = *(uint4*)ll;
                *(uint4*)(dl + 16) = *(uint4*)(ll + 8);
            }
        }
        // ---- stage B hi/lo
        {
            size_t off = (size_t)z * sB + (size_t)(n0 + sr) * K + k0 + sc;
            const unsigned short* shp = Bhi + off;
            const unsigned short* slp = Blo + off;
            char* dh = (char*)Bh + sr * 80 + sc * 2;
            char* dl = (char*)Bl + sr * 80 + sc * 2;
            *(uint4*)dh = *(const uint4*)(shp);
            *(uint4*)(dh + 16) = *(const uint4*)(shp + 8);
            *(uint4*)dl = *(const uint4*)(slp);
            *(uint4*)(dl + 16) = *(const uint4*)(slp + 8);
        }
        __syncthreads();

        bf16x8 ah[4], al[4], bh[4], bl[4];
        #pragma unroll
        for (int mt = 0; mt < 4; ++mt) {
            int r = wr + mt * 16 + lr;
            ah[mt] = *(const bf16x8*)((const char*)Ah + r * 80 + lk * 16);
            al[mt] = *(const bf16x8*)((const char*)Al + r * 80 + lk * 16);
        }
        #pragma unroll
        for (int nt = 0; nt < 4; ++nt) {
            int r = wc + nt * 16 + lr;
            bh[nt] = *(const bf16x8*)((const char*)Bh + r * 80 + lk * 16);
            bl[nt] = *(const bf16x8*)((const char*)Bl + r * 80 + lk * 16);
        }
        #pragma unroll
        for (int mt = 0; mt < 4; ++mt)
            #pragma unroll
            for (int nt = 0; nt < 4; ++nt) {
                acc[mt][nt] = __builtin_amdgcn_mfma_f32_16x16x32_bf16(ah[mt], bh[nt], acc[mt][nt], 0, 0, 0);
                acc[mt][nt] = __builtin_amdgcn_mfma_f32_16x16x32_bf16(al[mt], bh[nt], acc[mt][nt], 0, 0, 0);
                acc[mt][nt] = __builtin_amdgcn_mfma_f32_16x16x32_bf16(ah[mt], bl[nt], acc[mt][nt], 0, 0, 0);
            }
        __syncthreads();
    }

    // epilogue: C/D layout col=lane&15, row=(lane>>4)*4+reg
    #pragma unroll
    for (int nt = 0; nt < 4; ++nt) {
        int col = n0 + wc + nt * 16 + (lane & 15);
        float bv = bias ? bias[col] : 0.0f;
        #pragma unroll
        for (int mt = 0; mt < 4; ++mt) {
            #pragma unroll
            for (int i = 0; i < 4; ++i) {
                int row = m0 + wr + mt * 16 + (lane >> 4) * 4 + i;
                float x = acc[mt][nt][i] + bv;
                if (ACT == 1) x = 0.5f * x * (1.0f + erff(x * 0.70710678118654752f));
                C[(size_t)row * N + col] = x;
            }
        }
    }
}

static void gemm_f32A(int act, const float* A,
                      const unsigned short* Bhi, const unsigned short* Blo,
                      const float* bias, float* C, int M, int N, int K,
                      long sA, long sB, long sC, int Z, hipStream_t st)
{
    dim3 g(N / 128, M / 128, Z), b(256);
    if (act) sgemm<0, 1><<<g, b, 0, st>>>(A, nullptr, nullptr, Bhi, Blo, bias, C, M, N, K, sA, sB, sC);
    else     sgemm<0, 0><<<g, b, 0, st>>>(A, nullptr, nullptr, Bhi, Blo, bias, C, M, N, K, sA, sB, sC);
}

static void gemm_splitA(const unsigned short* Ahi, const unsigned short* Alo,
                        const unsigned short* Bhi, const unsigned short* Blo,
                        const float* bias, float* C, int M, int N, int K,
                        long sA, long sB, long sC, int Z, hipStream_t st)
{
    dim3 g(N / 128, M / 128, Z), b(256);
    sgemm<1, 0><<<g, b, 0, st>>>(nullptr, Ahi, Alo, Bhi, Blo, bias, C, M, N, K, sA, sB, sC);
}

// ---------------------------------------------------------------------------
// fp32 -> split bf16 hi/lo (n multiple of 1024)
// ---------------------------------------------------------------------------
__global__ __launch_bounds__(256) void cvt_split(const float* __restrict__ in,
                                                 unsigned short* __restrict__ hi,
                                                 unsigned short* __restrict__ lo)
{
    size_t i = ((size_t)blockIdx.x * 256 + threadIdx.x) * 4;
    float4 v = *(const float4*)(in + i);
    ushort4 h, l;
    h.x = f2bf(v.x); l.x = f2bf(v.x - bf2f(h.x));
    h.y = f2bf(v.y); l.y = f2bf(v.y - bf2f(h.y));
    h.z = f2bf(v.z); l.z = f2bf(v.z - bf2f(h.z));
    h.w = f2bf(v.w); l.w = f2bf(v.w - bf2f(h.w));
    *(ushort4*)(hi + i) = h;
    *(ushort4*)(lo + i) = l;
}

// ---------------------------------------------------------------------------
// bf16 (R,C) -> (C,R) transpose, z-batched. R,C multiples of 64.
// ---------------------------------------------------------------------------
__global__ __launch_bounds__(256) void tcvt_bf16(const unsigned short* __restrict__ in,
                                                 unsigned short* __restrict__ out,
                                                 int R, int C)
{
    __shared__ unsigned short tile[64 * 72];
    int z = blockIdx.z;
    in += (size_t)z * R * C;
    out += (size_t)z * R * C;
    int r0 = blockIdx.y * 64, c0 = blockIdx.x * 64;
    int t = threadIdx.x;
    int tr = t >> 2, tc = (t & 3) * 16;

    uint4 q0 = *(const uint4*)(in + (size_t)(r0 + tr) * C + c0 + tc);
    uint4 q1 = *(const uint4*)(in + (size_t)(r0 + tr) * C + c0 + tc + 8);
    unsigned short e[16];
    *(uint4*)(e) = q0;
    *(uint4*)(e + 8) = q1;
    #pragma unroll
    for (int i = 0; i < 16; ++i) tile[(tc + i) * 72 + tr] = e[i];
    __syncthreads();

    uint4 o0 = *(const uint4*)(&tile[tr * 72 + tc]);
    uint4 o1 = *(const uint4*)(&tile[tr * 72 + tc + 8]);
    *(uint4*)(out + (size_t)(c0 + tr) * R + r0 + tc) = o0;
    *(uint4*)(out + (size_t)(c0 + tr) * R + r0 + tc + 8) = o1;
}

// ---------------------------------------------------------------------------
// bias combine
// ---------------------------------------------------------------------------
__global__ __launch_bounds__(256) void bias_sum_kernel(
    const float* bihF, const float* bhhF, const float* bihB, const float* bhhB,
    float* out)
{
    int i = blockIdx.x * 256 + threadIdx.x;
    if (i < 1024) out[i] = bihF[i] + bhhF[i];
    else out[i] = bihB[i - 1024] + bhhB[i - 1024];
}

// ---------------------------------------------------------------------------
// LSTM recurrence v4: cross-CU cooperative.
// grid = 32 blocks (dir = bid>>4, slice = bid&15), block = 512 threads.
// Each block owns 16 units (slice*16..+16) of one direction; its 64 gate rows
// (64KB fp32) live in LDS for the whole kernel. Per step it computes
// 16 units x 16 batches, then all 32 blocks exchange h through a
// parity-double-buffered global buffer with a device-scope flag barrier.
// Thread decode: ul = tid>>5 (unit), b = (tid>>1)&15 (batch), kh = tid&1
// (K half, 128 each); kh pair combines via shfl_xor(1).
// Weights LDS padded to 260 floats/row -> 2-way bank conflicts only (free).
// ---------------------------------------------------------------------------
__global__ __launch_bounds__(512) void lstm_rec4(
    const float* __restrict__ preF, const float* __restrict__ preB,
    const float* __restrict__ WhhF, const float* __restrict__ WhhB,
    float* __restrict__ hg,      // [parity2][dir2][16b][256u] fp32
    int* __restrict__ flags,     // [32], zeroed before launch
    unsigned short* __restrict__ fhi, unsigned short* __restrict__ flo)
{
    const int bid = blockIdx.x;
    const int dir = bid >> 4;
    const int slice = bid & 15;
    const float* pre = dir ? preB : preF;
    const float* Whh = dir ? WhhB : WhhF;

    const int tid = threadIdx.x;
    const int ul = tid >> 5;          // 0..15
    const int b  = (tid >> 1) & 15;   // 0..15
    const int kh = tid & 1;           // 0..1
    const int ug = slice * 16 + ul;   // global unit

    __shared__ float wl[64 * 260];    // [g*16+ul][260]
    __shared__ float hl[16 * 260];    // [b][260]

    // one-time: load this slice's 64 gate rows into LDS
    for (int i = tid; i < 64 * 64; i += 512) {        // 64 rows x 64 float4
        int r = i >> 6, c4 = i & 63;
        int srow = (r >> 4) * 256 + slice * 16 + (r & 15);
        float4 v = *(const float4*)(Whh + (size_t)srow * 256 + c4 * 4);
        *(float4*)&wl[r * 260 + c4 * 4] = v;
    }
    for (int i = tid; i < 16 * 260; i += 512) hl[i] = 0.0f;   // h_{-1} = 0

    float c = 0.0f;                   // cell state (both kh lanes redundant)
    __syncthreads();

    const int kbase = kh * 128;
    const float* hrow = &hl[b * 260 + kbase];
    const float* wi = &wl[(0 * 16 + ul) * 260 + kbase];
    const float* wf = &wl[(1 * 16 + ul) * 260 + kbase];
    const float* wg = &wl[(2 * 16 + ul) * 260 + kbase];
    const float* wo = &wl[(3 * 16 + ul) * 260 + kbase];

    for (int si = 0; si < NS; ++si) {
        const int s = dir ? (NS - 1 - si) : si;
        // issue pre loads before the barrier wait (latency hides under spin)
        const float* prow = pre + ((size_t)(b * NS + s)) * 1024 + ug;
        float pi = prow[0], pf = prow[256], pg = prow[512], po = prow[768];

        if (si > 0) {
            if (tid < 64) {
                while (__hip_atomic_load(&flags[tid & 31], __ATOMIC_RELAXED,
                                         __HIP_MEMORY_SCOPE_AGENT) < si) {
                    __builtin_amdgcn_s_sleep(2);
                }
            }
            __syncthreads();
            __threadfence();          // acquire: invalidate stale cached h
            const float* src = hg + (size_t)(((si - 1) & 1) * 2 + dir) * (16 * 256);
            for (int i = tid; i < 16 * 256; i += 512)
                hl[(i >> 8) * 260 + (i & 255)] = src[i];
            __syncthreads();
        }

        float ai = 0.f, af = 0.f, ag = 0.f, ao = 0.f;
        #pragma unroll
        for (int k4 = 0; k4 < 32; ++k4) {
            float4 h4 = *(const float4*)(hrow + k4 * 4);
            float4 a  = *(const float4*)(wi + k4 * 4);
            float4 f  = *(const float4*)(wf + k4 * 4);
            float4 g  = *(const float4*)(wg + k4 * 4);
            float4 o  = *(const float4*)(wo + k4 * 4);
            ai += a.x * h4.x + a.y * h4.y + a.z * h4.z + a.w * h4.w;
            af += f.x * h4.x + f.y * h4.y + f.z * h4.z + f.w * h4.w;
            ag += g.x * h4.x + g.y * h4.y + g.z * h4.z + g.w * h4.w;
            ao += o.x * h4.x + o.y * h4.y + o.z * h4.z + o.w * h4.w;
        }
        // combine K halves (partner lane tid^1); both lanes end identical
        ai += __shfl_xor(ai, 1);  af += __shfl_xor(af, 1);
        ag += __shfl_xor(ag, 1);  ao += __shfl_xor(ao, 1);
        ai += pi; af += pf; ag += pg; ao += po;

        float gi = 1.0f / (1.0f + expf(-ai));
        float gf = 1.0f / (1.0f + expf(-af));
        float gg = tanhf(ag);
        float go = 1.0f / (1.0f + expf(-ao));
        c = gf * c + gi * gg;
        float h = go * tanhf(c);

        if (kh == 0) {
            float* dst = hg + (size_t)((si & 1) * 2 + dir) * (16 * 256);
            dst[b * 256 + ug] = h;
            size_t oi = ((size_t)(b * NS + s)) * 512 + dir * 256 + ug;
            unsigned short hh = f2bf(h);
            fhi[oi] = hh;
            flo[oi] = f2bf(h - bf2f(hh));
        }
        __syncthreads();              // all stores in block issued
        __threadfence();              // release: flush h to coherence point
        if (tid == 0)
            __hip_atomic_store(&flags[bid], si + 1, __ATOMIC_RELAXED,
                               __HIP_MEMORY_SCOPE_AGENT);
    }
}

// ---------------------------------------------------------------------------
// row softmax in place: grid = rows, block = 256
// ---------------------------------------------------------------------------
__global__ __launch_bounds__(256) void softmax_kernel(float* __restrict__ X, int N)
{
    float* row = X + (size_t)blockIdx.x * N;
    int t = threadIdx.x;
    float m = -1e30f;
    for (int j = t; j < N; j += 256) m = fmaxf(m, row[j]);
    for (int o = 32; o; o >>= 1) m = fmaxf(m, __shfl_xor(m, o));
    __shared__ float lm[4];
    if ((t & 63) == 0) lm[t >> 6] = m;
    __syncthreads();
    m = fmaxf(fmaxf(lm[0], lm[1]), fmaxf(lm[2], lm[3]));
    float s = 0.0f;
    for (int j = t; j < N; j += 256) { float e = expf(row[j] - m); row[j] = e; s += e; }
    for (int o = 32; o; o >>= 1) s += __shfl_xor(s, o);
    __shared__ float ls[4];
    if ((t & 63) == 0) ls[t >> 6] = s;
    __syncthreads();
    s = ls[0] + ls[1] + ls[2] + ls[3];
    float inv = 1.0f / s;
    for (int j = t; j < N; j += 256) row[j] *= inv;
}

// ---------------------------------------------------------------------------
// LayerNorm rows of 512 fp32 -> split bf16 out. grid = rows, block = 256.
// ---------------------------------------------------------------------------
__global__ __launch_bounds__(256) void layernorm_split(
    const float* __restrict__ X, const float* __restrict__ g, const float* __restrict__ b,
    unsigned short* __restrict__ ohi, unsigned short* __restrict__ olo)
{
    const float* row = X + (size_t)blockIdx.x * 512;
    size_t ob = (size_t)blockIdx.x * 512;
    int t = threadIdx.x;
    float x0 = row[t], x1 = row[t + 256];
    float s = x0 + x1, sq = x0 * x0 + x1 * x1;
    for (int o = 32; o; o >>= 1) { s += __shfl_xor(s, o); sq += __shfl_xor(sq, o); }
    __shared__ float ls[8];
    int w = t >> 6;
    if ((t & 63) == 0) { ls[w] = s; ls[4 + w] = sq; }
    __syncthreads();
    s = ls[0] + ls[1] + ls[2] + ls[3];
    sq = ls[4] + ls[5] + ls[6] + ls[7];
    float mu = s * (1.0f / 512.0f);
    float var = sq * (1.0f / 512.0f) - mu * mu;
    float inv = rsqrtf(var + 1e-5f);
    float y0 = (x0 - mu) * inv * g[t]       + b[t];
    float y1 = (x1 - mu) * inv * g[t + 256] + b[t + 256];
    unsigned short h0 = f2bf(y0), h1 = f2bf(y1);
    ohi[ob + t]       = h0;  olo[ob + t]       = f2bf(y0 - bf2f(h0));
    ohi[ob + t + 256] = h1;  olo[ob + t + 256] = f2bf(y1 - bf2f(h1));
}

// ---------------------------------------------------------------------------
// out[b,h] = dot(q[b,h,:], projT[h,:]) with hi+lo reconstruction
// ---------------------------------------------------------------------------
__global__ __launch_bounds__(256) void outproj3(
    const unsigned short* __restrict__ qhi, const unsigned short* __restrict__ qlo,
    const unsigned short* __restrict__ phi, const unsigned short* __restrict__ plo,
    float* __restrict__ out)
{
    int gw = blockIdx.x * 4 + (threadIdx.x >> 6);  // b*1024+h
    int lane = threadIdx.x & 63;
    int h = gw & 1023;
    uint4 qh = ((const uint4*)(qhi + (size_t)gw * 512))[lane];
    uint4 ql = ((const uint4*)(qlo + (size_t)gw * 512))[lane];
    uint4 ph = ((const uint4*)(phi + (size_t)h * 512))[lane];
    uint4 pl = ((const uint4*)(plo + (size_t)h * 512))[lane];
    unsigned short qhe[8], qle[8], phe[8], ple[8];
    *(uint4*)qhe = qh; *(uint4*)qle = ql; *(uint4*)phe = ph; *(uint4*)ple = pl;
    float s = 0.0f;
    #pragma unroll
    for (int i = 0; i < 8; ++i) {
        float q = bf2f(qhe[i]) + bf2f(qle[i]);
        float p = bf2f(phe[i]) + bf2f(ple[i]);
        s += q * p;
    }
    for (int o = 32; o; o >>= 1) s += __shfl_xor(s, o);
    if (lane == 0) out[gw] = s;
}

// ---------------------------------------------------------------------------
// launcher
// ---------------------------------------------------------------------------
extern "C" void kernel_launch(void* const* d_in, const int* in_sizes, int n_in,
                              void* d_out, int out_size, void* d_ws, size_t ws_size,
                              hipStream_t stream)
{
    (void)in_sizes; (void)n_in; (void)out_size; (void)ws_size;

    const float* x     = (const float*)d_in[0];   // (16,256,512)
    const float* le    = (const float*)d_in[1];   // (1024,512)
    const float* proj  = (const float*)d_in[2];   // (512,1024)
    const float* WihF  = (const float*)d_in[3];   // (1024,512)
    const float* WhhF  = (const float*)d_in[4];   // (1024,256)
    const float* bihF  = (const float*)d_in[5];
    const float* bhhF  = (const float*)d_in[6];
    const float* WihB  = (const float*)d_in[7];
    const float* WhhB  = (const float*)d_in[8];
    const float* bihB  = (const float*)d_in[9];
    const float* bhhB  = (const float*)d_in[10];
    const float* w1    = (const float*)d_in[11];  // (2,512,2048)
    const float* b1    = (const float*)d_in[12];  // (2,2048)
    const float* w2    = (const float*)d_in[13];  // (2,2048,512)
    const float* b2    = (const float*)d_in[14];  // (2,512)
    const float* lng   = (const float*)d_in[15];  // (2,512)
    const float* lnb   = (const float*)d_in[16];  // (2,512)
    float* out = (float*)d_out;
    float* ws  = (float*)d_ws;
    unsigned short* wsu = (unsigned short*)d_ws;

    const size_t MEG = 1048576;
    // float-offset layout
    const size_t LNSRC = 0;              // 8M: preF/preB -> qt hi/lo (L1 attn) -> FFN2 out
    const size_t HB    = 8 * MEG;        // 8M: attn value output q2attn fp32
    const size_t AR    = 16 * MEG;       // 8M: wsc/q1s/s2s scratch; ffh
    const size_t QHI   = 24 * MEG;       // 4M fl (8M elems bf16)
    const size_t QLO   = 28 * MEG;
    const size_t FHI   = 32 * MEG;       // 1M fl
    const size_t FLO   = 33 * MEG;
    const size_t FTHI  = 34 * MEG;
    const size_t FTLO  = 35 * MEG;
    const size_t LEHI  = 36 * MEG;                 // .25M fl
    const size_t LELO  = LEHI  + MEG / 4;
    const size_t LETHI = LELO  + MEG / 4;
    const size_t LETLO = LETHI + MEG / 4;
    const size_t WIHFH = LETLO + MEG / 4;
    const size_t WIHFL = WIHFH + MEG / 4;
    const size_t WIHBH = WIHFL + MEG / 4;
    const size_t WIHBL = WIHBH + MEG / 4;
    const size_t SYNC  = WIHBL + MEG / 4;          // flags[32] + hg (16K fl)
    const size_t W1TH  = SYNC  + MEG / 4;          // .5M fl (1M elems)
    const size_t W1TL  = W1TH  + MEG / 2;
    const size_t W2TH  = W1TL  + MEG / 2;
    const size_t W2TL  = W2TH  + MEG / 2;
    const size_t WTH   = W2TL  + MEG / 2;          // .5M fl tmp
    const size_t WTL   = WTH   + MEG / 2;
    const size_t PTH   = WTL   + MEG / 2;          // .25M fl
    const size_t PTL   = PTH   + MEG / 4;
    const size_t BSUM  = PTL   + MEG / 4;

    float* preF   = ws + LNSRC;
    float* preB   = ws + LNSRC + 4 * MEG;
    float* lnsrc  = ws + LNSRC;
    float* q2a    = ws + HB;
    float* arena  = ws + AR;
    float* bsum   = ws + BSUM;
    int*   flags  = (int*)(ws + SYNC);             // 32 ints
    float* hg     = ws + SYNC + 1024;              // 2*2*16*256 = 16384 fl
    unsigned short* qthi  = wsu + 2 * LNSRC;       // alias (layer-1 attn only)
    unsigned short* qtlo  = wsu + 2 * (LNSRC + 4 * MEG);
    unsigned short* qhi   = wsu + 2 * QHI;
    unsigned short* qlo   = wsu + 2 * QLO;
    unsigned short* fhi   = wsu + 2 * FHI;
    unsigned short* flo   = wsu + 2 * FLO;
    unsigned short* fthi  = wsu + 2 * FTHI;
    unsigned short* ftlo  = wsu + 2 * FTLO;
    unsigned short* lehi  = wsu + 2 * LEHI;
    unsigned short* lelo  = wsu + 2 * LELO;
    unsigned short* lethi = wsu + 2 * LETHI;
    unsigned short* letlo = wsu + 2 * LETLO;
    unsigned short* wihFh = wsu + 2 * WIHFH;
    unsigned short* wihFl = wsu + 2 * WIHFL;
    unsigned short* wihBh = wsu + 2 * WIHBH;
    unsigned short* wihBl = wsu + 2 * WIHBL;
    unsigned short* w1th  = wsu + 2 * W1TH;
    unsigned short* w1tl  = wsu + 2 * W1TL;
    unsigned short* w2th  = wsu + 2 * W2TH;
    unsigned short* w2tl  = wsu + 2 * W2TL;
    unsigned short* wth   = wsu + 2 * WTH;
    unsigned short* wtl   = wsu + 2 * WTL;
    unsigned short* pth   = wsu + 2 * PTH;
    unsigned short* ptl   = wsu + 2 * PTL;

    // ---- prep
    bias_sum_kernel<<<8, 256, 0, stream>>>(bihF, bhhF, bihB, bhhB, bsum);
    cvt_split<<<512, 256, 0, stream>>>(WihF, wihFh, wihFl);
    cvt_split<<<512, 256, 0, stream>>>(WihB, wihBh, wihBl);
    cvt_split<<<512, 256, 0, stream>>>(le, lehi, lelo);
    { dim3 g(512 / 64, 1024 / 64, 1);
      tcvt_bf16<<<g, 256, 0, stream>>>(lehi, lethi, 1024, 512);
      tcvt_bf16<<<g, 256, 0, stream>>>(lelo, letlo, 1024, 512); }
    hipMemsetAsync(flags, 0, 32 * sizeof(int), stream);

    // ---- LSTM input projections: pre = x @ Wih^T + (bih+bhh)
    gemm_f32A(0, x, wihFh, wihFl, bsum,        preF, NB * NS, 1024, ND, 0, 0, 0, 1, stream);
    gemm_f32A(0, x, wihBh, wihBl, bsum + 1024, preB, NB * NS, 1024, ND, 0, 0, 0, 1, stream);

    // ---- recurrence -> features (split bf16), cooperative 32-block kernel
    lstm_rec4<<<32, 512, 0, stream>>>(preF, preB, WhhF, WhhB, hg, flags, fhi, flo);
    { dim3 g(512 / 64, 256 / 64, 16);
      tcvt_bf16<<<g, 256, 0, stream>>>(fhi, fthi, 256, 512);
      tcvt_bf16<<<g, 256, 0, stream>>>(flo, ftlo, 256, 512); }

    // ---- layers
    for (int l = 0; l < 2; ++l) {
        const float* b1l = b1 + (size_t)l * NF;
        const float* b2l = b2 + (size_t)l * ND;
        const float* gl  = lng + (size_t)l * ND;
        const float* bl  = lnb + (size_t)l * ND;

        // FFN weights -> split bf16, transposed
        cvt_split<<<1024, 256, 0, stream>>>(w1 + (size_t)l * ND * NF, wth, wtl);   // (512,2048)
        { dim3 g(NF / 64, ND / 64, 1);
          tcvt_bf16<<<g, 256, 0, stream>>>(wth, w1th, ND, NF);
          tcvt_bf16<<<g, 256, 0, stream>>>(wtl, w1tl, ND, NF); }                   // (2048,512)
        cvt_split<<<1024, 256, 0, stream>>>(w2 + (size_t)l * NF * ND, wth, wtl);   // (2048,512)
        { dim3 g(ND / 64, NF / 64, 1);
          tcvt_bf16<<<g, 256, 0, stream>>>(wth, w2th, NF, ND);
          tcvt_bf16<<<g, 256, 0, stream>>>(wtl, w2tl, NF, ND); }                   // (512,2048)

        if (l == 0) {
            // query identical across batch: shared self-attn + q1
            float* wsc = arena;                  // 1M (1024,1024)
            float* q1s = arena + MEG;            // .5M (1024,512)
            float* s2s = arena + 2 * MEG;        // 4M (16,1024,256)
            gemm_f32A(0, le, lehi, lelo, nullptr, wsc, NH, NH, ND, 0, 0, 0, 1, stream);
            softmax_kernel<<<NH, 256, 0, stream>>>(wsc, NH);
            gemm_f32A(0, wsc, lethi, letlo, nullptr, q1s, NH, ND, NH, 0, 0, 0, 1, stream);
            gemm_f32A(0, q1s, fhi, flo, nullptr, s2s, NH, NS, ND,
                      0, (long)NS * ND, (long)NH * NS, 16, stream);
            softmax_kernel<<<NB * NH, 256, 0, stream>>>(s2s, NS);
            gemm_f32A(0, s2s, fthi, ftlo, nullptr, q2a, NH, ND, NS,
                      (long)NH * NS, (long)ND * NS, (long)NH * ND, 16, stream);
        } else {
            { dim3 g(512 / 64, 1024 / 64, 16);
              tcvt_bf16<<<g, 256, 0, stream>>>(qhi, qthi, 1024, 512);
              tcvt_bf16<<<g, 256, 0, stream>>>(qlo, qtlo, 1024, 512); }
            float* wsc4 = arena;                 // 4M (4,1024,1024)
            float* q1s4 = arena + 4 * MEG;       // 2M (4,1024,512)
            float* s2s4 = arena + 6 * MEG;       // 1M (4,1024,256)
            for (int g4 = 0; g4 < 4; ++g4) {
                size_t qo = (size_t)g4 * 4;
                gemm_splitA(qhi + qo * NH * ND, qlo + qo * NH * ND,
                            qhi + qo * NH * ND, qlo + qo * NH * ND,
                            nullptr, wsc4, NH, NH, ND,
                            (long)NH * ND, (long)NH * ND, (long)NH * NH, 4, stream);
                softmax_kernel<<<4 * NH, 256, 0, stream>>>(wsc4, NH);
                gemm_f32A(0, wsc4, qthi + qo * ND * NH, qtlo + qo * ND * NH,
                          nullptr, q1s4, NH, ND, NH,
                          (long)NH * NH, (long)ND * NH, (long)NH * ND, 4, stream);
                gemm_f32A(0, q1s4, fhi + qo * NS * ND, flo + qo * NS * ND,
                          nullptr, s2s4, NH, NS, ND,
                          (long)NH * ND, (long)NS * ND, (long)NH * NS, 4, stream);
                softmax_kernel<<<4 * NH, 256, 0, stream>>>(s2s4, NS);
                gemm_f32A(0, s2s4, fthi + qo * ND * NS, ftlo + qo * ND * NS,
                          nullptr, q2a + qo * NH * ND, NH, ND, NS,
                          (long)NH * NS, (long)ND * NS, (long)NH * ND, 4, stream);
            }
        }

        // FFN: 4 chunks of 4096 rows; q2a -> ffh(arena) -> lnsrc
        float* ffh = arena;
        for (int ch = 0; ch < 4; ++ch) {
            const float* rows_in = q2a + (size_t)ch * 4096 * ND;
            float* rows_out      = lnsrc + (size_t)ch * 4096 * ND;
            gemm_f32A(1, rows_in, w1th, w1tl, b1l, ffh, 4096, NF, ND, 0, 0, 0, 1, stream);
            gemm_f32A(0, ffh, w2th, w2tl, b2l, rows_out, 4096, ND, NF, 0, 0, 0, 1, stream);
        }
        layernorm_split<<<NB * NH, 256, 0, stream>>>(lnsrc, gl, bl, qhi, qlo);
    }

    // ---- final projection
    cvt_split<<<512, 256, 0, stream>>>(proj, wth, wtl);                    // (512,1024)
    { dim3 g(1024 / 64, 512 / 64, 1);
      tcvt_bf16<<<g, 256, 0, stream>>>(wth, pth, 512, 1024);
      tcvt_bf16<<<g, 256, 0, stream>>>(wtl, ptl, 512, 1024); }             // (1024,512)
    outproj3<<<4096, 256, 0, stream>>>(qhi, qlo, pth, ptl, out);
}

// Round 5
// 3973.924 us; speedup vs baseline: 4.4565x; 1.4727x over previous
//
#include <hip/hip_runtime.h>
#include <hip/hip_bf16.h>
#include <math.h>

// Problem dims
#define NB 16
#define NS 256
#define ND 512
#define NH 1024
#define NF 2048
#define NHID 256

typedef __attribute__((ext_vector_type(8))) short bf16x8;
typedef __attribute__((ext_vector_type(4))) float f32x4;

__device__ __forceinline__ unsigned short f2bf(float f) {
    unsigned u = __float_as_uint(f);
    unsigned r = u + 0x7fffu + ((u >> 16) & 1u);
    return (unsigned short)(r >> 16);
}
__device__ __forceinline__ float bf2f(unsigned short h) {
    return __uint_as_float(((unsigned)h) << 16);
}

// ---------------------------------------------------------------------------
// Split-bf16 MFMA GEMM: C[M,N] fp32 = A[M,K] @ B[N,K]^T (+bias)(+gelu)
// Operands as hi+lo bf16 pairs; C = Ah*Bh + Al*Bh + Ah*Bl  (~fp32 precision).
// ---------------------------------------------------------------------------
template<int TA_SPLIT, int ACT>
__global__ __launch_bounds__(256) void sgemm(
    const float* __restrict__ Af,
    const unsigned short* __restrict__ Ahi, const unsigned short* __restrict__ Alo,
    const unsigned short* __restrict__ Bhi, const unsigned short* __restrict__ Blo,
    const float* __restrict__ bias, float* __restrict__ Cp,
    int M, int N, int K, long sA, long sB, long sC)
{
    __shared__ unsigned short Ah[128 * 40];
    __shared__ unsigned short Al[128 * 40];
    __shared__ unsigned short Bh[128 * 40];
    __shared__ unsigned short Bl[128 * 40];

    const int t = threadIdx.x;
    const int z = blockIdx.z;
    const int m0 = blockIdx.y * 128, n0 = blockIdx.x * 128;

    float* C = Cp + (size_t)z * sC;

    const int wid = t >> 6, lane = t & 63;
    const int wr = (wid >> 1) * 64, wc = (wid & 1) * 64;
    const int lr = lane & 15, lk = lane >> 4;

    f32x4 acc[4][4];
    #pragma unroll
    for (int i = 0; i < 4; ++i)
        #pragma unroll
        for (int j = 0; j < 4; ++j) acc[i][j] = (f32x4){0.f, 0.f, 0.f, 0.f};

    const int sr = t >> 1;            // staging row 0..127
    const int sc = (t & 1) * 16;      // staging col elem base (16 elems each)

    for (int k0 = 0; k0 < K; k0 += 32) {
        // ---- stage A hi/lo
        {
            char* dh = (char*)Ah + sr * 80 + sc * 2;
            char* dl = (char*)Al + sr * 80 + sc * 2;
            if (TA_SPLIT) {
                size_t off = (size_t)z * sA + (size_t)(m0 + sr) * K + k0 + sc;
                const unsigned short* shp = Ahi + off;
                const unsigned short* slp = Alo + off;
                *(uint4*)dh = *(const uint4*)(shp);
                *(uint4*)(dh + 16) = *(const uint4*)(shp + 8);
                *(uint4*)dl = *(const uint4*)(slp);
                *(uint4*)(dl + 16) = *(const uint4*)(slp + 8);
            } else {
                const float* src = Af + (size_t)z * sA + (size_t)(m0 + sr) * K + k0 + sc;
                float v[16];
                *(float4*)(v)      = *(const float4*)(src);
                *(float4*)(v + 4)  = *(const float4*)(src + 4);
                *(float4*)(v + 8)  = *(const float4*)(src + 8);
                *(float4*)(v + 12) = *(const float4*)(src + 12);
                unsigned short hh[16], ll[16];
                #pragma unroll
                for (int i = 0; i < 16; ++i) {
                    unsigned short h = f2bf(v[i]);
                    hh[i] = h;
                    ll[i] = f2bf(v[i] - bf2f(h));
                }
                *(uint4*)dh = *(uint4*)hh;
                *(uint4*)(dh + 16) = *(uint4*)(hh + 8);
                *(uint4*)dl = *(uint4*)ll;
                *(uint4*)(dl + 16) = *(uint4*)(ll + 8);
            }
        }
        // ---- stage B hi/lo
        {
            size_t off = (size_t)z * sB + (size_t)(n0 + sr) * K + k0 + sc;
            const unsigned short* shp = Bhi + off;
            const unsigned short* slp = Blo + off;
            char* dh = (char*)Bh + sr * 80 + sc * 2;
            char* dl = (char*)Bl + sr * 80 + sc * 2;
            *(uint4*)dh = *(const uint4*)(shp);
            *(uint4*)(dh + 16) = *(const uint4*)(shp + 8);
            *(uint4*)dl = *(const uint4*)(slp);
            *(uint4*)(dl + 16) = *(const uint4*)(slp + 8);
        }
        __syncthreads();

        bf16x8 ah[4], al[4], bh[4], bl[4];
        #pragma unroll
        for (int mt = 0; mt < 4; ++mt) {
            int r = wr + mt * 16 + lr;
            ah[mt] = *(const bf16x8*)((const char*)Ah + r * 80 + lk * 16);
            al[mt] = *(const bf16x8*)((const char*)Al + r * 80 + lk * 16);
        }
        #pragma unroll
        for (int nt = 0; nt < 4; ++nt) {
            int r = wc + nt * 16 + lr;
            bh[nt] = *(const bf16x8*)((const char*)Bh + r * 80 + lk * 16);
            bl[nt] = *(const bf16x8*)((const char*)Bl + r * 80 + lk * 16);
        }
        #pragma unroll
        for (int mt = 0; mt < 4; ++mt)
            #pragma unroll
            for (int nt = 0; nt < 4; ++nt) {
                acc[mt][nt] = __builtin_amdgcn_mfma_f32_16x16x32_bf16(ah[mt], bh[nt], acc[mt][nt], 0, 0, 0);
                acc[mt][nt] = __builtin_amdgcn_mfma_f32_16x16x32_bf16(al[mt], bh[nt], acc[mt][nt], 0, 0, 0);
                acc[mt][nt] = __builtin_amdgcn_mfma_f32_16x16x32_bf16(ah[mt], bl[nt], acc[mt][nt], 0, 0, 0);
            }
        __syncthreads();
    }

    // epilogue: C/D layout col=lane&15, row=(lane>>4)*4+reg
    #pragma unroll
    for (int nt = 0; nt < 4; ++nt) {
        int col = n0 + wc + nt * 16 + (lane & 15);
        float bv = bias ? bias[col] : 0.0f;
        #pragma unroll
        for (int mt = 0; mt < 4; ++mt) {
            #pragma unroll
            for (int i = 0; i < 4; ++i) {
                int row = m0 + wr + mt * 16 + (lane >> 4) * 4 + i;
                float x = acc[mt][nt][i] + bv;
                if (ACT == 1) x = 0.5f * x * (1.0f + erff(x * 0.70710678118654752f));
                C[(size_t)row * N + col] = x;
            }
        }
    }
}

static void gemm_f32A(int act, const float* A,
                      const unsigned short* Bhi, const unsigned short* Blo,
                      const float* bias, float* C, int M, int N, int K,
                      long sA, long sB, long sC, int Z, hipStream_t st)
{
    dim3 g(N / 128, M / 128, Z), b(256);
    if (act) sgemm<0, 1><<<g, b, 0, st>>>(A, nullptr, nullptr, Bhi, Blo, bias, C, M, N, K, sA, sB, sC);
    else     sgemm<0, 0><<<g, b, 0, st>>>(A, nullptr, nullptr, Bhi, Blo, bias, C, M, N, K, sA, sB, sC);
}

static void gemm_splitA(const unsigned short* Ahi, const unsigned short* Alo,
                        const unsigned short* Bhi, const unsigned short* Blo,
                        const float* bias, float* C, int M, int N, int K,
                        long sA, long sB, long sC, int Z, hipStream_t st)
{
    dim3 g(N / 128, M / 128, Z), b(256);
    sgemm<1, 0><<<g, b, 0, st>>>(nullptr, Ahi, Alo, Bhi, Blo, bias, C, M, N, K, sA, sB, sC);
}

// ---------------------------------------------------------------------------
// fp32 -> split bf16 hi/lo (n multiple of 1024)
// ---------------------------------------------------------------------------
__global__ __launch_bounds__(256) void cvt_split(const float* __restrict__ in,
                                                 unsigned short* __restrict__ hi,
                                                 unsigned short* __restrict__ lo)
{
    size_t i = ((size_t)blockIdx.x * 256 + threadIdx.x) * 4;
    float4 v = *(const float4*)(in + i);
    ushort4 h, l;
    h.x = f2bf(v.x); l.x = f2bf(v.x - bf2f(h.x));
    h.y = f2bf(v.y); l.y = f2bf(v.y - bf2f(h.y));
    h.z = f2bf(v.z); l.z = f2bf(v.z - bf2f(h.z));
    h.w = f2bf(v.w); l.w = f2bf(v.w - bf2f(h.w));
    *(ushort4*)(hi + i) = h;
    *(ushort4*)(lo + i) = l;
}

// ---------------------------------------------------------------------------
// bf16 (R,C) -> (C,R) transpose, z-batched. R,C multiples of 64.
// ---------------------------------------------------------------------------
__global__ __launch_bounds__(256) void tcvt_bf16(const unsigned short* __restrict__ in,
                                                 unsigned short* __restrict__ out,
                                                 int R, int C)
{
    __shared__ unsigned short tile[64 * 72];
    int z = blockIdx.z;
    in += (size_t)z * R * C;
    out += (size_t)z * R * C;
    int r0 = blockIdx.y * 64, c0 = blockIdx.x * 64;
    int t = threadIdx.x;
    int tr = t >> 2, tc = (t & 3) * 16;

    uint4 q0 = *(const uint4*)(in + (size_t)(r0 + tr) * C + c0 + tc);
    uint4 q1 = *(const uint4*)(in + (size_t)(r0 + tr) * C + c0 + tc + 8);
    unsigned short e[16];
    *(uint4*)(e) = q0;
    *(uint4*)(e + 8) = q1;
    #pragma unroll
    for (int i = 0; i < 16; ++i) tile[(tc + i) * 72 + tr] = e[i];
    __syncthreads();

    uint4 o0 = *(const uint4*)(&tile[tr * 72 + tc]);
    uint4 o1 = *(const uint4*)(&tile[tr * 72 + tc + 8]);
    *(uint4*)(out + (size_t)(c0 + tr) * R + r0 + tc) = o0;
    *(uint4*)(out + (size_t)(c0 + tr) * R + r0 + tc + 8) = o1;
}

// ---------------------------------------------------------------------------
// bias combine
// ---------------------------------------------------------------------------
__global__ __launch_bounds__(256) void bias_sum_kernel(
    const float* bihF, const float* bhhF, const float* bihB, const float* bhhB,
    float* out)
{
    int i = blockIdx.x * 256 + threadIdx.x;
    if (i < 1024) out[i] = bihF[i] + bhhF[i];
    else out[i] = bihB[i - 1024] + bhhB[i - 1024];
}

// ---------------------------------------------------------------------------
// LSTM recurrence v5: cross-CU cooperative, FENCE-FREE.
// grid = 32 blocks (dir = bid>>4, slice = bid&15), block = 512 threads.
// Each block owns 16 units of one direction; its 64 gate rows (64KB fp32)
// are LDS-resident for the whole kernel. Per step: compute 16 units x 16
// batches, exchange h through a parity-double-buffered global buffer.
// ALL cross-block data (h, flags) moves via RELAXED AGENT-scope atomics
// (global_load/store sc1 -> MALL-coherent, bypasses non-coherent L2s).
// NO __threadfence() -> no L2 writeback/invalidate per step (round-4's
// 262 MB/step FETCH_SIZE pathology).
// Release order: h stores -> s_waitcnt vmcnt(0) -> __syncthreads -> flag.
// Acquire order: spin branch resolves before h loads issue (in-order HW).
// LDS layout: row stride 268 dwords, K halves at +0 / +132:
//   delta(kh)=132%32=4 (no collision), delta(b=8)=2144%32=0 (2-way, free).
// ---------------------------------------------------------------------------
__global__ __launch_bounds__(512) void lstm_rec5(
    const float* __restrict__ preF, const float* __restrict__ preB,
    const float* __restrict__ WhhF, const float* __restrict__ WhhB,
    float* __restrict__ hg,      // [parity2][dir2][16b][256u] fp32
    int* __restrict__ flags,     // [32], zeroed before launch
    unsigned short* __restrict__ fhi, unsigned short* __restrict__ flo)
{
    const int bid = blockIdx.x;
    const int dir = bid >> 4;
    const int slice = bid & 15;
    const float* pre = dir ? preB : preF;
    const float* Whh = dir ? WhhB : WhhF;

    const int tid = threadIdx.x;
    const int ul = tid >> 5;          // 0..15 unit-local
    const int b  = (tid >> 1) & 15;   // 0..15 batch
    const int kh = tid & 1;           // K half
    const int ug = slice * 16 + ul;   // global unit

    __shared__ __align__(16) float wl[64 * 268];   // [gate*16+ul][268]
    __shared__ __align__(16) float hl[16 * 268];   // [b][268]

    // one-time: stage this slice's 64 gate rows; elem k at k + (k>>7)*4
    for (int i = tid; i < 64 * 64; i += 512) {     // 64 rows x 64 float4
        int r = i >> 6, c4 = i & 63;
        int srow = (r >> 4) * 256 + slice * 16 + (r & 15);
        float4 v = *(const float4*)(Whh + (size_t)srow * 256 + c4 * 4);
        int off = c4 * 4 + ((c4 >= 32) ? 4 : 0);
        *(float4*)&wl[r * 268 + off] = v;
    }
    for (int i = tid; i < 16 * 268; i += 512) hl[i] = 0.0f;   // h_{-1} = 0

    float c = 0.0f;                   // cell state (kh lanes redundant)
    __syncthreads();

    const int kbase = kh * 132;
    const float* hrow = &hl[b * 268 + kbase];
    const float* wi = &wl[(0 * 16 + ul) * 268 + kbase];
    const float* wf = &wl[(1 * 16 + ul) * 268 + kbase];
    const float* wg = &wl[(2 * 16 + ul) * 268 + kbase];
    const float* wo = &wl[(3 * 16 + ul) * 268 + kbase];

    for (int si = 0; si < NS; ++si) {
        const int s = dir ? (NS - 1 - si) : si;
        // issue pre loads early (latency hides under spin/h-load)
        const float* prow = pre + ((size_t)(b * NS + s)) * 1024 + ug;
        float pi = prow[0], pf = prow[256], pg = prow[512], po = prow[768];

        if (si > 0) {
            if (tid < 16) {
                const int fj = dir * 16 + tid;     // only own-dir flags
                while (__hip_atomic_load(&flags[fj], __ATOMIC_RELAXED,
                                         __HIP_MEMORY_SCOPE_AGENT) < si) {
                    __builtin_amdgcn_s_sleep(1);
                }
            }
            __syncthreads();
            const float* src = hg + (size_t)(((si - 1) & 1) * 2 + dir) * (16 * 256);
            for (int i = tid; i < 16 * 256; i += 512) {
                float v = __hip_atomic_load(&src[i], __ATOMIC_RELAXED,
                                            __HIP_MEMORY_SCOPE_AGENT);
                int bb = i >> 8, k = i & 255;
                hl[bb * 268 + k + ((k >> 7) << 2)] = v;
            }
            __syncthreads();
        }

        float ai = 0.f, af = 0.f, ag = 0.f, ao = 0.f;
        #pragma unroll
        for (int k4 = 0; k4 < 32; ++k4) {
            float4 h4 = *(const float4*)(hrow + k4 * 4);
            float4 a  = *(const float4*)(wi + k4 * 4);
            float4 f  = *(const float4*)(wf + k4 * 4);
            float4 g  = *(const float4*)(wg + k4 * 4);
            float4 o  = *(const float4*)(wo + k4 * 4);
            ai += a.x * h4.x + a.y * h4.y + a.z * h4.z + a.w * h4.w;
            af += f.x * h4.x + f.y * h4.y + f.z * h4.z + f.w * h4.w;
            ag += g.x * h4.x + g.y * h4.y + g.z * h4.z + g.w * h4.w;
            ao += o.x * h4.x + o.y * h4.y + o.z * h4.z + o.w * h4.w;
        }
        // combine K halves (partner lane tid^1); both lanes end identical
        ai += __shfl_xor(ai, 1);  af += __shfl_xor(af, 1);
        ag += __shfl_xor(ag, 1);  ao += __shfl_xor(ao, 1);
        ai += pi; af += pf; ag += pg; ao += po;

        float gi = 1.0f / (1.0f + expf(-ai));
        float gf = 1.0f / (1.0f + expf(-af));
        float gg = tanhf(ag);
        float go = 1.0f / (1.0f + expf(-ao));
        c = gf * c + gi * gg;
        float h = go * tanhf(c);

        if (kh == 0) {
            float* dst = hg + (size_t)((si & 1) * 2 + dir) * (16 * 256);
            __hip_atomic_store(&dst[b * 256 + ug], h, __ATOMIC_RELAXED,
                               __HIP_MEMORY_SCOPE_AGENT);
            size_t oi = ((size_t)(b * NS + s)) * 512 + dir * 256 + ug;
            unsigned short hh = f2bf(h);
            fhi[oi] = hh;
            flo[oi] = f2bf(h - bf2f(hh));
        }
        // release: my h stores visible at MALL before flag
        asm volatile("s_waitcnt vmcnt(0)" ::: "memory");
        __syncthreads();              // all threads' stores drained
        if (tid == 0)
            __hip_atomic_store(&flags[bid], si + 1, __ATOMIC_RELAXED,
                               __HIP_MEMORY_SCOPE_AGENT);
    }
}

// ---------------------------------------------------------------------------
// row softmax in place: grid = rows, block = 256
// ---------------------------------------------------------------------------
__global__ __launch_bounds__(256) void softmax_kernel(float* __restrict__ X, int N)
{
    float* row = X + (size_t)blockIdx.x * N;
    int t = threadIdx.x;
    float m = -1e30f;
    for (int j = t; j < N; j += 256) m = fmaxf(m, row[j]);
    for (int o = 32; o; o >>= 1) m = fmaxf(m, __shfl_xor(m, o));
    __shared__ float lm[4];
    if ((t & 63) == 0) lm[t >> 6] = m;
    __syncthreads();
    m = fmaxf(fmaxf(lm[0], lm[1]), fmaxf(lm[2], lm[3]));
    float s = 0.0f;
    for (int j = t; j < N; j += 256) { float e = expf(row[j] - m); row[j] = e; s += e; }
    for (int o = 32; o; o >>= 1) s += __shfl_xor(s, o);
    __shared__ float ls[4];
    if ((t & 63) == 0) ls[t >> 6] = s;
    __syncthreads();
    s = ls[0] + ls[1] + ls[2] + ls[3];
    float inv = 1.0f / s;
    for (int j = t; j < N; j += 256) row[j] *= inv;
}

// ---------------------------------------------------------------------------
// LayerNorm rows of 512 fp32 -> split bf16 out. grid = rows, block = 256.
// ---------------------------------------------------------------------------
__global__ __launch_bounds__(256) void layernorm_split(
    const float* __restrict__ X, const float* __restrict__ g, const float* __restrict__ b,
    unsigned short* __restrict__ ohi, unsigned short* __restrict__ olo)
{
    const float* row = X + (size_t)blockIdx.x * 512;
    size_t ob = (size_t)blockIdx.x * 512;
    int t = threadIdx.x;
    float x0 = row[t], x1 = row[t + 256];
    float s = x0 + x1, sq = x0 * x0 + x1 * x1;
    for (int o = 32; o; o >>= 1) { s += __shfl_xor(s, o); sq += __shfl_xor(sq, o); }
    __shared__ float ls[8];
    int w = t >> 6;
    if ((t & 63) == 0) { ls[w] = s; ls[4 + w] = sq; }
    __syncthreads();
    s = ls[0] + ls[1] + ls[2] + ls[3];
    sq = ls[4] + ls[5] + ls[6] + ls[7];
    float mu = s * (1.0f / 512.0f);
    float var = sq * (1.0f / 512.0f) - mu * mu;
    float inv = rsqrtf(var + 1e-5f);
    float y0 = (x0 - mu) * inv * g[t]       + b[t];
    float y1 = (x1 - mu) * inv * g[t + 256] + b[t + 256];
    unsigned short h0 = f2bf(y0), h1 = f2bf(y1);
    ohi[ob + t]       = h0;  olo[ob + t]       = f2bf(y0 - bf2f(h0));
    ohi[ob + t + 256] = h1;  olo[ob + t + 256] = f2bf(y1 - bf2f(h1));
}

// ---------------------------------------------------------------------------
// out[b,h] = dot(q[b,h,:], projT[h,:]) with hi+lo reconstruction
// ---------------------------------------------------------------------------
__global__ __launch_bounds__(256) void outproj3(
    const unsigned short* __restrict__ qhi, const unsigned short* __restrict__ qlo,
    const unsigned short* __restrict__ phi, const unsigned short* __restrict__ plo,
    float* __restrict__ out)
{
    int gw = blockIdx.x * 4 + (threadIdx.x >> 6);  // b*1024+h
    int lane = threadIdx.x & 63;
    int h = gw & 1023;
    uint4 qh = ((const uint4*)(qhi + (size_t)gw * 512))[lane];
    uint4 ql = ((const uint4*)(qlo + (size_t)gw * 512))[lane];
    uint4 ph = ((const uint4*)(phi + (size_t)h * 512))[lane];
    uint4 pl = ((const uint4*)(plo + (size_t)h * 512))[lane];
    unsigned short qhe[8], qle[8], phe[8], ple[8];
    *(uint4*)qhe = qh; *(uint4*)qle = ql; *(uint4*)phe = ph; *(uint4*)ple = pl;
    float s = 0.0f;
    #pragma unroll
    for (int i = 0; i < 8; ++i) {
        float q = bf2f(qhe[i]) + bf2f(qle[i]);
        float p = bf2f(phe[i]) + bf2f(ple[i]);
        s += q * p;
    }
    for (int o = 32; o; o >>= 1) s += __shfl_xor(s, o);
    if (lane == 0) out[gw] = s;
}

// ---------------------------------------------------------------------------
// launcher
// ---------------------------------------------------------------------------
extern "C" void kernel_launch(void* const* d_in, const int* in_sizes, int n_in,
                              void* d_out, int out_size, void* d_ws, size_t ws_size,
                              hipStream_t stream)
{
    (void)in_sizes; (void)n_in; (void)out_size; (void)ws_size;

    const float* x     = (const float*)d_in[0];   // (16,256,512)
    const float* le    = (const float*)d_in[1];   // (1024,512)
    const float* proj  = (const float*)d_in[2];   // (512,1024)
    const float* WihF  = (const float*)d_in[3];   // (1024,512)
    const float* WhhF  = (const float*)d_in[4];   // (1024,256)
    const float* bihF  = (const float*)d_in[5];
    const float* bhhF  = (const float*)d_in[6];
    const float* WihB  = (const float*)d_in[7];
    const float* WhhB  = (const float*)d_in[8];
    const float* bihB  = (const float*)d_in[9];
    const float* bhhB  = (const float*)d_in[10];
    const float* w1    = (const float*)d_in[11];  // (2,512,2048)
    const float* b1    = (const float*)d_in[12];  // (2,2048)
    const float* w2    = (const float*)d_in[13];  // (2,2048,512)
    const float* b2    = (const float*)d_in[14];  // (2,512)
    const float* lng   = (const float*)d_in[15];  // (2,512)
    const float* lnb   = (const float*)d_in[16];  // (2,512)
    float* out = (float*)d_out;
    float* ws  = (float*)d_ws;
    unsigned short* wsu = (unsigned short*)d_ws;

    const size_t MEG = 1048576;
    // float-offset layout
    const size_t LNSRC = 0;              // 8M: preF/preB -> qt hi/lo (L1 attn) -> FFN2 out
    const size_t HB    = 8 * MEG;        // 8M: attn value output q2attn fp32
    const size_t AR    = 16 * MEG;       // 8M: wsc/q1s/s2s scratch; ffh
    const size_t QHI   = 24 * MEG;       // 4M fl (8M elems bf16)
    const size_t QLO   = 28 * MEG;
    const size_t FHI   = 32 * MEG;       // 1M fl
    const size_t FLO   = 33 * MEG;
    const size_t FTHI  = 34 * MEG;
    const size_t FTLO  = 35 * MEG;
    const size_t LEHI  = 36 * MEG;                 // .25M fl
    const size_t LELO  = LEHI  + MEG / 4;
    const size_t LETHI = LELO  + MEG / 4;
    const size_t LETLO = LETHI + MEG / 4;
    const size_t WIHFH = LETLO + MEG / 4;
    const size_t WIHFL = WIHFH + MEG / 4;
    const size_t WIHBH = WIHFL + MEG / 4;
    const size_t WIHBL = WIHBH + MEG / 4;
    const size_t SYNC  = WIHBL + MEG / 4;          // flags[32] + hg (16K fl)
    const size_t W1TH  = SYNC  + MEG / 4;          // .5M fl (1M elems)
    const size_t W1TL  = W1TH  + MEG / 2;
    const size_t W2TH  = W1TL  + MEG / 2;
    const size_t W2TL  = W2TH  + MEG / 2;
    const size_t WTH   = W2TL  + MEG / 2;          // .5M fl tmp
    const size_t WTL   = WTH   + MEG / 2;
    const size_t PTH   = WTL   + MEG / 2;          // .25M fl
    const size_t PTL   = PTH   + MEG / 4;
    const size_t BSUM  = PTL   + MEG / 4;

    float* preF   = ws + LNSRC;
    float* preB   = ws + LNSRC + 4 * MEG;
    float* lnsrc  = ws + LNSRC;
    float* q2a    = ws + HB;
    float* arena  = ws + AR;
    float* bsum   = ws + BSUM;
    int*   flags  = (int*)(ws + SYNC);             // 32 ints
    float* hg     = ws + SYNC + 1024;              // 2*2*16*256 = 16384 fl
    unsigned short* qthi  = wsu + 2 * LNSRC;       // alias (layer-1 attn only)
    unsigned short* qtlo  = wsu + 2 * (LNSRC + 4 * MEG);
    unsigned short* qhi   = wsu + 2 * QHI;
    unsigned short* qlo   = wsu + 2 * QLO;
    unsigned short* fhi   = wsu + 2 * FHI;
    unsigned short* flo   = wsu + 2 * FLO;
    unsigned short* fthi  = wsu + 2 * FTHI;
    unsigned short* ftlo  = wsu + 2 * FTLO;
    unsigned short* lehi  = wsu + 2 * LEHI;
    unsigned short* lelo  = wsu + 2 * LELO;
    unsigned short* lethi = wsu + 2 * LETHI;
    unsigned short* letlo = wsu + 2 * LETLO;
    unsigned short* wihFh = wsu + 2 * WIHFH;
    unsigned short* wihFl = wsu + 2 * WIHFL;
    unsigned short* wihBh = wsu + 2 * WIHBH;
    unsigned short* wihBl = wsu + 2 * WIHBL;
    unsigned short* w1th  = wsu + 2 * W1TH;
    unsigned short* w1tl  = wsu + 2 * W1TL;
    unsigned short* w2th  = wsu + 2 * W2TH;
    unsigned short* w2tl  = wsu + 2 * W2TL;
    unsigned short* wth   = wsu + 2 * WTH;
    unsigned short* wtl   = wsu + 2 * WTL;
    unsigned short* pth   = wsu + 2 * PTH;
    unsigned short* ptl   = wsu + 2 * PTL;

    // ---- prep
    bias_sum_kernel<<<8, 256, 0, stream>>>(bihF, bhhF, bihB, bhhB, bsum);
    cvt_split<<<512, 256, 0, stream>>>(WihF, wihFh, wihFl);
    cvt_split<<<512, 256, 0, stream>>>(WihB, wihBh, wihBl);
    cvt_split<<<512, 256, 0, stream>>>(le, lehi, lelo);
    { dim3 g(512 / 64, 1024 / 64, 1);
      tcvt_bf16<<<g, 256, 0, stream>>>(lehi, lethi, 1024, 512);
      tcvt_bf16<<<g, 256, 0, stream>>>(lelo, letlo, 1024, 512); }
    hipMemsetAsync(flags, 0, 32 * sizeof(int), stream);

    // ---- LSTM input projections: pre = x @ Wih^T + (bih+bhh)
    gemm_f32A(0, x, wihFh, wihFl, bsum,        preF, NB * NS, 1024, ND, 0, 0, 0, 1, stream);
    gemm_f32A(0, x, wihBh, wihBl, bsum + 1024, preB, NB * NS, 1024, ND, 0, 0, 0, 1, stream);

    // ---- recurrence -> features (split bf16), cooperative 32-block kernel
    lstm_rec5<<<32, 512, 0, stream>>>(preF, preB, WhhF, WhhB, hg, flags, fhi, flo);
    { dim3 g(512 / 64, 256 / 64, 16);
      tcvt_bf16<<<g, 256, 0, stream>>>(fhi, fthi, 256, 512);
      tcvt_bf16<<<g, 256, 0, stream>>>(flo, ftlo, 256, 512); }

    // ---- layers
    for (int l = 0; l < 2; ++l) {
        const float* b1l = b1 + (size_t)l * NF;
        const float* b2l = b2 + (size_t)l * ND;
        const float* gl  = lng + (size_t)l * ND;
        const float* bl  = lnb + (size_t)l * ND;

        // FFN weights -> split bf16, transposed
        cvt_split<<<1024, 256, 0, stream>>>(w1 + (size_t)l * ND * NF, wth, wtl);   // (512,2048)
        { dim3 g(NF / 64, ND / 64, 1);
          tcvt_bf16<<<g, 256, 0, stream>>>(wth, w1th, ND, NF);
          tcvt_bf16<<<g, 256, 0, stream>>>(wtl, w1tl, ND, NF); }                   // (2048,512)
        cvt_split<<<1024, 256, 0, stream>>>(w2 + (size_t)l * NF * ND, wth, wtl);   // (2048,512)
        { dim3 g(ND / 64, NF / 64, 1);
          tcvt_bf16<<<g, 256, 0, stream>>>(wth, w2th, NF, ND);
          tcvt_bf16<<<g, 256, 0, stream>>>(wtl, w2tl, NF, ND); }                   // (512,2048)

        if (l == 0) {
            // query identical across batch: shared self-attn + q1
            float* wsc = arena;                  // 1M (1024,1024)
            float* q1s = arena + MEG;            // .5M (1024,512)
            float* s2s = arena + 2 * MEG;        // 4M (16,1024,256)
            gemm_f32A(0, le, lehi, lelo, nullptr, wsc, NH, NH, ND, 0, 0, 0, 1, stream);
            softmax_kernel<<<NH, 256, 0, stream>>>(wsc, NH);
            gemm_f32A(0, wsc, lethi, letlo, nullptr, q1s, NH, ND, NH, 0, 0, 0, 1, stream);
            gemm_f32A(0, q1s, fhi, flo, nullptr, s2s, NH, NS, ND,
                      0, (long)NS * ND, (long)NH * NS, 16, stream);
            softmax_kernel<<<NB * NH, 256, 0, stream>>>(s2s, NS);
            gemm_f32A(0, s2s, fthi, ftlo, nullptr, q2a, NH, ND, NS,
                      (long)NH * NS, (long)ND * NS, (long)NH * ND, 16, stream);
        } else {
            { dim3 g(512 / 64, 1024 / 64, 16);
              tcvt_bf16<<<g, 256, 0, stream>>>(qhi, qthi, 1024, 512);
              tcvt_bf16<<<g, 256, 0, stream>>>(qlo, qtlo, 1024, 512); }
            float* wsc4 = arena;                 // 4M (4,1024,1024)
            float* q1s4 = arena + 4 * MEG;       // 2M (4,1024,512)
            float* s2s4 = arena + 6 * MEG;       // 1M (4,1024,256)
            for (int g4 = 0; g4 < 4; ++g4) {
                size_t qo = (size_t)g4 * 4;
                gemm_splitA(qhi + qo * NH * ND, qlo + qo * NH * ND,
                            qhi + qo * NH * ND, qlo + qo * NH * ND,
                            nullptr, wsc4, NH, NH, ND,
                            (long)NH * ND, (long)NH * ND, (long)NH * NH, 4, stream);
                softmax_kernel<<<4 * NH, 256, 0, stream>>>(wsc4, NH);
                gemm_f32A(0, wsc4, qthi + qo * ND * NH, qtlo + qo * ND * NH,
                          nullptr, q1s4, NH, ND, NH,
                          (long)NH * NH, (long)ND * NH, (long)NH * ND, 4, stream);
                gemm_f32A(0, q1s4, fhi + qo * NS * ND, flo + qo * NS * ND,
                          nullptr, s2s4, NH, NS, ND,
                          (long)NH * ND, (long)NS * ND, (long)NH * NS, 4, stream);
                softmax_kernel<<<4 * NH, 256, 0, stream>>>(s2s4, NS);
                gemm_f32A(0, s2s4, fthi + qo * ND * NS, ftlo + qo * ND * NS,
                          nullptr, q2a + qo * NH * ND, NH, ND, NS,
                          (long)NH * NS, (long)ND * NS, (long)NH * ND, 4, stream);
            }
        }

        // FFN: 4 chunks of 4096 rows; q2a -> ffh(arena) -> lnsrc
        float* ffh = arena;
        for (int ch = 0; ch < 4; ++ch) {
            const float* rows_in = q2a + (size_t)ch * 4096 * ND;
            float* rows_out      = lnsrc + (size_t)ch * 4096 * ND;
            gemm_f32A(1, rows_in, w1th, w1tl, b1l, ffh, 4096, NF, ND, 0, 0, 0, 1, stream);
            gemm_f32A(0, ffh, w2th, w2tl, b2l, rows_out, 4096, ND, NF, 0, 0, 0, 1, stream);
        }
        layernorm_split<<<NB * NH, 256, 0, stream>>>(lnsrc, gl, bl, qhi, qlo);
    }

    // ---- final projection
    cvt_split<<<512, 256, 0, stream>>>(proj, wth, wtl);                    // (512,1024)
    { dim3 g(1024 / 64, 512 / 64, 1);
      tcvt_bf16<<<g, 256, 0, stream>>>(wth, pth, 512, 1024);
      tcvt_bf16<<<g, 256, 0, stream>>>(wtl, ptl, 512, 1024); }             // (1024,512)
    outproj3<<<4096, 256, 0, stream>>>(qhi, qlo, pth, ptl, out);
}

// Round 6
// 2947.288 us; speedup vs baseline: 6.0088x; 1.3483x over previous
//
#include <hip/hip_runtime.h>
#include <hip/hip_bf16.h>
#include <math.h>

// Problem dims
#define NB 16
#define NS 256
#define ND 512
#define NH 1024
#define NF 2048
#define NHID 256

typedef __attribute__((ext_vector_type(8))) short bf16x8;
typedef __attribute__((ext_vector_type(4))) float f32x4;

__device__ __forceinline__ unsigned short f2bf(float f) {
    unsigned u = __float_as_uint(f);
    unsigned r = u + 0x7fffu + ((u >> 16) & 1u);
    return (unsigned short)(r >> 16);
}
__device__ __forceinline__ float bf2f(unsigned short h) {
    return __uint_as_float(((unsigned)h) << 16);
}

// ---------------------------------------------------------------------------
// Split-bf16 MFMA GEMM: C[M,N] fp32 = A[M,K] @ B[N,K]^T (+bias)(+gelu)
// Operands as hi+lo bf16 pairs; C = Ah*Bh + Al*Bh + Ah*Bl  (~fp32 precision).
// ---------------------------------------------------------------------------
template<int TA_SPLIT, int ACT>
__global__ __launch_bounds__(256) void sgemm(
    const float* __restrict__ Af,
    const unsigned short* __restrict__ Ahi, const unsigned short* __restrict__ Alo,
    const unsigned short* __restrict__ Bhi, const unsigned short* __restrict__ Blo,
    const float* __restrict__ bias, float* __restrict__ Cp,
    int M, int N, int K, long sA, long sB, long sC)
{
    __shared__ unsigned short Ah[128 * 40];
    __shared__ unsigned short Al[128 * 40];
    __shared__ unsigned short Bh[128 * 40];
    __shared__ unsigned short Bl[128 * 40];

    const int t = threadIdx.x;
    const int z = blockIdx.z;
    const int m0 = blockIdx.y * 128, n0 = blockIdx.x * 128;

    float* C = Cp + (size_t)z * sC;

    const int wid = t >> 6, lane = t & 63;
    const int wr = (wid >> 1) * 64, wc = (wid & 1) * 64;
    const int lr = lane & 15, lk = lane >> 4;

    f32x4 acc[4][4];
    #pragma unroll
    for (int i = 0; i < 4; ++i)
        #pragma unroll
        for (int j = 0; j < 4; ++j) acc[i][j] = (f32x4){0.f, 0.f, 0.f, 0.f};

    const int sr = t >> 1;            // staging row 0..127
    const int sc = (t & 1) * 16;      // staging col elem base (16 elems each)

    for (int k0 = 0; k0 < K; k0 += 32) {
        // ---- stage A hi/lo
        {
            char* dh = (char*)Ah + sr * 80 + sc * 2;
            char* dl = (char*)Al + sr * 80 + sc * 2;
            if (TA_SPLIT) {
                size_t off = (size_t)z * sA + (size_t)(m0 + sr) * K + k0 + sc;
                const unsigned short* shp = Ahi + off;
                const unsigned short* slp = Alo + off;
                *(uint4*)dh = *(const uint4*)(shp);
                *(uint4*)(dh + 16) = *(const uint4*)(shp + 8);
                *(uint4*)dl = *(const uint4*)(slp);
                *(uint4*)(dl + 16) = *(const uint4*)(slp + 8);
            } else {
                const float* src = Af + (size_t)z * sA + (size_t)(m0 + sr) * K + k0 + sc;
                float v[16];
                *(float4*)(v)      = *(const float4*)(src);
                *(float4*)(v + 4)  = *(const float4*)(src + 4);
                *(float4*)(v + 8)  = *(const float4*)(src + 8);
                *(float4*)(v + 12) = *(const float4*)(src + 12);
                unsigned short hh[16], ll[16];
                #pragma unroll
                for (int i = 0; i < 16; ++i) {
                    unsigned short h = f2bf(v[i]);
                    hh[i] = h;
                    ll[i] = f2bf(v[i] - bf2f(h));
                }
                *(uint4*)dh = *(uint4*)hh;
                *(uint4*)(dh + 16) = *(uint4*)(hh + 8);
                *(uint4*)dl = *(uint4*)ll;
                *(uint4*)(dl + 16) = *(uint4*)(ll + 8);
            }
        }
        // ---- stage B hi/lo
        {
            size_t off = (size_t)z * sB + (size_t)(n0 + sr) * K + k0 + sc;
            const unsigned short* shp = Bhi + off;
            const unsigned short* slp = Blo + off;
            char* dh = (char*)Bh + sr * 80 + sc * 2;
            char* dl = (char*)Bl + sr * 80 + sc * 2;
            *(uint4*)dh = *(const uint4*)(shp);
            *(uint4*)(dh + 16) = *(const uint4*)(shp + 8);
            *(uint4*)dl = *(const uint4*)(slp);
            *(uint4*)(dl + 16) = *(const uint4*)(slp + 8);
        }
        __syncthreads();

        bf16x8 ah[4], al[4], bh[4], bl[4];
        #pragma unroll
        for (int mt = 0; mt < 4; ++mt) {
            int r = wr + mt * 16 + lr;
            ah[mt] = *(const bf16x8*)((const char*)Ah + r * 80 + lk * 16);
            al[mt] = *(const bf16x8*)((const char*)Al + r * 80 + lk * 16);
        }
        #pragma unroll
        for (int nt = 0; nt < 4; ++nt) {
            int r = wc + nt * 16 + lr;
            bh[nt] = *(const bf16x8*)((const char*)Bh + r * 80 + lk * 16);
            bl[nt] = *(const bf16x8*)((const char*)Bl + r * 80 + lk * 16);
        }
        #pragma unroll
        for (int mt = 0; mt < 4; ++mt)
            #pragma unroll
            for (int nt = 0; nt < 4; ++nt) {
                acc[mt][nt] = __builtin_amdgcn_mfma_f32_16x16x32_bf16(ah[mt], bh[nt], acc[mt][nt], 0, 0, 0);
                acc[mt][nt] = __builtin_amdgcn_mfma_f32_16x16x32_bf16(al[mt], bh[nt], acc[mt][nt], 0, 0, 0);
                acc[mt][nt] = __builtin_amdgcn_mfma_f32_16x16x32_bf16(ah[mt], bl[nt], acc[mt][nt], 0, 0, 0);
            }
        __syncthreads();
    }

    // epilogue: C/D layout col=lane&15, row=(lane>>4)*4+reg
    #pragma unroll
    for (int nt = 0; nt < 4; ++nt) {
        int col = n0 + wc + nt * 16 + (lane & 15);
        float bv = bias ? bias[col] : 0.0f;
        #pragma unroll
        for (int mt = 0; mt < 4; ++mt) {
            #pragma unroll
            for (int i = 0; i < 4; ++i) {
                int row = m0 + wr + mt * 16 + (lane >> 4) * 4 + i;
                float x = acc[mt][nt][i] + bv;
                if (ACT == 1) x = 0.5f * x * (1.0f + erff(x * 0.70710678118654752f));
                C[(size_t)row * N + col] = x;
            }
        }
    }
}

static void gemm_f32A(int act, const float* A,
                      const unsigned short* Bhi, const unsigned short* Blo,
                      const float* bias, float* C, int M, int N, int K,
                      long sA, long sB, long sC, int Z, hipStream_t st)
{
    dim3 g(N / 128, M / 128, Z), b(256);
    if (act) sgemm<0, 1><<<g, b, 0, st>>>(A, nullptr, nullptr, Bhi, Blo, bias, C, M, N, K, sA, sB, sC);
    else     sgemm<0, 0><<<g, b, 0, st>>>(A, nullptr, nullptr, Bhi, Blo, bias, C, M, N, K, sA, sB, sC);
}

static void gemm_splitA(const unsigned short* Ahi, const unsigned short* Alo,
                        const unsigned short* Bhi, const unsigned short* Blo,
                        const float* bias, float* C, int M, int N, int K,
                        long sA, long sB, long sC, int Z, hipStream_t st)
{
    dim3 g(N / 128, M / 128, Z), b(256);
    sgemm<1, 0><<<g, b, 0, st>>>(nullptr, Ahi, Alo, Bhi, Blo, bias, C, M, N, K, sA, sB, sC);
}

// ---------------------------------------------------------------------------
// fp32 -> split bf16 hi/lo (n multiple of 1024)
// ---------------------------------------------------------------------------
__global__ __launch_bounds__(256) void cvt_split(const float* __restrict__ in,
                                                 unsigned short* __restrict__ hi,
                                                 unsigned short* __restrict__ lo)
{
    size_t i = ((size_t)blockIdx.x * 256 + threadIdx.x) * 4;
    float4 v = *(const float4*)(in + i);
    ushort4 h, l;
    h.x = f2bf(v.x); l.x = f2bf(v.x - bf2f(h.x));
    h.y = f2bf(v.y); l.y = f2bf(v.y - bf2f(h.y));
    h.z = f2bf(v.z); l.z = f2bf(v.z - bf2f(h.z));
    h.w = f2bf(v.w); l.w = f2bf(v.w - bf2f(h.w));
    *(ushort4*)(hi + i) = h;
    *(ushort4*)(lo + i) = l;
}

// ---------------------------------------------------------------------------
// bf16 (R,C) -> (C,R) transpose, z-batched. R,C multiples of 64.
// ---------------------------------------------------------------------------
__global__ __launch_bounds__(256) void tcvt_bf16(const unsigned short* __restrict__ in,
                                                 unsigned short* __restrict__ out,
                                                 int R, int C)
{
    __shared__ unsigned short tile[64 * 72];
    int z = blockIdx.z;
    in += (size_t)z * R * C;
    out += (size_t)z * R * C;
    int r0 = blockIdx.y * 64, c0 = blockIdx.x * 64;
    int t = threadIdx.x;
    int tr = t >> 2, tc = (t & 3) * 16;

    uint4 q0 = *(const uint4*)(in + (size_t)(r0 + tr) * C + c0 + tc);
    uint4 q1 = *(const uint4*)(in + (size_t)(r0 + tr) * C + c0 + tc + 8);
    unsigned short e[16];
    *(uint4*)(e) = q0;
    *(uint4*)(e + 8) = q1;
    #pragma unroll
    for (int i = 0; i < 16; ++i) tile[(tc + i) * 72 + tr] = e[i];
    __syncthreads();

    uint4 o0 = *(const uint4*)(&tile[tr * 72 + tc]);
    uint4 o1 = *(const uint4*)(&tile[tr * 72 + tc + 8]);
    *(uint4*)(out + (size_t)(c0 + tr) * R + r0 + tc) = o0;
    *(uint4*)(out + (size_t)(c0 + tr) * R + r0 + tc + 8) = o1;
}

// ---------------------------------------------------------------------------
// bias combine
// ---------------------------------------------------------------------------
__global__ __launch_bounds__(256) void bias_sum_kernel(
    const float* bihF, const float* bhhF, const float* bihB, const float* bhhB,
    float* out)
{
    int i = blockIdx.x * 256 + threadIdx.x;
    if (i < 1024) out[i] = bihF[i] + bhhF[i];
    else out[i] = bihB[i - 1024] + bhhB[i - 1024];
}

// ---------------------------------------------------------------------------
// LSTM recurrence v6: MFMA + register-resident weights, MALL sync.
// grid = 32 blocks (dir = bid>>4, slice = bid&15), block = 256 (4 waves).
// Wave g owns gate g for the block's 16 units. Its 8 B-fragments (split
// hi/lo bf16 of Whh rows g*256+slice*16+u) live in 64 VGPRs, loaded ONCE.
// Per step: stage h (hi|lo packed u64 via MALL atomics) into LDS
// [16 batches][264] bf16, each wave does 24 mfma_16x16x32 (3-pass split),
// gates exchanged through LDS, elementwise update, h repacked to MALL.
// Frag mappings copied from verified sgemm: A-row/B-row = lane&15,
// K-chunk = (lane>>4)*8 elems; C: col=lane&15(unit), row=(lane>>4)*4+i(batch).
// LDS h stride 528B -> 2-way conflicts only (free, m136).
// Sync: r5's fence-free AGENT-scope atomic flags (release = vmcnt(0)+barrier).
// ---------------------------------------------------------------------------
__global__ __launch_bounds__(256) void lstm_rec6(
    const float* __restrict__ preF, const float* __restrict__ preB,
    const float* __restrict__ WhhF, const float* __restrict__ WhhB,
    unsigned long long* __restrict__ hg,   // [2 parity][2 dir][16 b][128] u64
    int* __restrict__ flags,               // [32], zeroed before launch
    unsigned short* __restrict__ fhi, unsigned short* __restrict__ flo)
{
    const int bid = blockIdx.x;
    const int dir = bid >> 4, slice = bid & 15;
    const float* pre = dir ? preB : preF;
    const float* Whh = dir ? WhhB : WhhF;

    const int tid = threadIdx.x;
    const int wv = tid >> 6;            // wave = gate 0..3 (i,f,g,o)
    const int lane = tid & 63;
    const int lr = lane & 15;           // frag row (batch for A / unit for B)
    const int lk = lane >> 4;           // frag K-chunk
    const int eb = tid >> 4;            // elementwise batch 0..15
    const int eu = tid & 15;            // elementwise unit-local 0..15

    __shared__ unsigned short hh[16 * 264];   // h hi, row=batch stride 528B
    __shared__ unsigned short hl[16 * 264];   // h lo
    __shared__ float gx[4][16][17];           // [gate][batch][unit] pad 17

    // ---- one-time: weight fragments into registers (split hi/lo)
    bf16x8 wfh[8], wfl[8];
    {
        const float* wrow = Whh + (size_t)(wv * 256 + slice * 16 + lr) * 256 + lk * 8;
        #pragma unroll
        for (int kt = 0; kt < 8; ++kt) {
            float4 a = *(const float4*)(wrow + kt * 32);
            float4 b = *(const float4*)(wrow + kt * 32 + 4);
            float v[8] = {a.x, a.y, a.z, a.w, b.x, b.y, b.z, b.w};
            unsigned short hhv[8], llv[8];
            #pragma unroll
            for (int i = 0; i < 8; ++i) {
                unsigned short h = f2bf(v[i]);
                hhv[i] = h;
                llv[i] = f2bf(v[i] - bf2f(h));
            }
            wfh[kt] = *(bf16x8*)hhv;
            wfl[kt] = *(bf16x8*)llv;
        }
    }
    // zero h LDS (step 0 uses h = 0)
    for (int i = tid; i < 16 * 264; i += 256) { hh[i] = 0; hl[i] = 0; }

    float c = 0.0f;                     // cell state for (eb, eu)
    __syncthreads();

    for (int si = 0; si < NS; ++si) {
        const int s = dir ? (NS - 1 - si) : si;
        // pre loads issued early (hide L2 latency under spin)
        const float* pp = pre + ((size_t)(eb * NS + s)) * 1024 + slice * 16 + eu;
        float pi = pp[0], pf = pp[256], pg = pp[512], po = pp[768];

        if (si > 0) {
            if (tid < 16) {
                while (__hip_atomic_load(&flags[dir * 16 + tid], __ATOMIC_RELAXED,
                                         __HIP_MEMORY_SCOPE_AGENT) < si) {
                    __builtin_amdgcn_s_sleep(1);
                }
            }
            __syncthreads();
            // stage h: 8 u64/thread = 16 units of one batch row
            const unsigned long long* src =
                hg + (size_t)(((si - 1) & 1) * 2 + dir) * 2048;
            const int b2 = tid >> 4, pb = (tid & 15) * 8;
            unsigned short hbuf[16], lbuf[16];
            #pragma unroll
            for (int j = 0; j < 8; ++j) {
                unsigned long long v = __hip_atomic_load(
                    &src[b2 * 128 + pb + j], __ATOMIC_RELAXED,
                    __HIP_MEMORY_SCOPE_AGENT);
                hbuf[2 * j]     = (unsigned short)(v & 0xffff);
                lbuf[2 * j]     = (unsigned short)((v >> 16) & 0xffff);
                hbuf[2 * j + 1] = (unsigned short)((v >> 32) & 0xffff);
                lbuf[2 * j + 1] = (unsigned short)(v >> 48);
            }
            char* dh = (char*)hh + b2 * 528 + (tid & 15) * 32;
            char* dl = (char*)hl + b2 * 528 + (tid & 15) * 32;
            *(uint4*)dh        = *(uint4*)(hbuf);
            *(uint4*)(dh + 16) = *(uint4*)(hbuf + 8);
            *(uint4*)dl        = *(uint4*)(lbuf);
            *(uint4*)(dl + 16) = *(uint4*)(lbuf + 8);
            __syncthreads();
        }

        // ---- MFMA: this wave's gate for 16 batches x 16 units
        f32x4 acc = (f32x4){0.f, 0.f, 0.f, 0.f};
        #pragma unroll
        for (int kt = 0; kt < 8; ++kt) {
            const char* hp = (const char*)hh + lr * 528 + kt * 64 + lk * 16;
            const char* lp = (const char*)hl + lr * 528 + kt * 64 + lk * 16;
            bf16x8 ah = *(const bf16x8*)hp;
            bf16x8 al = *(const bf16x8*)lp;
            acc = __builtin_amdgcn_mfma_f32_16x16x32_bf16(ah, wfh[kt], acc, 0, 0, 0);
            acc = __builtin_amdgcn_mfma_f32_16x16x32_bf16(al, wfh[kt], acc, 0, 0, 0);
            acc = __builtin_amdgcn_mfma_f32_16x16x32_bf16(ah, wfl[kt], acc, 0, 0, 0);
        }
        #pragma unroll
        for (int i = 0; i < 4; ++i) gx[wv][lk * 4 + i][lr] = acc[i];
        __syncthreads();

        // ---- elementwise LSTM update for (eb, eu)
        float ai = gx[0][eb][eu] + pi;
        float af = gx[1][eb][eu] + pf;
        float ag = gx[2][eb][eu] + pg;
        float ao = gx[3][eb][eu] + po;
        float gi = 1.0f / (1.0f + expf(-ai));
        float gf = 1.0f / (1.0f + expf(-af));
        float gg = tanhf(ag);
        float go = 1.0f / (1.0f + expf(-ao));
        c = gf * c + gi * gg;
        float h = go * tanhf(c);

        unsigned short h16 = f2bf(h);
        unsigned short l16 = f2bf(h - bf2f(h16));
        unsigned my = (unsigned)h16 | ((unsigned)l16 << 16);
        unsigned oth = __shfl_xor(my, 1);          // lane parity == eu parity
        if ((eu & 1) == 0) {
            unsigned long long v = (unsigned long long)my |
                                   ((unsigned long long)oth << 32);
            unsigned long long* dst =
                hg + (size_t)((si & 1) * 2 + dir) * 2048;
            __hip_atomic_store(&dst[eb * 128 + slice * 8 + (eu >> 1)], v,
                               __ATOMIC_RELAXED, __HIP_MEMORY_SCOPE_AGENT);
        }
        size_t oi = ((size_t)(eb * NS + s)) * 512 + dir * 256 + slice * 16 + eu;
        fhi[oi] = h16;
        flo[oi] = l16;

        // release: h stores visible at MALL before flag
        asm volatile("s_waitcnt vmcnt(0)" ::: "memory");
        __syncthreads();
        if (tid == 0)
            __hip_atomic_store(&flags[bid], si + 1, __ATOMIC_RELAXED,
                               __HIP_MEMORY_SCOPE_AGENT);
    }
}

// ---------------------------------------------------------------------------
// row softmax in place: grid = rows, block = 256
// ---------------------------------------------------------------------------
__global__ __launch_bounds__(256) void softmax_kernel(float* __restrict__ X, int N)
{
    float* row = X + (size_t)blockIdx.x * N;
    int t = threadIdx.x;
    float m = -1e30f;
    for (int j = t; j < N; j += 256) m = fmaxf(m, row[j]);
    for (int o = 32; o; o >>= 1) m = fmaxf(m, __shfl_xor(m, o));
    __shared__ float lm[4];
    if ((t & 63) == 0) lm[t >> 6] = m;
    __syncthreads();
    m = fmaxf(fmaxf(lm[0], lm[1]), fmaxf(lm[2], lm[3]));
    float s = 0.0f;
    for (int j = t; j < N; j += 256) { float e = expf(row[j] - m); row[j] = e; s += e; }
    for (int o = 32; o; o >>= 1) s += __shfl_xor(s, o);
    __shared__ float ls[4];
    if ((t & 63) == 0) ls[t >> 6] = s;
    __syncthreads();
    s = ls[0] + ls[1] + ls[2] + ls[3];
    float inv = 1.0f / s;
    for (int j = t; j < N; j += 256) row[j] *= inv;
}

// ---------------------------------------------------------------------------
// LayerNorm rows of 512 fp32 -> split bf16 out. grid = rows, block = 256.
// ---------------------------------------------------------------------------
__global__ __launch_bounds__(256) void layernorm_split(
    const float* __restrict__ X, const float* __restrict__ g, const float* __restrict__ b,
    unsigned short* __restrict__ ohi, unsigned short* __restrict__ olo)
{
    const float* row = X + (size_t)blockIdx.x * 512;
    size_t ob = (size_t)blockIdx.x * 512;
    int t = threadIdx.x;
    float x0 = row[t], x1 = row[t + 256];
    float s = x0 + x1, sq = x0 * x0 + x1 * x1;
    for (int o = 32; o; o >>= 1) { s += __shfl_xor(s, o); sq += __shfl_xor(sq, o); }
    __shared__ float ls[8];
    int w = t >> 6;
    if ((t & 63) == 0) { ls[w] = s; ls[4 + w] = sq; }
    __syncthreads();
    s = ls[0] + ls[1] + ls[2] + ls[3];
    sq = ls[4] + ls[5] + ls[6] + ls[7];
    float mu = s * (1.0f / 512.0f);
    float var = sq * (1.0f / 512.0f) - mu * mu;
    float inv = rsqrtf(var + 1e-5f);
    float y0 = (x0 - mu) * inv * g[t]       + b[t];
    float y1 = (x1 - mu) * inv * g[t + 256] + b[t + 256];
    unsigned short h0 = f2bf(y0), h1 = f2bf(y1);
    ohi[ob + t]       = h0;  olo[ob + t]       = f2bf(y0 - bf2f(h0));
    ohi[ob + t + 256] = h1;  olo[ob + t + 256] = f2bf(y1 - bf2f(h1));
}

// ---------------------------------------------------------------------------
// out[b,h] = dot(q[b,h,:], projT[h,:]) with hi+lo reconstruction
// ---------------------------------------------------------------------------
__global__ __launch_bounds__(256) void outproj3(
    const unsigned short* __restrict__ qhi, const unsigned short* __restrict__ qlo,
    const unsigned short* __restrict__ phi, const unsigned short* __restrict__ plo,
    float* __restrict__ out)
{
    int gw = blockIdx.x * 4 + (threadIdx.x >> 6);  // b*1024+h
    int lane = threadIdx.x & 63;
    int h = gw & 1023;
    uint4 qh = ((const uint4*)(qhi + (size_t)gw * 512))[lane];
    uint4 ql = ((const uint4*)(qlo + (size_t)gw * 512))[lane];
    uint4 ph = ((const uint4*)(phi + (size_t)h * 512))[lane];
    uint4 pl = ((const uint4*)(plo + (size_t)h * 512))[lane];
    unsigned short qhe[8], qle[8], phe[8], ple[8];
    *(uint4*)qhe = qh; *(uint4*)qle = ql; *(uint4*)phe = ph; *(uint4*)ple = pl;
    float s = 0.0f;
    #pragma unroll
    for (int i = 0; i < 8; ++i) {
        float q = bf2f(qhe[i]) + bf2f(qle[i]);
        float p = bf2f(phe[i]) + bf2f(ple[i]);
        s += q * p;
    }
    for (int o = 32; o; o >>= 1) s += __shfl_xor(s, o);
    if (lane == 0) out[gw] = s;
}

// ---------------------------------------------------------------------------
// launcher
// ---------------------------------------------------------------------------
extern "C" void kernel_launch(void* const* d_in, const int* in_sizes, int n_in,
                              void* d_out, int out_size, void* d_ws, size_t ws_size,
                              hipStream_t stream)
{
    (void)in_sizes; (void)n_in; (void)out_size; (void)ws_size;

    const float* x     = (const float*)d_in[0];   // (16,256,512)
    const float* le    = (const float*)d_in[1];   // (1024,512)
    const float* proj  = (const float*)d_in[2];   // (512,1024)
    const float* WihF  = (const float*)d_in[3];   // (1024,512)
    const float* WhhF  = (const float*)d_in[4];   // (1024,256)
    const float* bihF  = (const float*)d_in[5];
    const float* bhhF  = (const float*)d_in[6];
    const float* WihB  = (const float*)d_in[7];
    const float* WhhB  = (const float*)d_in[8];
    const float* bihB  = (const float*)d_in[9];
    const float* bhhB  = (const float*)d_in[10];
    const float* w1    = (const float*)d_in[11];  // (2,512,2048)
    const float* b1    = (const float*)d_in[12];  // (2,2048)
    const float* w2    = (const float*)d_in[13];  // (2,2048,512)
    const float* b2    = (const float*)d_in[14];  // (2,512)
    const float* lng   = (const float*)d_in[15];  // (2,512)
    const float* lnb   = (const float*)d_in[16];  // (2,512)
    float* out = (float*)d_out;
    float* ws  = (float*)d_ws;
    unsigned short* wsu = (unsigned short*)d_ws;

    const size_t MEG = 1048576;
    // float-offset layout
    const size_t LNSRC = 0;              // 8M: preF/preB -> qt hi/lo (L1 attn) -> FFN2 out
    const size_t HB    = 8 * MEG;        // 8M: attn value output q2attn fp32
    const size_t AR    = 16 * MEG;       // 8M: wsc/q1s/s2s scratch; ffh
    const size_t QHI   = 24 * MEG;       // 4M fl (8M elems bf16)
    const size_t QLO   = 28 * MEG;
    const size_t FHI   = 32 * MEG;       // 1M fl
    const size_t FLO   = 33 * MEG;
    const size_t FTHI  = 34 * MEG;
    const size_t FTLO  = 35 * MEG;
    const size_t LEHI  = 36 * MEG;                 // .25M fl
    const size_t LELO  = LEHI  + MEG / 4;
    const size_t LETHI = LELO  + MEG / 4;
    const size_t LETLO = LETHI + MEG / 4;
    const size_t WIHFH = LETLO + MEG / 4;
    const size_t WIHFL = WIHFH + MEG / 4;
    const size_t WIHBH = WIHFL + MEG / 4;
    const size_t WIHBL = WIHBH + MEG / 4;
    const size_t SYNC  = WIHBL + MEG / 4;          // flags[32] + hg u64
    const size_t W1TH  = SYNC  + MEG / 4;          // .5M fl (1M elems)
    const size_t W1TL  = W1TH  + MEG / 2;
    const size_t W2TH  = W1TL  + MEG / 2;
    const size_t W2TL  = W2TH  + MEG / 2;
    const size_t WTH   = W2TL  + MEG / 2;          // .5M fl tmp
    const size_t WTL   = WTH   + MEG / 2;
    const size_t PTH   = WTL   + MEG / 2;          // .25M fl
    const size_t PTL   = PTH   + MEG / 4;
    const size_t BSUM  = PTL   + MEG / 4;

    float* preF   = ws + LNSRC;
    float* preB   = ws + LNSRC + 4 * MEG;
    float* lnsrc  = ws + LNSRC;
    float* q2a    = ws + HB;
    float* arena  = ws + AR;
    float* bsum   = ws + BSUM;
    int*   flags  = (int*)(ws + SYNC);             // 32 ints
    unsigned long long* hg = (unsigned long long*)(ws + SYNC + 1024);  // 8192 u64
    unsigned short* qthi  = wsu + 2 * LNSRC;       // alias (layer-1 attn only)
    unsigned short* qtlo  = wsu + 2 * (LNSRC + 4 * MEG);
    unsigned short* qhi   = wsu + 2 * QHI;
    unsigned short* qlo   = wsu + 2 * QLO;
    unsigned short* fhi   = wsu + 2 * FHI;
    unsigned short* flo   = wsu + 2 * FLO;
    unsigned short* fthi  = wsu + 2 * FTHI;
    unsigned short* ftlo  = wsu + 2 * FTLO;
    unsigned short* lehi  = wsu + 2 * LEHI;
    unsigned short* lelo  = wsu + 2 * LELO;
    unsigned short* lethi = wsu + 2 * LETHI;
    unsigned short* letlo = wsu + 2 * LETLO;
    unsigned short* wihFh = wsu + 2 * WIHFH;
    unsigned short* wihFl = wsu + 2 * WIHFL;
    unsigned short* wihBh = wsu + 2 * WIHBH;
    unsigned short* wihBl = wsu + 2 * WIHBL;
    unsigned short* w1th  = wsu + 2 * W1TH;
    unsigned short* w1tl  = wsu + 2 * W1TL;
    unsigned short* w2th  = wsu + 2 * W2TH;
    unsigned short* w2tl  = wsu + 2 * W2TL;
    unsigned short* wth   = wsu + 2 * WTH;
    unsigned short* wtl   = wsu + 2 * WTL;
    unsigned short* pth   = wsu + 2 * PTH;
    unsigned short* ptl   = wsu + 2 * PTL;

    // ---- prep
    bias_sum_kernel<<<8, 256, 0, stream>>>(bihF, bhhF, bihB, bhhB, bsum);
    cvt_split<<<512, 256, 0, stream>>>(WihF, wihFh, wihFl);
    cvt_split<<<512, 256, 0, stream>>>(WihB, wihBh, wihBl);
    cvt_split<<<512, 256, 0, stream>>>(le, lehi, lelo);
    { dim3 g(512 / 64, 1024 / 64, 1);
      tcvt_bf16<<<g, 256, 0, stream>>>(lehi, lethi, 1024, 512);
      tcvt_bf16<<<g, 256, 0, stream>>>(lelo, letlo, 1024, 512); }
    hipMemsetAsync(flags, 0, 32 * sizeof(int), stream);

    // ---- LSTM input projections: pre = x @ Wih^T + (bih+bhh)
    gemm_f32A(0, x, wihFh, wihFl, bsum,        preF, NB * NS, 1024, ND, 0, 0, 0, 1, stream);
    gemm_f32A(0, x, wihBh, wihBl, bsum + 1024, preB, NB * NS, 1024, ND, 0, 0, 0, 1, stream);

    // ---- recurrence -> features (split bf16), cooperative 32-block kernel
    lstm_rec6<<<32, 256, 0, stream>>>(preF, preB, WhhF, WhhB, hg, flags, fhi, flo);
    { dim3 g(512 / 64, 256 / 64, 16);
      tcvt_bf16<<<g, 256, 0, stream>>>(fhi, fthi, 256, 512);
      tcvt_bf16<<<g, 256, 0, stream>>>(flo, ftlo, 256, 512); }

    // ---- layers
    for (int l = 0; l < 2; ++l) {
        const float* b1l = b1 + (size_t)l * NF;
        const float* b2l = b2 + (size_t)l * ND;
        const float* gl  = lng + (size_t)l * ND;
        const float* bl  = lnb + (size_t)l * ND;

        // FFN weights -> split bf16, transposed
        cvt_split<<<1024, 256, 0, stream>>>(w1 + (size_t)l * ND * NF, wth, wtl);   // (512,2048)
        { dim3 g(NF / 64, ND / 64, 1);
          tcvt_bf16<<<g, 256, 0, stream>>>(wth, w1th, ND, NF);
          tcvt_bf16<<<g, 256, 0, stream>>>(wtl, w1tl, ND, NF); }                   // (2048,512)
        cvt_split<<<1024, 256, 0, stream>>>(w2 + (size_t)l * NF * ND, wth, wtl);   // (2048,512)
        { dim3 g(ND / 64, NF / 64, 1);
          tcvt_bf16<<<g, 256, 0, stream>>>(wth, w2th, NF, ND);
          tcvt_bf16<<<g, 256, 0, stream>>>(wtl, w2tl, NF, ND); }                   // (512,2048)

        if (l == 0) {
            // query identical across batch: shared self-attn + q1
            float* wsc = arena;                  // 1M (1024,1024)
            float* q1s = arena + MEG;            // .5M (1024,512)
            float* s2s = arena + 2 * MEG;        // 4M (16,1024,256)
            gemm_f32A(0, le, lehi, lelo, nullptr, wsc, NH, NH, ND, 0, 0, 0, 1, stream);
            softmax_kernel<<<NH, 256, 0, stream>>>(wsc, NH);
            gemm_f32A(0, wsc, lethi, letlo, nullptr, q1s, NH, ND, NH, 0, 0, 0, 1, stream);
            gemm_f32A(0, q1s, fhi, flo, nullptr, s2s, NH, NS, ND,
                      0, (long)NS * ND, (long)NH * NS, 16, stream);
            softmax_kernel<<<NB * NH, 256, 0, stream>>>(s2s, NS);
            gemm_f32A(0, s2s, fthi, ftlo, nullptr, q2a, NH, ND, NS,
                      (long)NH * NS, (long)ND * NS, (long)NH * ND, 16, stream);
        } else {
            { dim3 g(512 / 64, 1024 / 64, 16);
              tcvt_bf16<<<g, 256, 0, stream>>>(qhi, qthi, 1024, 512);
              tcvt_bf16<<<g, 256, 0, stream>>>(qlo, qtlo, 1024, 512); }
            float* wsc4 = arena;                 // 4M (4,1024,1024)
            float* q1s4 = arena + 4 * MEG;       // 2M (4,1024,512)
            float* s2s4 = arena + 6 * MEG;       // 1M (4,1024,256)
            for (int g4 = 0; g4 < 4; ++g4) {
                size_t qo = (size_t)g4 * 4;
                gemm_splitA(qhi + qo * NH * ND, qlo + qo * NH * ND,
                            qhi + qo * NH * ND, qlo + qo * NH * ND,
                            nullptr, wsc4, NH, NH, ND,
                            (long)NH * ND, (long)NH * ND, (long)NH * NH, 4, stream);
                softmax_kernel<<<4 * NH, 256, 0, stream>>>(wsc4, NH);
                gemm_f32A(0, wsc4, qthi + qo * ND * NH, qtlo + qo * ND * NH,
                          nullptr, q1s4, NH, ND, NH,
                          (long)NH * NH, (long)ND * NH, (long)NH * ND, 4, stream);
                gemm_f32A(0, q1s4, fhi + qo * NS * ND, flo + qo * NS * ND,
                          nullptr, s2s4, NH, NS, ND,
                          (long)NH * ND, (long)NS * ND, (long)NH * NS, 4, stream);
                softmax_kernel<<<4 * NH, 256, 0, stream>>>(s2s4, NS);
                gemm_f32A(0, s2s4, fthi + qo * ND * NS, ftlo + qo * ND * NS,
                          nullptr, q2a + qo * NH * ND, NH, ND, NS,
                          (long)NH * NS, (long)ND * NS, (long)NH * ND, 4, stream);
            }
        }

        // FFN: 4 chunks of 4096 rows; q2a -> ffh(arena) -> lnsrc
        float* ffh = arena;
        for (int ch = 0; ch < 4; ++ch) {
            const float* rows_in = q2a + (size_t)ch * 4096 * ND;
            float* rows_out      = lnsrc + (size_t)ch * 4096 * ND;
            gemm_f32A(1, rows_in, w1th, w1tl, b1l, ffh, 4096, NF, ND, 0, 0, 0, 1, stream);
            gemm_f32A(0, ffh, w2th, w2tl, b2l, rows_out, 4096, ND, NF, 0, 0, 0, 1, stream);
        }
        layernorm_split<<<NB * NH, 256, 0, stream>>>(lnsrc, gl, bl, qhi, qlo);
    }

    // ---- final projection
    cvt_split<<<512, 256, 0, stream>>>(proj, wth, wtl);                    // (512,1024)
    { dim3 g(1024 / 64, 512 / 64, 1);
      tcvt_bf16<<<g, 256, 0, stream>>>(wth, pth, 512, 1024);
      tcvt_bf16<<<g, 256, 0, stream>>>(wtl, ptl, 512, 1024); }             // (1024,512)
    outproj3<<<4096, 256, 0, stream>>>(qhi, qlo, pth, ptl, out);
}

// Round 7
// 2571.797 us; speedup vs baseline: 6.8861x; 1.1460x over previous
//
#include <hip/hip_runtime.h>
#include <hip/hip_bf16.h>
#include <math.h>

// Problem dims
#define NB 16
#define NS 256
#define ND 512
#define NH 1024
#define NF 2048
#define NHID 256

typedef __attribute__((ext_vector_type(8))) short bf16x8;
typedef __attribute__((ext_vector_type(4))) float f32x4;

__device__ __forceinline__ unsigned short f2bf(float f) {
    unsigned u = __float_as_uint(f);
    unsigned r = u + 0x7fffu + ((u >> 16) & 1u);
    return (unsigned short)(r >> 16);
}
__device__ __forceinline__ float bf2f(unsigned short h) {
    return __uint_as_float(((unsigned)h) << 16);
}

// ---------------------------------------------------------------------------
// Split-bf16 MFMA GEMM v2: C[M,N] = A[M,K] @ B[N,K]^T (+bias)(+gelu)
// ALL operands pre-split hi/lo bf16. 3-pass: Ah*Bh + Al*Bh + Ah*Bl (~fp32).
// Staging: global_load_lds width-16, linear LDS 128x32 bf16 per buffer
// (m97 structure). Output fp32 (OUT_SPLIT=0) or split hi/lo (OUT_SPLIT=1).
// Tile 128x128, BK=32, 256 thr (4 waves, 2x2 of 64x64). M,N%128==0, K%32==0.
// ---------------------------------------------------------------------------
template<int ACT, int OUT_SPLIT>
__global__ __launch_bounds__(256) void sgemm2(
    const unsigned short* __restrict__ Ahi, const unsigned short* __restrict__ Alo,
    const unsigned short* __restrict__ Bhi, const unsigned short* __restrict__ Blo,
    const float* __restrict__ bias,
    float* __restrict__ C, unsigned short* __restrict__ Chi, unsigned short* __restrict__ Clo,
    int M, int N, int K, long sA, long sB, long sC)
{
    __shared__ unsigned short Ah[128 * 32];
    __shared__ unsigned short Al[128 * 32];
    __shared__ unsigned short Bh[128 * 32];
    __shared__ unsigned short Bl[128 * 32];

    const int t = threadIdx.x;
    const int z = blockIdx.z;
    const int m0 = blockIdx.y * 128, n0 = blockIdx.x * 128;
    const int wid = t >> 6, lane = t & 63;
    const int wr = (wid >> 1) * 64, wc = (wid & 1) * 64;
    const int lr = lane & 15, lk = lane >> 4;
    const int rl = lane >> 2, sl = lane & 3;     // staging: row-in-16, 16B slot

    const unsigned short* pAh = Ahi + (size_t)z * sA;
    const unsigned short* pAl = Alo + (size_t)z * sA;
    const unsigned short* pBh = Bhi + (size_t)z * sB;
    const unsigned short* pBl = Blo + (size_t)z * sB;

    f32x4 acc[4][4];
    #pragma unroll
    for (int i = 0; i < 4; ++i)
        #pragma unroll
        for (int j = 0; j < 4; ++j) acc[i][j] = (f32x4){0.f, 0.f, 0.f, 0.f};

    for (int k0 = 0; k0 < K; k0 += 32) {
        // ---- stage 4 buffers via global_load_lds (wave-issue = 16 rows)
        #pragma unroll
        for (int e = 0; e < 2; ++e) {
            const int r = e * 64 + wid * 16 + rl;
            const size_t goA = (size_t)(m0 + r) * K + k0 + sl * 8;
            const size_t goB = (size_t)(n0 + r) * K + k0 + sl * 8;
            const int lo = (e * 64 + wid * 16) * 32;     // elem offset of base
            __builtin_amdgcn_global_load_lds((const void*)(pAh + goA), (void*)&Ah[lo], 16, 0, 0);
            __builtin_amdgcn_global_load_lds((const void*)(pAl + goA), (void*)&Al[lo], 16, 0, 0);
            __builtin_amdgcn_global_load_lds((const void*)(pBh + goB), (void*)&Bh[lo], 16, 0, 0);
            __builtin_amdgcn_global_load_lds((const void*)(pBl + goB), (void*)&Bl[lo], 16, 0, 0);
        }
        __syncthreads();

        bf16x8 ah[4], al[4], bh[4], bl[4];
        #pragma unroll
        for (int mt = 0; mt < 4; ++mt) {
            int rf = wr + mt * 16 + lr;
            ah[mt] = *(const bf16x8*)&Ah[rf * 32 + lk * 8];
            al[mt] = *(const bf16x8*)&Al[rf * 32 + lk * 8];
        }
        #pragma unroll
        for (int nt = 0; nt < 4; ++nt) {
            int rf = wc + nt * 16 + lr;
            bh[nt] = *(const bf16x8*)&Bh[rf * 32 + lk * 8];
            bl[nt] = *(const bf16x8*)&Bl[rf * 32 + lk * 8];
        }
        #pragma unroll
        for (int mt = 0; mt < 4; ++mt)
            #pragma unroll
            for (int nt = 0; nt < 4; ++nt) {
                acc[mt][nt] = __builtin_amdgcn_mfma_f32_16x16x32_bf16(ah[mt], bh[nt], acc[mt][nt], 0, 0, 0);
                acc[mt][nt] = __builtin_amdgcn_mfma_f32_16x16x32_bf16(al[mt], bh[nt], acc[mt][nt], 0, 0, 0);
                acc[mt][nt] = __builtin_amdgcn_mfma_f32_16x16x32_bf16(ah[mt], bl[nt], acc[mt][nt], 0, 0, 0);
            }
        __syncthreads();
    }

    // epilogue: C/D layout col=lane&15, row=(lane>>4)*4+reg (verified)
    #pragma unroll
    for (int nt = 0; nt < 4; ++nt) {
        int col = n0 + wc + nt * 16 + lr;
        float bv = bias ? bias[col] : 0.0f;
        #pragma unroll
        for (int mt = 0; mt < 4; ++mt) {
            #pragma unroll
            for (int i = 0; i < 4; ++i) {
                int row = m0 + wr + mt * 16 + lk * 4 + i;
                float x = acc[mt][nt][i] + bv;
                if (ACT == 1) x = 0.5f * x * (1.0f + erff(x * 0.70710678118654752f));
                size_t oi = (size_t)z * sC + (size_t)row * N + col;
                if (OUT_SPLIT) {
                    unsigned short h = f2bf(x);
                    Chi[oi] = h;
                    Clo[oi] = f2bf(x - bf2f(h));
                } else {
                    C[oi] = x;
                }
            }
        }
    }
}

// fp32 output
static void gemm_f(int act, const unsigned short* Ahi, const unsigned short* Alo,
                   const unsigned short* Bhi, const unsigned short* Blo,
                   const float* bias, float* C, int M, int N, int K,
                   long sA, long sB, long sC, int Z, hipStream_t st)
{
    dim3 g(N / 128, M / 128, Z), b(256);
    if (act) sgemm2<1, 0><<<g, b, 0, st>>>(Ahi, Alo, Bhi, Blo, bias, C, nullptr, nullptr, M, N, K, sA, sB, sC);
    else     sgemm2<0, 0><<<g, b, 0, st>>>(Ahi, Alo, Bhi, Blo, bias, C, nullptr, nullptr, M, N, K, sA, sB, sC);
}
// split output
static void gemm_s(int act, const unsigned short* Ahi, const unsigned short* Alo,
                   const unsigned short* Bhi, const unsigned short* Blo,
                   const float* bias, unsigned short* Chi, unsigned short* Clo,
                   int M, int N, int K, long sA, long sB, long sC, int Z, hipStream_t st)
{
    dim3 g(N / 128, M / 128, Z), b(256);
    if (act) sgemm2<1, 1><<<g, b, 0, st>>>(Ahi, Alo, Bhi, Blo, bias, nullptr, Chi, Clo, M, N, K, sA, sB, sC);
    else     sgemm2<0, 1><<<g, b, 0, st>>>(Ahi, Alo, Bhi, Blo, bias, nullptr, Chi, Clo, M, N, K, sA, sB, sC);
}

// ---------------------------------------------------------------------------
// fp32 -> split bf16 hi/lo (n multiple of 1024)
// ---------------------------------------------------------------------------
__global__ __launch_bounds__(256) void cvt_split(const float* __restrict__ in,
                                                 unsigned short* __restrict__ hi,
                                                 unsigned short* __restrict__ lo)
{
    size_t i = ((size_t)blockIdx.x * 256 + threadIdx.x) * 4;
    float4 v = *(const float4*)(in + i);
    ushort4 h, l;
    h.x = f2bf(v.x); l.x = f2bf(v.x - bf2f(h.x));
    h.y = f2bf(v.y); l.y = f2bf(v.y - bf2f(h.y));
    h.z = f2bf(v.z); l.z = f2bf(v.z - bf2f(h.z));
    h.w = f2bf(v.w); l.w = f2bf(v.w - bf2f(h.w));
    *(ushort4*)(hi + i) = h;
    *(ushort4*)(lo + i) = l;
}

// ---------------------------------------------------------------------------
// bf16 (R,C) -> (C,R) transpose, z-batched. R,C multiples of 64.
// ---------------------------------------------------------------------------
__global__ __launch_bounds__(256) void tcvt_bf16(const unsigned short* __restrict__ in,
                                                 unsigned short* __restrict__ out,
                                                 int R, int C)
{
    __shared__ unsigned short tile[64 * 72];
    int z = blockIdx.z;
    in += (size_t)z * R * C;
    out += (size_t)z * R * C;
    int r0 = blockIdx.y * 64, c0 = blockIdx.x * 64;
    int t = threadIdx.x;
    int tr = t >> 2, tc = (t & 3) * 16;

    uint4 q0 = *(const uint4*)(in + (size_t)(r0 + tr) * C + c0 + tc);
    uint4 q1 = *(const uint4*)(in + (size_t)(r0 + tr) * C + c0 + tc + 8);
    unsigned short e[16];
    *(uint4*)(e) = q0;
    *(uint4*)(e + 8) = q1;
    #pragma unroll
    for (int i = 0; i < 16; ++i) tile[(tc + i) * 72 + tr] = e[i];
    __syncthreads();

    uint4 o0 = *(const uint4*)(&tile[tr * 72 + tc]);
    uint4 o1 = *(const uint4*)(&tile[tr * 72 + tc + 8]);
    *(uint4*)(out + (size_t)(c0 + tr) * R + r0 + tc) = o0;
    *(uint4*)(out + (size_t)(c0 + tr) * R + r0 + tc + 8) = o1;
}

// ---------------------------------------------------------------------------
// bias combine
// ---------------------------------------------------------------------------
__global__ __launch_bounds__(256) void bias_sum_kernel(
    const float* bihF, const float* bhhF, const float* bihB, const float* bhhB,
    float* out)
{
    int i = blockIdx.x * 256 + threadIdx.x;
    if (i < 1024) out[i] = bihF[i] + bhhF[i];
    else out[i] = bihB[i - 1024] + bhhB[i - 1024];
}

// ---------------------------------------------------------------------------
// LSTM recurrence v6 (unchanged from round 5, ~890us): MFMA + reg weights,
// fence-free MALL sync via AGENT-scope relaxed atomics.
// ---------------------------------------------------------------------------
__global__ __launch_bounds__(256) void lstm_rec6(
    const float* __restrict__ preF, const float* __restrict__ preB,
    const float* __restrict__ WhhF, const float* __restrict__ WhhB,
    unsigned long long* __restrict__ hg,   // [2 parity][2 dir][16 b][128] u64
    int* __restrict__ flags,               // [32], zeroed before launch
    unsigned short* __restrict__ fhi, unsigned short* __restrict__ flo)
{
    const int bid = blockIdx.x;
    const int dir = bid >> 4, slice = bid & 15;
    const float* pre = dir ? preB : preF;
    const float* Whh = dir ? WhhB : WhhF;

    const int tid = threadIdx.x;
    const int wv = tid >> 6;            // wave = gate 0..3 (i,f,g,o)
    const int lane = tid & 63;
    const int lr = lane & 15;
    const int lk = lane >> 4;
    const int eb = tid >> 4;            // elementwise batch
    const int eu = tid & 15;            // elementwise unit-local

    __shared__ unsigned short hh[16 * 264];
    __shared__ unsigned short hl[16 * 264];
    __shared__ float gx[4][16][17];

    bf16x8 wfh[8], wfl[8];
    {
        const float* wrow = Whh + (size_t)(wv * 256 + slice * 16 + lr) * 256 + lk * 8;
        #pragma unroll
        for (int kt = 0; kt < 8; ++kt) {
            float4 a = *(const float4*)(wrow + kt * 32);
            float4 b = *(const float4*)(wrow + kt * 32 + 4);
            float v[8] = {a.x, a.y, a.z, a.w, b.x, b.y, b.z, b.w};
            unsigned short hhv[8], llv[8];
            #pragma unroll
            for (int i = 0; i < 8; ++i) {
                unsigned short h = f2bf(v[i]);
                hhv[i] = h;
                llv[i] = f2bf(v[i] - bf2f(h));
            }
            wfh[kt] = *(bf16x8*)hhv;
            wfl[kt] = *(bf16x8*)llv;
        }
    }
    for (int i = tid; i < 16 * 264; i += 256) { hh[i] = 0; hl[i] = 0; }

    float c = 0.0f;
    __syncthreads();

    for (int si = 0; si < NS; ++si) {
        const int s = dir ? (NS - 1 - si) : si;
        const float* pp = pre + ((size_t)(eb * NS + s)) * 1024 + slice * 16 + eu;
        float pi = pp[0], pf = pp[256], pg = pp[512], po = pp[768];

        if (si > 0) {
            if (tid < 16) {
                while (__hip_atomic_load(&flags[dir * 16 + tid], __ATOMIC_RELAXED,
                                         __HIP_MEMORY_SCOPE_AGENT) < si) {
                    __builtin_amdgcn_s_sleep(1);
                }
            }
            __syncthreads();
            const unsigned long long* src =
                hg + (size_t)(((si - 1) & 1) * 2 + dir) * 2048;
            const int b2 = tid >> 4, pb = (tid & 15) * 8;
            unsigned short hbuf[16], lbuf[16];
            #pragma unroll
            for (int j = 0; j < 8; ++j) {
                unsigned long long v = __hip_atomic_load(
                    &src[b2 * 128 + pb + j], __ATOMIC_RELAXED,
                    __HIP_MEMORY_SCOPE_AGENT);
                hbuf[2 * j]     = (unsigned short)(v & 0xffff);
                lbuf[2 * j]     = (unsigned short)((v >> 16) & 0xffff);
                hbuf[2 * j + 1] = (unsigned short)((v >> 32) & 0xffff);
                lbuf[2 * j + 1] = (unsigned short)(v >> 48);
            }
            char* dh = (char*)hh + b2 * 528 + (tid & 15) * 32;
            char* dl = (char*)hl + b2 * 528 + (tid & 15) * 32;
            *(uint4*)dh        = *(uint4*)(hbuf);
            *(uint4*)(dh + 16) = *(uint4*)(hbuf + 8);
            *(uint4*)dl        = *(uint4*)(lbuf);
            *(uint4*)(dl + 16) = *(uint4*)(lbuf + 8);
            __syncthreads();
        }

        f32x4 acc = (f32x4){0.f, 0.f, 0.f, 0.f};
        #pragma unroll
        for (int kt = 0; kt < 8; ++kt) {
            const char* hp = (const char*)hh + lr * 528 + kt * 64 + lk * 16;
            const char* lp = (const char*)hl + lr * 528 + kt * 64 + lk * 16;
            bf16x8 ah = *(const bf16x8*)hp;
            bf16x8 al = *(const bf16x8*)lp;
            acc = __builtin_amdgcn_mfma_f32_16x16x32_bf16(ah, wfh[kt], acc, 0, 0, 0);
            acc = __builtin_amdgcn_mfma_f32_16x16x32_bf16(al, wfh[kt], acc, 0, 0, 0);
            acc = __builtin_amdgcn_mfma_f32_16x16x32_bf16(ah, wfl[kt], acc, 0, 0, 0);
        }
        #pragma unroll
        for (int i = 0; i < 4; ++i) gx[wv][lk * 4 + i][lr] = acc[i];
        __syncthreads();

        float ai = gx[0][eb][eu] + pi;
        float af = gx[1][eb][eu] + pf;
        float ag = gx[2][eb][eu] + pg;
        float ao = gx[3][eb][eu] + po;
        float gi = 1.0f / (1.0f + expf(-ai));
        float gf = 1.0f / (1.0f + expf(-af));
        float gg = tanhf(ag);
        float go = 1.0f / (1.0f + expf(-ao));
        c = gf * c + gi * gg;
        float h = go * tanhf(c);

        unsigned short h16 = f2bf(h);
        unsigned short l16 = f2bf(h - bf2f(h16));
        unsigned my = (unsigned)h16 | ((unsigned)l16 << 16);
        unsigned oth = __shfl_xor(my, 1);
        if ((eu & 1) == 0) {
            unsigned long long v = (unsigned long long)my |
                                   ((unsigned long long)oth << 32);
            unsigned long long* dst =
                hg + (size_t)((si & 1) * 2 + dir) * 2048;
            __hip_atomic_store(&dst[eb * 128 + slice * 8 + (eu >> 1)], v,
                               __ATOMIC_RELAXED, __HIP_MEMORY_SCOPE_AGENT);
        }
        size_t oi = ((size_t)(eb * NS + s)) * 512 + dir * 256 + slice * 16 + eu;
        fhi[oi] = h16;
        flo[oi] = l16;

        asm volatile("s_waitcnt vmcnt(0)" ::: "memory");
        __syncthreads();
        if (tid == 0)
            __hip_atomic_store(&flags[bid], si + 1, __ATOMIC_RELAXED,
                               __HIP_MEMORY_SCOPE_AGENT);
    }
}

// ---------------------------------------------------------------------------
// row softmax: read fp32 X (scratch, overwritten with exp), write split hi/lo
// grid = rows, block = 256
// ---------------------------------------------------------------------------
__global__ __launch_bounds__(256) void softmax_split(
    float* __restrict__ X, unsigned short* __restrict__ Ohi,
    unsigned short* __restrict__ Olo, int N)
{
    float* row = X + (size_t)blockIdx.x * N;
    unsigned short* ohr = Ohi + (size_t)blockIdx.x * N;
    unsigned short* olr = Olo + (size_t)blockIdx.x * N;
    int t = threadIdx.x;
    float m = -1e30f;
    for (int j = t; j < N; j += 256) m = fmaxf(m, row[j]);
    for (int o = 32; o; o >>= 1) m = fmaxf(m, __shfl_xor(m, o));
    __shared__ float lm[4];
    if ((t & 63) == 0) lm[t >> 6] = m;
    __syncthreads();
    m = fmaxf(fmaxf(lm[0], lm[1]), fmaxf(lm[2], lm[3]));
    float s = 0.0f;
    for (int j = t; j < N; j += 256) { float e = expf(row[j] - m); row[j] = e; s += e; }
    for (int o = 32; o; o >>= 1) s += __shfl_xor(s, o);
    __shared__ float ls[4];
    if ((t & 63) == 0) ls[t >> 6] = s;
    __syncthreads();
    s = ls[0] + ls[1] + ls[2] + ls[3];
    float inv = 1.0f / s;
    for (int j = t; j < N; j += 256) {
        float y = row[j] * inv;
        unsigned short h = f2bf(y);
        ohr[j] = h;
        olr[j] = f2bf(y - bf2f(h));
    }
}

// ---------------------------------------------------------------------------
// LayerNorm rows of 512 fp32 -> split bf16 out. grid = rows, block = 256.
// ---------------------------------------------------------------------------
__global__ __launch_bounds__(256) void layernorm_split(
    const float* __restrict__ X, const float* __restrict__ g, const float* __restrict__ b,
    unsigned short* __restrict__ ohi, unsigned short* __restrict__ olo)
{
    const float* row = X + (size_t)blockIdx.x * 512;
    size_t ob = (size_t)blockIdx.x * 512;
    int t = threadIdx.x;
    float x0 = row[t], x1 = row[t + 256];
    float s = x0 + x1, sq = x0 * x0 + x1 * x1;
    for (int o = 32; o; o >>= 1) { s += __shfl_xor(s, o); sq += __shfl_xor(sq, o); }
    __shared__ float ls[8];
    int w = t >> 6;
    if ((t & 63) == 0) { ls[w] = s; ls[4 + w] = sq; }
    __syncthreads();
    s = ls[0] + ls[1] + ls[2] + ls[3];
    sq = ls[4] + ls[5] + ls[6] + ls[7];
    float mu = s * (1.0f / 512.0f);
    float var = sq * (1.0f / 512.0f) - mu * mu;
    float inv = rsqrtf(var + 1e-5f);
    float y0 = (x0 - mu) * inv * g[t]       + b[t];
    float y1 = (x1 - mu) * inv * g[t + 256] + b[t + 256];
    unsigned short h0 = f2bf(y0), h1 = f2bf(y1);
    ohi[ob + t]       = h0;  olo[ob + t]       = f2bf(y0 - bf2f(h0));
    ohi[ob + t + 256] = h1;  olo[ob + t + 256] = f2bf(y1 - bf2f(h1));
}

// ---------------------------------------------------------------------------
// out[b,h] = dot(q[b,h,:], projT[h,:]) with hi+lo reconstruction
// ---------------------------------------------------------------------------
__global__ __launch_bounds__(256) void outproj3(
    const unsigned short* __restrict__ qhi, const unsigned short* __restrict__ qlo,
    const unsigned short* __restrict__ phi, const unsigned short* __restrict__ plo,
    float* __restrict__ out)
{
    int gw = blockIdx.x * 4 + (threadIdx.x >> 6);  // b*1024+h
    int lane = threadIdx.x & 63;
    int h = gw & 1023;
    uint4 qh = ((const uint4*)(qhi + (size_t)gw * 512))[lane];
    uint4 ql = ((const uint4*)(qlo + (size_t)gw * 512))[lane];
    uint4 ph = ((const uint4*)(phi + (size_t)h * 512))[lane];
    uint4 pl = ((const uint4*)(plo + (size_t)h * 512))[lane];
    unsigned short qhe[8], qle[8], phe[8], ple[8];
    *(uint4*)qhe = qh; *(uint4*)qle = ql; *(uint4*)phe = ph; *(uint4*)ple = pl;
    float s = 0.0f;
    #pragma unroll
    for (int i = 0; i < 8; ++i) {
        float q = bf2f(qhe[i]) + bf2f(qle[i]);
        float p = bf2f(phe[i]) + bf2f(ple[i]);
        s += q * p;
    }
    for (int o = 32; o; o >>= 1) s += __shfl_xor(s, o);
    if (lane == 0) out[gw] = s;
}

// ---------------------------------------------------------------------------
// launcher
// ---------------------------------------------------------------------------
extern "C" void kernel_launch(void* const* d_in, const int* in_sizes, int n_in,
                              void* d_out, int out_size, void* d_ws, size_t ws_size,
                              hipStream_t stream)
{
    (void)in_sizes; (void)n_in; (void)out_size; (void)ws_size;

    const float* x     = (const float*)d_in[0];   // (16,256,512)
    const float* le    = (const float*)d_in[1];   // (1024,512)
    const float* proj  = (const float*)d_in[2];   // (512,1024)
    const float* WihF  = (const float*)d_in[3];   // (1024,512)
    const float* WhhF  = (const float*)d_in[4];   // (1024,256)
    const float* bihF  = (const float*)d_in[5];
    const float* bhhF  = (const float*)d_in[6];
    const float* WihB  = (const float*)d_in[7];
    const float* WhhB  = (const float*)d_in[8];
    const float* bihB  = (const float*)d_in[9];
    const float* bhhB  = (const float*)d_in[10];
    const float* w1    = (const float*)d_in[11];  // (2,512,2048)
    const float* b1    = (const float*)d_in[12];  // (2,2048)
    const float* w2    = (const float*)d_in[13];  // (2,2048,512)
    const float* b2    = (const float*)d_in[14];  // (2,512)
    const float* lng   = (const float*)d_in[15];  // (2,512)
    const float* lnb   = (const float*)d_in[16];  // (2,512)
    float* out = (float*)d_out;
    float* ws  = (float*)d_ws;
    unsigned short* wsu = (unsigned short*)d_ws;

    const size_t MEG = 1048576;
    // float-offset layout (~45M floats = 180 MB)
    const size_t R0    = 0;              // 8M: preF/preB -> qt-split (L1) -> lnsrc
    const size_t R1    = 8 * MEG;        // 8M: q2 split (hi @8M, lo @12M)
    const size_t AR    = 16 * MEG;       // 12M arena: x-split / attn scratch / ffh-split / wtmp
    const size_t QHI   = 28 * MEG;       // 4M fl each
    const size_t QLO   = 32 * MEG;
    const size_t FHI   = 36 * MEG;       // 1M fl each
    const size_t FLO   = 37 * MEG;
    const size_t FTHI  = 38 * MEG;
    const size_t FTLO  = 39 * MEG;
    const size_t LEHI  = 40 * MEG;                 // .25M fl each
    const size_t LELO  = LEHI  + MEG / 4;
    const size_t LETHI = LELO  + MEG / 4;
    const size_t LETLO = LETHI + MEG / 4;
    const size_t WIHFH = LETLO + MEG / 4;
    const size_t WIHFL = WIHFH + MEG / 4;
    const size_t WIHBH = WIHFL + MEG / 4;
    const size_t WIHBL = WIHBH + MEG / 4;
    const size_t SYNC  = WIHBL + MEG / 4;          // flags[32] + hg u64
    const size_t W1TH  = SYNC  + MEG / 4;          // .5M fl each
    const size_t W1TL  = W1TH  + MEG / 2;
    const size_t W2TH  = W1TL  + MEG / 2;
    const size_t W2TL  = W2TH  + MEG / 2;
    const size_t PTH   = W2TL  + MEG / 2;          // .25M fl each
    const size_t PTL   = PTH   + MEG / 4;
    const size_t BSUM  = PTL   + MEG / 4;

    float* preF   = ws + R0;
    float* preB   = ws + R0 + 4 * MEG;
    float* lnsrc  = ws + R0;
    float* arena  = ws + AR;
    float* bsum   = ws + BSUM;
    int*   flags  = (int*)(ws + SYNC);
    unsigned long long* hg = (unsigned long long*)(ws + SYNC + 1024);
    unsigned short* qthi  = wsu + 2 * R0;                  // L1 only
    unsigned short* qtlo  = wsu + 2 * (R0 + 4 * MEG);
    unsigned short* q2hi  = wsu + 2 * R1;
    unsigned short* q2lo  = wsu + 2 * (R1 + 4 * MEG);
    unsigned short* qhi   = wsu + 2 * QHI;
    unsigned short* qlo   = wsu + 2 * QLO;
    unsigned short* fhi   = wsu + 2 * FHI;
    unsigned short* flo   = wsu + 2 * FLO;
    unsigned short* fthi  = wsu + 2 * FTHI;
    unsigned short* ftlo  = wsu + 2 * FTLO;
    unsigned short* lehi  = wsu + 2 * LEHI;
    unsigned short* lelo  = wsu + 2 * LELO;
    unsigned short* lethi = wsu + 2 * LETHI;
    unsigned short* letlo = wsu + 2 * LETLO;
    unsigned short* wihFh = wsu + 2 * WIHFH;
    unsigned short* wihFl = wsu + 2 * WIHFL;
    unsigned short* wihBh = wsu + 2 * WIHBH;
    unsigned short* wihBl = wsu + 2 * WIHBL;
    unsigned short* w1th  = wsu + 2 * W1TH;
    unsigned short* w1tl  = wsu + 2 * W1TL;
    unsigned short* w2th  = wsu + 2 * W2TH;
    unsigned short* w2tl  = wsu + 2 * W2TL;
    unsigned short* pth   = wsu + 2 * PTH;
    unsigned short* ptl   = wsu + 2 * PTL;

    // ---- prep
    bias_sum_kernel<<<8, 256, 0, stream>>>(bihF, bhhF, bihB, bhhB, bsum);
    cvt_split<<<512, 256, 0, stream>>>(WihF, wihFh, wihFl);
    cvt_split<<<512, 256, 0, stream>>>(WihB, wihBh, wihBl);
    cvt_split<<<512, 256, 0, stream>>>(le, lehi, lelo);
    { dim3 g(512 / 64, 1024 / 64, 1);
      tcvt_bf16<<<g, 256, 0, stream>>>(lehi, lethi, 1024, 512);
      tcvt_bf16<<<g, 256, 0, stream>>>(lelo, letlo, 1024, 512); }
    hipMemsetAsync(flags, 0, 32 * sizeof(int), stream);

    // x -> split (arena scratch, dead after pre GEMMs)
    unsigned short* xhi = wsu + 2 * AR;              // 2M elems
    unsigned short* xlo = wsu + 2 * (AR + MEG);
    cvt_split<<<2048, 256, 0, stream>>>(x, xhi, xlo);

    // ---- LSTM input projections: pre = x @ Wih^T + (bih+bhh)
    gemm_f(0, xhi, xlo, wihFh, wihFl, bsum,        preF, NB * NS, 1024, ND, 0, 0, 0, 1, stream);
    gemm_f(0, xhi, xlo, wihBh, wihBl, bsum + 1024, preB, NB * NS, 1024, ND, 0, 0, 0, 1, stream);

    // ---- recurrence -> features (split bf16), cooperative 32-block kernel
    lstm_rec6<<<32, 256, 0, stream>>>(preF, preB, WhhF, WhhB, hg, flags, fhi, flo);
    { dim3 g(512 / 64, 256 / 64, 16);
      tcvt_bf16<<<g, 256, 0, stream>>>(fhi, fthi, 256, 512);
      tcvt_bf16<<<g, 256, 0, stream>>>(flo, ftlo, 256, 512); }

    // ---- layers
    for (int l = 0; l < 2; ++l) {
        const float* b1l = b1 + (size_t)l * NF;
        const float* b2l = b2 + (size_t)l * ND;
        const float* gl  = lng + (size_t)l * ND;
        const float* bl  = lnb + (size_t)l * ND;

        // FFN weights -> split bf16, transposed (tmp in arena)
        unsigned short* wth = wsu + 2 * (AR + 2 * MEG);   // 1M elems
        unsigned short* wtl = wsu + 2 * (AR + 2 * MEG + MEG / 2);
        cvt_split<<<1024, 256, 0, stream>>>(w1 + (size_t)l * ND * NF, wth, wtl);   // (512,2048)
        { dim3 g(NF / 64, ND / 64, 1);
          tcvt_bf16<<<g, 256, 0, stream>>>(wth, w1th, ND, NF);
          tcvt_bf16<<<g, 256, 0, stream>>>(wtl, w1tl, ND, NF); }                   // (2048,512)
        cvt_split<<<1024, 256, 0, stream>>>(w2 + (size_t)l * NF * ND, wth, wtl);   // (2048,512)
        { dim3 g(ND / 64, NF / 64, 1);
          tcvt_bf16<<<g, 256, 0, stream>>>(wth, w2th, NF, ND);
          tcvt_bf16<<<g, 256, 0, stream>>>(wtl, w2tl, NF, ND); }                   // (512,2048)

        if (l == 0) {
            // query identical across batch: shared self-attn + q1
            float* wsc = arena;                                    // 1M fl
            unsigned short* wschi = wsu + 2 * (AR + 1 * MEG);      // .5M fl
            unsigned short* wsclo = wsu + 2 * (AR + MEG + MEG / 2);
            unsigned short* q1hi  = wsu + 2 * (AR + 2 * MEG);      // .25M fl
            unsigned short* q1lo  = wsu + 2 * (AR + 2 * MEG + MEG / 4);
            float* s2s = arena + 3 * MEG;                          // 4M fl
            unsigned short* s2hi = wsu + 2 * (AR + 7 * MEG);       // 2M fl
            unsigned short* s2lo = wsu + 2 * (AR + 9 * MEG);

            gemm_f(0, lehi, lelo, lehi, lelo, nullptr, wsc, NH, NH, ND, 0, 0, 0, 1, stream);
            softmax_split<<<NH, 256, 0, stream>>>(wsc, wschi, wsclo, NH);
            gemm_s(0, wschi, wsclo, lethi, letlo, nullptr, q1hi, q1lo, NH, ND, NH, 0, 0, 0, 1, stream);
            gemm_f(0, q1hi, q1lo, fhi, flo, nullptr, s2s, NH, NS, ND,
                   0, (long)NS * ND, (long)NH * NS, 16, stream);
            softmax_split<<<NB * NH, 256, 0, stream>>>(s2s, s2hi, s2lo, NS);
            gemm_s(0, s2hi, s2lo, fthi, ftlo, nullptr, q2hi, q2lo, NH, ND, NS,
                   (long)NH * NS, (long)ND * NS, (long)NH * ND, 16, stream);
        } else {
            { dim3 g(512 / 64, 1024 / 64, 16);
              tcvt_bf16<<<g, 256, 0, stream>>>(qhi, qthi, 1024, 512);
              tcvt_bf16<<<g, 256, 0, stream>>>(qlo, qtlo, 1024, 512); }
            float* wsc4 = arena;                                   // 4M fl
            unsigned short* wschi = wsu + 2 * (AR + 4 * MEG);      // 2M fl
            unsigned short* wsclo = wsu + 2 * (AR + 6 * MEG);
            unsigned short* q1hi  = wsu + 2 * (AR + 8 * MEG);      // 1M fl
            unsigned short* q1lo  = wsu + 2 * (AR + 9 * MEG);
            float* s2s4 = arena + 10 * MEG;                        // 1M fl
            unsigned short* s2hi = wsu + 2 * (AR + 11 * MEG);      // .5M fl
            unsigned short* s2lo = wsu + 2 * (AR + 11 * MEG + MEG / 2);
            for (int g4 = 0; g4 < 4; ++g4) {
                size_t qo = (size_t)g4 * 4;
                gemm_f(0, qhi + qo * NH * ND, qlo + qo * NH * ND,
                       qhi + qo * NH * ND, qlo + qo * NH * ND, nullptr, wsc4,
                       NH, NH, ND, (long)NH * ND, (long)NH * ND, (long)NH * NH, 4, stream);
                softmax_split<<<4 * NH, 256, 0, stream>>>(wsc4, wschi, wsclo, NH);
                gemm_s(0, wschi, wsclo, qthi + qo * ND * NH, qtlo + qo * ND * NH,
                       nullptr, q1hi, q1lo, NH, ND, NH,
                       (long)NH * NH, (long)ND * NH, (long)NH * ND, 4, stream);
                gemm_f(0, q1hi, q1lo, fhi + qo * NS * ND, flo + qo * NS * ND,
                       nullptr, s2s4, NH, NS, ND,
                       (long)NH * ND, (long)NS * ND, (long)NH * NS, 4, stream);
                softmax_split<<<4 * NH, 256, 0, stream>>>(s2s4, s2hi, s2lo, NS);
                gemm_s(0, s2hi, s2lo, fthi + qo * ND * NS, ftlo + qo * ND * NS,
                       nullptr, q2hi + qo * NH * ND, q2lo + qo * NH * ND, NH, ND, NS,
                       (long)NH * NS, (long)ND * NS, (long)NH * ND, 4, stream);
            }
        }

        // FFN: 4 chunks of 4096 rows; q2-split -> ffh-split(arena) -> lnsrc fp32
        unsigned short* ffhi = wsu + 2 * AR;               // 4M fl
        unsigned short* fflo = wsu + 2 * (AR + 4 * MEG);
        for (int ch = 0; ch < 4; ++ch) {
            const unsigned short* rih = q2hi + (size_t)ch * 4096 * ND;
            const unsigned short* ril = q2lo + (size_t)ch * 4096 * ND;
            float* rows_out = lnsrc + (size_t)ch * 4096 * ND;
            gemm_s(1, rih, ril, w1th, w1tl, b1l, ffhi, fflo, 4096, NF, ND, 0, 0, 0, 1, stream);
            gemm_f(0, ffhi, fflo, w2th, w2tl, b2l, rows_out, 4096, ND, NF, 0, 0, 0, 1, stream);
        }
        layernorm_split<<<NB * NH, 256, 0, stream>>>(lnsrc, gl, bl, qhi, qlo);
    }

    // ---- final projection (proj -> split, transposed; arena free now)
    {
        unsigned short* prh = wsu + 2 * AR;                // .25M fl
        unsigned short* prl = wsu + 2 * (AR + MEG / 4);
        cvt_split<<<512, 256, 0, stream>>>(proj, prh, prl);              // (512,1024)
        dim3 g(1024 / 64, 512 / 64, 1);
        tcvt_bf16<<<g, 256, 0, stream>>>(prh, pth, 512, 1024);
        tcvt_bf16<<<g, 256, 0, stream>>>(prl, ptl, 512, 1024);           // (1024,512)
    }
    outproj3<<<4096, 256, 0, stream>>>(qhi, qlo, pth, ptl, out);
}

// Round 8
// 2150.998 us; speedup vs baseline: 8.2332x; 1.1956x over previous
//
#include <hip/hip_runtime.h>
#include <hip/hip_bf16.h>
#include <math.h>

// Problem dims
#define NB 16
#define NS 256
#define ND 512
#define NH 1024
#define NF 2048
#define NHID 256

typedef __attribute__((ext_vector_type(8))) short bf16x8;
typedef __attribute__((ext_vector_type(4))) float f32x4;

__device__ __forceinline__ unsigned short f2bf(float f) {
    unsigned u = __float_as_uint(f);
    unsigned r = u + 0x7fffu + ((u >> 16) & 1u);
    return (unsigned short)(r >> 16);
}
__device__ __forceinline__ float bf2f(unsigned short h) {
    return __uint_as_float(((unsigned)h) << 16);
}

// ---------------------------------------------------------------------------
// Split-bf16 MFMA GEMM v3: C[M,N] = A[M,K] @ B[N,K]^T (+bias)(+gelu)
// Pre-split hi/lo bf16 operands, 3-pass (Ah*Bh + Al*Bh + Ah*Bl ~ fp32).
// lda/ldb: row strides in u16 elems (lda=K normal; lda=2K for in-place
// softmax output where hi=row[0..K), lo=row[K..2K)).
// global_load_lds width-16 staging, linear LDS (m97 structure).
// Tile 128x128, BK=32, 256 thr. M,N%128==0, K%32==0. Z-batched.
// ---------------------------------------------------------------------------
template<int ACT, int OUT_SPLIT>
__global__ __launch_bounds__(256) void sgemm3(
    const unsigned short* __restrict__ Ahi, const unsigned short* __restrict__ Alo,
    const unsigned short* __restrict__ Bhi, const unsigned short* __restrict__ Blo,
    const float* __restrict__ bias,
    float* __restrict__ C, unsigned short* __restrict__ Chi, unsigned short* __restrict__ Clo,
    int M, int N, int K, int lda, int ldb, long sA, long sB, long sC)
{
    __shared__ unsigned short Ah[128 * 32];
    __shared__ unsigned short Al[128 * 32];
    __shared__ unsigned short Bh[128 * 32];
    __shared__ unsigned short Bl[128 * 32];

    const int t = threadIdx.x;
    const int z = blockIdx.z;
    const int m0 = blockIdx.y * 128, n0 = blockIdx.x * 128;
    const int wid = t >> 6, lane = t & 63;
    const int wr = (wid >> 1) * 64, wc = (wid & 1) * 64;
    const int lr = lane & 15, lk = lane >> 4;
    const int rl = lane >> 2, sl = lane & 3;     // staging: row-in-16, 16B slot

    const unsigned short* pAh = Ahi + (size_t)z * sA;
    const unsigned short* pAl = Alo + (size_t)z * sA;
    const unsigned short* pBh = Bhi + (size_t)z * sB;
    const unsigned short* pBl = Blo + (size_t)z * sB;

    f32x4 acc[4][4];
    #pragma unroll
    for (int i = 0; i < 4; ++i)
        #pragma unroll
        for (int j = 0; j < 4; ++j) acc[i][j] = (f32x4){0.f, 0.f, 0.f, 0.f};

    for (int k0 = 0; k0 < K; k0 += 32) {
        #pragma unroll
        for (int e = 0; e < 2; ++e) {
            const int r = e * 64 + wid * 16 + rl;
            const size_t goA = (size_t)(m0 + r) * lda + k0 + sl * 8;
            const size_t goB = (size_t)(n0 + r) * ldb + k0 + sl * 8;
            const int lo = (e * 64 + wid * 16) * 32;
            __builtin_amdgcn_global_load_lds((const void*)(pAh + goA), (void*)&Ah[lo], 16, 0, 0);
            __builtin_amdgcn_global_load_lds((const void*)(pAl + goA), (void*)&Al[lo], 16, 0, 0);
            __builtin_amdgcn_global_load_lds((const void*)(pBh + goB), (void*)&Bh[lo], 16, 0, 0);
            __builtin_amdgcn_global_load_lds((const void*)(pBl + goB), (void*)&Bl[lo], 16, 0, 0);
        }
        __syncthreads();

        bf16x8 ah[4], al[4], bh[4], bl[4];
        #pragma unroll
        for (int mt = 0; mt < 4; ++mt) {
            int rf = wr + mt * 16 + lr;
            ah[mt] = *(const bf16x8*)&Ah[rf * 32 + lk * 8];
            al[mt] = *(const bf16x8*)&Al[rf * 32 + lk * 8];
        }
        #pragma unroll
        for (int nt = 0; nt < 4; ++nt) {
            int rf = wc + nt * 16 + lr;
            bh[nt] = *(const bf16x8*)&Bh[rf * 32 + lk * 8];
            bl[nt] = *(const bf16x8*)&Bl[rf * 32 + lk * 8];
        }
        #pragma unroll
        for (int mt = 0; mt < 4; ++mt)
            #pragma unroll
            for (int nt = 0; nt < 4; ++nt) {
                acc[mt][nt] = __builtin_amdgcn_mfma_f32_16x16x32_bf16(ah[mt], bh[nt], acc[mt][nt], 0, 0, 0);
                acc[mt][nt] = __builtin_amdgcn_mfma_f32_16x16x32_bf16(al[mt], bh[nt], acc[mt][nt], 0, 0, 0);
                acc[mt][nt] = __builtin_amdgcn_mfma_f32_16x16x32_bf16(ah[mt], bl[nt], acc[mt][nt], 0, 0, 0);
            }
        __syncthreads();
    }

    #pragma unroll
    for (int nt = 0; nt < 4; ++nt) {
        int col = n0 + wc + nt * 16 + lr;
        float bv = bias ? bias[col] : 0.0f;
        #pragma unroll
        for (int mt = 0; mt < 4; ++mt) {
            #pragma unroll
            for (int i = 0; i < 4; ++i) {
                int row = m0 + wr + mt * 16 + lk * 4 + i;
                float x = acc[mt][nt][i] + bv;
                if (ACT == 1) x = 0.5f * x * (1.0f + erff(x * 0.70710678118654752f));
                size_t oi = (size_t)z * sC + (size_t)row * N + col;
                if (OUT_SPLIT) {
                    unsigned short h = f2bf(x);
                    Chi[oi] = h;
                    Clo[oi] = f2bf(x - bf2f(h));
                } else {
                    C[oi] = x;
                }
            }
        }
    }
}

static void gemm_f(int act, const unsigned short* Ahi, const unsigned short* Alo,
                   const unsigned short* Bhi, const unsigned short* Blo,
                   const float* bias, float* C, int M, int N, int K, int lda, int ldb,
                   long sA, long sB, long sC, int Z, hipStream_t st)
{
    dim3 g(N / 128, M / 128, Z), b(256);
    if (act) sgemm3<1, 0><<<g, b, 0, st>>>(Ahi, Alo, Bhi, Blo, bias, C, nullptr, nullptr, M, N, K, lda, ldb, sA, sB, sC);
    else     sgemm3<0, 0><<<g, b, 0, st>>>(Ahi, Alo, Bhi, Blo, bias, C, nullptr, nullptr, M, N, K, lda, ldb, sA, sB, sC);
}
static void gemm_s(int act, const unsigned short* Ahi, const unsigned short* Alo,
                   const unsigned short* Bhi, const unsigned short* Blo,
                   const float* bias, unsigned short* Chi, unsigned short* Clo,
                   int M, int N, int K, int lda, int ldb,
                   long sA, long sB, long sC, int Z, hipStream_t st)
{
    dim3 g(N / 128, M / 128, Z), b(256);
    if (act) sgemm3<1, 1><<<g, b, 0, st>>>(Ahi, Alo, Bhi, Blo, bias, nullptr, Chi, Clo, M, N, K, lda, ldb, sA, sB, sC);
    else     sgemm3<0, 1><<<g, b, 0, st>>>(Ahi, Alo, Bhi, Blo, bias, nullptr, Chi, Clo, M, N, K, lda, ldb, sA, sB, sC);
}

// ---------------------------------------------------------------------------
// fp32 -> split bf16 hi/lo (n multiple of 1024)
// ---------------------------------------------------------------------------
__global__ __launch_bounds__(256) void cvt_split(const float* __restrict__ in,
                                                 unsigned short* __restrict__ hi,
                                                 unsigned short* __restrict__ lo)
{
    size_t i = ((size_t)blockIdx.x * 256 + threadIdx.x) * 4;
    float4 v = *(const float4*)(in + i);
    ushort4 h, l;
    h.x = f2bf(v.x); l.x = f2bf(v.x - bf2f(h.x));
    h.y = f2bf(v.y); l.y = f2bf(v.y - bf2f(h.y));
    h.z = f2bf(v.z); l.z = f2bf(v.z - bf2f(h.z));
    h.w = f2bf(v.w); l.w = f2bf(v.w - bf2f(h.w));
    *(ushort4*)(hi + i) = h;
    *(ushort4*)(lo + i) = l;
}

// ---------------------------------------------------------------------------
// bf16 (R,C) -> (C,R) transpose, z-batched. R,C multiples of 64.
// ---------------------------------------------------------------------------
__global__ __launch_bounds__(256) void tcvt_bf16(const unsigned short* __restrict__ in,
                                                 unsigned short* __restrict__ out,
                                                 int R, int C)
{
    __shared__ unsigned short tile[64 * 72];
    int z = blockIdx.z;
    in += (size_t)z * R * C;
    out += (size_t)z * R * C;
    int r0 = blockIdx.y * 64, c0 = blockIdx.x * 64;
    int t = threadIdx.x;
    int tr = t >> 2, tc = (t & 3) * 16;

    uint4 q0 = *(const uint4*)(in + (size_t)(r0 + tr) * C + c0 + tc);
    uint4 q1 = *(const uint4*)(in + (size_t)(r0 + tr) * C + c0 + tc + 8);
    unsigned short e[16];
    *(uint4*)(e) = q0;
    *(uint4*)(e + 8) = q1;
    #pragma unroll
    for (int i = 0; i < 16; ++i) tile[(tc + i) * 72 + tr] = e[i];
    __syncthreads();

    uint4 o0 = *(const uint4*)(&tile[tr * 72 + tc]);
    uint4 o1 = *(const uint4*)(&tile[tr * 72 + tc + 8]);
    *(uint4*)(out + (size_t)(c0 + tr) * R + r0 + tc) = o0;
    *(uint4*)(out + (size_t)(c0 + tr) * R + r0 + tc + 8) = o1;
}

// ---------------------------------------------------------------------------
// bias combine
// ---------------------------------------------------------------------------
__global__ __launch_bounds__(256) void bias_sum_kernel(
    const float* bihF, const float* bhhF, const float* bihB, const float* bhhB,
    float* out)
{
    int i = blockIdx.x * 256 + threadIdx.x;
    if (i < 1024) out[i] = bihF[i] + bhhF[i];
    else out[i] = bihB[i - 1024] + bhhB[i - 1024];
}

// ---------------------------------------------------------------------------
// LSTM recurrence v7: = v6 (MFMA + reg weights, fence-free MALL sync) with
// the feature (fhi/flo) stores moved AFTER the flag release — they drain
// during the next spin window instead of polluting the per-step vmcnt(0).
// ---------------------------------------------------------------------------
__global__ __launch_bounds__(256) void lstm_rec7(
    const float* __restrict__ preF, const float* __restrict__ preB,
    const float* __restrict__ WhhF, const float* __restrict__ WhhB,
    unsigned long long* __restrict__ hg,   // [2 parity][2 dir][16 b][128] u64
    int* __restrict__ flags,               // [32], zeroed before launch
    unsigned short* __restrict__ fhi, unsigned short* __restrict__ flo)
{
    const int bid = blockIdx.x;
    const int dir = bid >> 4, slice = bid & 15;
    const float* pre = dir ? preB : preF;
    const float* Whh = dir ? WhhB : WhhF;

    const int tid = threadIdx.x;
    const int wv = tid >> 6;
    const int lane = tid & 63;
    const int lr = lane & 15;
    const int lk = lane >> 4;
    const int eb = tid >> 4;
    const int eu = tid & 15;

    __shared__ unsigned short hh[16 * 264];
    __shared__ unsigned short hl[16 * 264];
    __shared__ float gx[4][16][17];

    bf16x8 wfh[8], wfl[8];
    {
        const float* wrow = Whh + (size_t)(wv * 256 + slice * 16 + lr) * 256 + lk * 8;
        #pragma unroll
        for (int kt = 0; kt < 8; ++kt) {
            float4 a = *(const float4*)(wrow + kt * 32);
            float4 b = *(const float4*)(wrow + kt * 32 + 4);
            float v[8] = {a.x, a.y, a.z, a.w, b.x, b.y, b.z, b.w};
            unsigned short hhv[8], llv[8];
            #pragma unroll
            for (int i = 0; i < 8; ++i) {
                unsigned short h = f2bf(v[i]);
                hhv[i] = h;
                llv[i] = f2bf(v[i] - bf2f(h));
            }
            wfh[kt] = *(bf16x8*)hhv;
            wfl[kt] = *(bf16x8*)llv;
        }
    }
    for (int i = tid; i < 16 * 264; i += 256) { hh[i] = 0; hl[i] = 0; }

    float c = 0.0f;
    __syncthreads();

    for (int si = 0; si < NS; ++si) {
        const int s = dir ? (NS - 1 - si) : si;
        const float* pp = pre + ((size_t)(eb * NS + s)) * 1024 + slice * 16 + eu;
        float pi = pp[0], pf = pp[256], pg = pp[512], po = pp[768];

        if (si > 0) {
            if (tid < 16) {
                while (__hip_atomic_load(&flags[dir * 16 + tid], __ATOMIC_RELAXED,
                                         __HIP_MEMORY_SCOPE_AGENT) < si) {
                    __builtin_amdgcn_s_sleep(1);
                }
            }
            __syncthreads();
            const unsigned long long* src =
                hg + (size_t)(((si - 1) & 1) * 2 + dir) * 2048;
            const int b2 = tid >> 4, pb = (tid & 15) * 8;
            unsigned short hbuf[16], lbuf[16];
            #pragma unroll
            for (int j = 0; j < 8; ++j) {
                unsigned long long v = __hip_atomic_load(
                    &src[b2 * 128 + pb + j], __ATOMIC_RELAXED,
                    __HIP_MEMORY_SCOPE_AGENT);
                hbuf[2 * j]     = (unsigned short)(v & 0xffff);
                lbuf[2 * j]     = (unsigned short)((v >> 16) & 0xffff);
                hbuf[2 * j + 1] = (unsigned short)((v >> 32) & 0xffff);
                lbuf[2 * j + 1] = (unsigned short)(v >> 48);
            }
            char* dh = (char*)hh + b2 * 528 + (tid & 15) * 32;
            char* dl = (char*)hl + b2 * 528 + (tid & 15) * 32;
            *(uint4*)dh        = *(uint4*)(hbuf);
            *(uint4*)(dh + 16) = *(uint4*)(hbuf + 8);
            *(uint4*)dl        = *(uint4*)(lbuf);
            *(uint4*)(dl + 16) = *(uint4*)(lbuf + 8);
            __syncthreads();
        }

        f32x4 acc = (f32x4){0.f, 0.f, 0.f, 0.f};
        #pragma unroll
        for (int kt = 0; kt < 8; ++kt) {
            const char* hp = (const char*)hh + lr * 528 + kt * 64 + lk * 16;
            const char* lp = (const char*)hl + lr * 528 + kt * 64 + lk * 16;
            bf16x8 ah = *(const bf16x8*)hp;
            bf16x8 al = *(const bf16x8*)lp;
            acc = __builtin_amdgcn_mfma_f32_16x16x32_bf16(ah, wfh[kt], acc, 0, 0, 0);
            acc = __builtin_amdgcn_mfma_f32_16x16x32_bf16(al, wfh[kt], acc, 0, 0, 0);
            acc = __builtin_amdgcn_mfma_f32_16x16x32_bf16(ah, wfl[kt], acc, 0, 0, 0);
        }
        #pragma unroll
        for (int i = 0; i < 4; ++i) gx[wv][lk * 4 + i][lr] = acc[i];
        __syncthreads();

        float ai = gx[0][eb][eu] + pi;
        float af = gx[1][eb][eu] + pf;
        float ag = gx[2][eb][eu] + pg;
        float ao = gx[3][eb][eu] + po;
        float gi = 1.0f / (1.0f + expf(-ai));
        float gf = 1.0f / (1.0f + expf(-af));
        float gg = tanhf(ag);
        float go = 1.0f / (1.0f + expf(-ao));
        c = gf * c + gi * gg;
        float h = go * tanhf(c);

        unsigned short h16 = f2bf(h);
        unsigned short l16 = f2bf(h - bf2f(h16));
        unsigned my = (unsigned)h16 | ((unsigned)l16 << 16);
        unsigned oth = __shfl_xor(my, 1);
        if ((eu & 1) == 0) {
            unsigned long long v = (unsigned long long)my |
                                   ((unsigned long long)oth << 32);
            unsigned long long* dst =
                hg + (size_t)((si & 1) * 2 + dir) * 2048;
            __hip_atomic_store(&dst[eb * 128 + slice * 8 + (eu >> 1)], v,
                               __ATOMIC_RELAXED, __HIP_MEMORY_SCOPE_AGENT);
        }
        // release: only the hg stores need to be visible before the flag
        asm volatile("s_waitcnt vmcnt(0)" ::: "memory");
        __syncthreads();
        if (tid == 0)
            __hip_atomic_store(&flags[bid], si + 1, __ATOMIC_RELAXED,
                               __HIP_MEMORY_SCOPE_AGENT);
        // feature stores off the critical path (drain during next spin)
        size_t oi = ((size_t)(eb * NS + s)) * 512 + dir * 256 + slice * 16 + eu;
        fhi[oi] = h16;
        flo[oi] = l16;
    }
}

// ---------------------------------------------------------------------------
// In-place split softmax: row of N fp32 -> same memory becomes
// [N hi bf16][N lo bf16]. grid = rows, block = 256, N in {256, 1024}.
// ---------------------------------------------------------------------------
__global__ __launch_bounds__(256) void softmax_ip(float* __restrict__ X, int N)
{
    float* row = X + (size_t)blockIdx.x * N;
    unsigned short* o = (unsigned short*)row;
    int t = threadIdx.x;
    int cnt = N >> 8;                  // 1 or 4
    float v[4];
    float m = -1e30f;
    for (int i = 0; i < cnt; ++i) { v[i] = row[t + (i << 8)]; m = fmaxf(m, v[i]); }
    for (int sh = 32; sh; sh >>= 1) m = fmaxf(m, __shfl_xor(m, sh));
    __shared__ float lm[4];
    if ((t & 63) == 0) lm[t >> 6] = m;
    __syncthreads();
    m = fmaxf(fmaxf(lm[0], lm[1]), fmaxf(lm[2], lm[3]));
    float s = 0.0f;
    for (int i = 0; i < cnt; ++i) { v[i] = expf(v[i] - m); s += v[i]; }
    for (int sh = 32; sh; sh >>= 1) s += __shfl_xor(s, sh);
    __shared__ float ls[4];
    if ((t & 63) == 0) ls[t >> 6] = s;
    __syncthreads();
    s = ls[0] + ls[1] + ls[2] + ls[3];
    float inv = 1.0f / s;
    __syncthreads();                   // all reads done before overwrite
    for (int i = 0; i < cnt; ++i) {
        float y = v[i] * inv;
        unsigned short h = f2bf(y);
        int j = t + (i << 8);
        o[j] = h;
        o[N + j] = f2bf(y - bf2f(h));
    }
}

// ---------------------------------------------------------------------------
// LayerNorm rows of 512 fp32 -> split bf16 out. grid = rows, block = 256.
// ---------------------------------------------------------------------------
__global__ __launch_bounds__(256) void layernorm_split(
    const float* __restrict__ X, const float* __restrict__ g, const float* __restrict__ b,
    unsigned short* __restrict__ ohi, unsigned short* __restrict__ olo)
{
    const float* row = X + (size_t)blockIdx.x * 512;
    size_t ob = (size_t)blockIdx.x * 512;
    int t = threadIdx.x;
    float x0 = row[t], x1 = row[t + 256];
    float s = x0 + x1, sq = x0 * x0 + x1 * x1;
    for (int o = 32; o; o >>= 1) { s += __shfl_xor(s, o); sq += __shfl_xor(sq, o); }
    __shared__ float ls[8];
    int w = t >> 6;
    if ((t & 63) == 0) { ls[w] = s; ls[4 + w] = sq; }
    __syncthreads();
    s = ls[0] + ls[1] + ls[2] + ls[3];
    sq = ls[4] + ls[5] + ls[6] + ls[7];
    float mu = s * (1.0f / 512.0f);
    float var = sq * (1.0f / 512.0f) - mu * mu;
    float inv = rsqrtf(var + 1e-5f);
    float y0 = (x0 - mu) * inv * g[t]       + b[t];
    float y1 = (x1 - mu) * inv * g[t + 256] + b[t + 256];
    unsigned short h0 = f2bf(y0), h1 = f2bf(y1);
    ohi[ob + t]       = h0;  olo[ob + t]       = f2bf(y0 - bf2f(h0));
    ohi[ob + t + 256] = h1;  olo[ob + t + 256] = f2bf(y1 - bf2f(h1));
}

// ---------------------------------------------------------------------------
// out[b,h] = dot(q[b,h,:], projT[h,:]) with hi+lo reconstruction
// ---------------------------------------------------------------------------
__global__ __launch_bounds__(256) void outproj3(
    const unsigned short* __restrict__ qhi, const unsigned short* __restrict__ qlo,
    const unsigned short* __restrict__ phi, const unsigned short* __restrict__ plo,
    float* __restrict__ out)
{
    int gw = blockIdx.x * 4 + (threadIdx.x >> 6);
    int lane = threadIdx.x & 63;
    int h = gw & 1023;
    uint4 qh = ((const uint4*)(qhi + (size_t)gw * 512))[lane];
    uint4 ql = ((const uint4*)(qlo + (size_t)gw * 512))[lane];
    uint4 ph = ((const uint4*)(phi + (size_t)h * 512))[lane];
    uint4 pl = ((const uint4*)(plo + (size_t)h * 512))[lane];
    unsigned short qhe[8], qle[8], phe[8], ple[8];
    *(uint4*)qhe = qh; *(uint4*)qle = ql; *(uint4*)phe = ph; *(uint4*)ple = pl;
    float s = 0.0f;
    #pragma unroll
    for (int i = 0; i < 8; ++i) {
        float q = bf2f(qhe[i]) + bf2f(qle[i]);
        float p = bf2f(phe[i]) + bf2f(ple[i]);
        s += q * p;
    }
    for (int o = 32; o; o >>= 1) s += __shfl_xor(s, o);
    if (lane == 0) out[gw] = s;
}

// ---------------------------------------------------------------------------
// launcher
// ---------------------------------------------------------------------------
extern "C" void kernel_launch(void* const* d_in, const int* in_sizes, int n_in,
                              void* d_out, int out_size, void* d_ws, size_t ws_size,
                              hipStream_t stream)
{
    (void)in_sizes; (void)n_in; (void)out_size; (void)ws_size;

    const float* x     = (const float*)d_in[0];
    const float* le    = (const float*)d_in[1];
    const float* proj  = (const float*)d_in[2];
    const float* WihF  = (const float*)d_in[3];
    const float* WhhF  = (const float*)d_in[4];
    const float* bihF  = (const float*)d_in[5];
    const float* bhhF  = (const float*)d_in[6];
    const float* WihB  = (const float*)d_in[7];
    const float* WhhB  = (const float*)d_in[8];
    const float* bihB  = (const float*)d_in[9];
    const float* bhhB  = (const float*)d_in[10];
    const float* w1    = (const float*)d_in[11];
    const float* b1    = (const float*)d_in[12];
    const float* w2    = (const float*)d_in[13];
    const float* b2    = (const float*)d_in[14];
    const float* lng   = (const float*)d_in[15];
    const float* lnb   = (const float*)d_in[16];
    float* out = (float*)d_out;
    float* ws  = (float*)d_ws;
    unsigned short* wsu = (unsigned short*)d_ws;

    const size_t MEG = 1048576;
    // float-offset layout (~50M floats = 200 MB)
    const size_t R0    = 0;              // 8M: preF/preB -> qt-split (L1) -> lnsrc
    const size_t R1    = 8 * MEG;        // 8M: q2 split
    const size_t AR    = 16 * MEG;       // 17M arena
    const size_t QHI   = 33 * MEG;       // 4M each
    const size_t QLO   = 37 * MEG;
    const size_t FHI   = 41 * MEG;       // 1M each
    const size_t FLO   = 42 * MEG;
    const size_t FTHI  = 43 * MEG;
    const size_t FTLO  = 44 * MEG;
    const size_t LEHI  = 45 * MEG;
    const size_t LELO  = LEHI  + MEG / 4;
    const size_t LETHI = LELO  + MEG / 4;
    const size_t LETLO = LETHI + MEG / 4;
    const size_t WIHFH = 46 * MEG;
    const size_t WIHFL = WIHFH + MEG / 4;
    const size_t WIHBH = WIHFL + MEG / 4;
    const size_t WIHBL = WIHBH + MEG / 4;
    const size_t SYNC  = 47 * MEG;
    const size_t W1TH  = SYNC  + MEG / 4;
    const size_t W1TL  = W1TH  + MEG / 2;
    const size_t W2TH  = W1TL  + MEG / 2;
    const size_t W2TL  = W2TH  + MEG / 2;
    const size_t PTH   = W2TL  + MEG / 2;
    const size_t PTL   = PTH   + MEG / 4;
    const size_t BSUM  = PTL   + MEG / 4;

    float* preF   = ws + R0;
    float* preB   = ws + R0 + 4 * MEG;
    float* lnsrc  = ws + R0;
    float* arena  = ws + AR;
    float* bsum   = ws + BSUM;
    int*   flags  = (int*)(ws + SYNC);
    unsigned long long* hg = (unsigned long long*)(ws + SYNC + 1024);
    unsigned short* qthi  = wsu + 2 * R0;
    unsigned short* qtlo  = wsu + 2 * (R0 + 4 * MEG);
    unsigned short* q2hi  = wsu + 2 * R1;
    unsigned short* q2lo  = wsu + 2 * (R1 + 4 * MEG);
    unsigned short* qhi   = wsu + 2 * QHI;
    unsigned short* qlo   = wsu + 2 * QLO;
    unsigned short* fhi   = wsu + 2 * FHI;
    unsigned short* flo   = wsu + 2 * FLO;
    unsigned short* fthi  = wsu + 2 * FTHI;
    unsigned short* ftlo  = wsu + 2 * FTLO;
    unsigned short* lehi  = wsu + 2 * LEHI;
    unsigned short* lelo  = wsu + 2 * LELO;
    unsigned short* lethi = wsu + 2 * LETHI;
    unsigned short* letlo = wsu + 2 * LETLO;
    unsigned short* wihFh = wsu + 2 * WIHFH;
    unsigned short* wihFl = wsu + 2 * WIHFL;
    unsigned short* wihBh = wsu + 2 * WIHBH;
    unsigned short* wihBl = wsu + 2 * WIHBL;
    unsigned short* w1th  = wsu + 2 * W1TH;
    unsigned short* w1tl  = wsu + 2 * W1TL;
    unsigned short* w2th  = wsu + 2 * W2TH;
    unsigned short* w2tl  = wsu + 2 * W2TL;
    unsigned short* pth   = wsu + 2 * PTH;
    unsigned short* ptl   = wsu + 2 * PTL;

    // ---- prep
    bias_sum_kernel<<<8, 256, 0, stream>>>(bihF, bhhF, bihB, bhhB, bsum);
    cvt_split<<<512, 256, 0, stream>>>(WihF, wihFh, wihFl);
    cvt_split<<<512, 256, 0, stream>>>(WihB, wihBh, wihBl);
    cvt_split<<<512, 256, 0, stream>>>(le, lehi, lelo);
    { dim3 g(512 / 64, 1024 / 64, 1);
      tcvt_bf16<<<g, 256, 0, stream>>>(lehi, lethi, 1024, 512);
      tcvt_bf16<<<g, 256, 0, stream>>>(lelo, letlo, 1024, 512); }
    hipMemsetAsync(flags, 0, 32 * sizeof(int), stream);

    // x -> split (arena scratch)
    unsigned short* xhi = wsu + 2 * AR;
    unsigned short* xlo = wsu + 2 * (AR + MEG);
    cvt_split<<<2048, 256, 0, stream>>>(x, xhi, xlo);

    // ---- LSTM input projections
    gemm_f(0, xhi, xlo, wihFh, wihFl, bsum,        preF, NB * NS, 1024, ND, ND, ND, 0, 0, 0, 1, stream);
    gemm_f(0, xhi, xlo, wihBh, wihBl, bsum + 1024, preB, NB * NS, 1024, ND, ND, ND, 0, 0, 0, 1, stream);

    // ---- recurrence -> features (split bf16)
    lstm_rec7<<<32, 256, 0, stream>>>(preF, preB, WhhF, WhhB, hg, flags, fhi, flo);
    { dim3 g(512 / 64, 256 / 64, 16);
      tcvt_bf16<<<g, 256, 0, stream>>>(fhi, fthi, 256, 512);
      tcvt_bf16<<<g, 256, 0, stream>>>(flo, ftlo, 256, 512); }

    // ---- layers
    for (int l = 0; l < 2; ++l) {
        const float* b1l = b1 + (size_t)l * NF;
        const float* b2l = b2 + (size_t)l * ND;
        const float* gl  = lng + (size_t)l * ND;
        const float* bl  = lnb + (size_t)l * ND;

        // FFN weights -> split bf16, transposed (tmp in arena)
        unsigned short* wth = wsu + 2 * (AR + 2 * MEG);
        unsigned short* wtl = wsu + 2 * (AR + 2 * MEG + MEG / 2);
        cvt_split<<<1024, 256, 0, stream>>>(w1 + (size_t)l * ND * NF, wth, wtl);
        { dim3 g(NF / 64, ND / 64, 1);
          tcvt_bf16<<<g, 256, 0, stream>>>(wth, w1th, ND, NF);
          tcvt_bf16<<<g, 256, 0, stream>>>(wtl, w1tl, ND, NF); }
        cvt_split<<<1024, 256, 0, stream>>>(w2 + (size_t)l * NF * ND, wth, wtl);
        { dim3 g(ND / 64, NF / 64, 1);
          tcvt_bf16<<<g, 256, 0, stream>>>(wth, w2th, NF, ND);
          tcvt_bf16<<<g, 256, 0, stream>>>(wtl, w2tl, NF, ND); }

        if (l == 0) {
            // shared self-attn (batch-invariant) + batched cross-attn Z=16
            float* wsc = arena;                                  // 1M fl
            unsigned short* wscu = (unsigned short*)wsc;
            unsigned short* q1hi = wsu + 2 * (AR + 1 * MEG);     // .25M fl
            unsigned short* q1lo = wsu + 2 * (AR + 1 * MEG + MEG / 4);
            float* s2s = arena + 4 * MEG;                        // 4M fl
            unsigned short* s2u = (unsigned short*)s2s;

            gemm_f(0, lehi, lelo, lehi, lelo, nullptr, wsc, NH, NH, ND, ND, ND, 0, 0, 0, 1, stream);
            softmax_ip<<<NH, 256, 0, stream>>>(wsc, NH);
            gemm_s(0, wscu, wscu + NH, lethi, letlo, nullptr, q1hi, q1lo,
                   NH, ND, NH, 2 * NH, NH, 0, 0, 0, 1, stream);
            gemm_f(0, q1hi, q1lo, fhi, flo, nullptr, s2s, NH, NS, ND, ND, ND,
                   0, (long)NS * ND, (long)NH * NS, 16, stream);
            softmax_ip<<<NB * NH, 256, 0, stream>>>(s2s, NS);
            gemm_s(0, s2u, s2u + NS, fthi, ftlo, nullptr, q2hi, q2lo,
                   NH, ND, NS, 2 * NS, NS,
                   (long)2 * NH * NS, (long)ND * NS, (long)NH * ND, 16, stream);
        } else {
            { dim3 g(512 / 64, 1024 / 64, 16);
              tcvt_bf16<<<g, 256, 0, stream>>>(qhi, qthi, 1024, 512);
              tcvt_bf16<<<g, 256, 0, stream>>>(qlo, qtlo, 1024, 512); }
            float* wsc = arena;                                  // 8M fl (Z=8)
            unsigned short* wscu = (unsigned short*)wsc;
            unsigned short* q1hi = wsu + 2 * (AR + 8 * MEG);     // 2M fl each
            unsigned short* q1lo = wsu + 2 * (AR + 10 * MEG);
            float* s2s = arena + 12 * MEG;                       // 2M fl
            unsigned short* s2u = (unsigned short*)s2s;
            for (int g8 = 0; g8 < 2; ++g8) {
                size_t qo = (size_t)g8 * 8;
                gemm_f(0, qhi + qo * NH * ND, qlo + qo * NH * ND,
                       qhi + qo * NH * ND, qlo + qo * NH * ND, nullptr, wsc,
                       NH, NH, ND, ND, ND,
                       (long)NH * ND, (long)NH * ND, (long)NH * NH, 8, stream);
                softmax_ip<<<8 * NH, 256, 0, stream>>>(wsc, NH);
                gemm_s(0, wscu, wscu + NH, qthi + qo * ND * NH, qtlo + qo * ND * NH,
                       nullptr, q1hi, q1lo, NH, ND, NH, 2 * NH, NH,
                       (long)2 * NH * NH, (long)ND * NH, (long)NH * ND, 8, stream);
                gemm_f(0, q1hi, q1lo, fhi + qo * NS * ND, flo + qo * NS * ND,
                       nullptr, s2s, NH, NS, ND, ND, ND,
                       (long)NH * ND, (long)NS * ND, (long)NH * NS, 8, stream);
                softmax_ip<<<8 * NH, 256, 0, stream>>>(s2s, NS);
                gemm_s(0, s2u, s2u + NS, fthi + qo * ND * NS, ftlo + qo * ND * NS,
                       nullptr, q2hi + qo * NH * ND, q2lo + qo * NH * ND,
                       NH, ND, NS, 2 * NS, NS,
                       (long)2 * NH * NS, (long)ND * NS, (long)NH * ND, 8, stream);
            }
        }

        // FFN: 2 chunks of 8192 rows; q2-split -> ffh-split(arena) -> lnsrc fp32
        unsigned short* ffhi = wsu + 2 * AR;                  // 8M fl
        unsigned short* fflo = wsu + 2 * (AR + 8 * MEG);      // 8M fl
        for (int ch = 0; ch < 2; ++ch) {
            const unsigned short* rih = q2hi + (size_t)ch * 8192 * ND;
            const unsigned short* ril = q2lo + (size_t)ch * 8192 * ND;
            float* rows_out = lnsrc + (size_t)ch * 8192 * ND;
            gemm_s(1, rih, ril, w1th, w1tl, b1l, ffhi, fflo,
                   8192, NF, ND, ND, ND, 0, 0, 0, 1, stream);
            gemm_f(0, ffhi, fflo, w2th, w2tl, b2l, rows_out,
                   8192, ND, NF, NF, NF, 0, 0, 0, 1, stream);
        }
        layernorm_split<<<NB * NH, 256, 0, stream>>>(lnsrc, gl, bl, qhi, qlo);
    }

    // ---- final projection
    {
        unsigned short* prh = wsu + 2 * AR;
        unsigned short* prl = wsu + 2 * (AR + MEG / 4);
        cvt_split<<<512, 256, 0, stream>>>(proj, prh, prl);
        dim3 g(1024 / 64, 512 / 64, 1);
        tcvt_bf16<<<g, 256, 0, stream>>>(prh, pth, 512, 1024);
        tcvt_bf16<<<g, 256, 0, stream>>>(prl, ptl, 512, 1024);
    }
    outproj3<<<4096, 256, 0, stream>>>(qhi, qlo, pth, ptl, out);
}